// Round 1
// baseline (1318.657 us; speedup 1.0000x reference)
//
#include <hip/hip_runtime.h>
#include <math.h>

// ---------------------------------------------------------------------------
// MultiTaskGAT: 2x GATConv(8 heads x 32ch, concat) + 4 task heads (1 head)
// N=50000 nodes, E=800000 edges (+N self loops), F_IN=128, DH=256.
// Pipeline:
//   CSR build (by dst) -> GEMM1 -> alphas1 -> agg1(+ELU) -> GEMM2 -> alphas2
//   -> agg2 -> pack Wcat/bcat -> GEMM-heads -> task alphas -> task agg
//   -> log_softmax -> d_out
// ---------------------------------------------------------------------------

#define NEG_SLOPE 0.2f

// ---------------- CSR build ----------------

__global__ void init_kernel(int* __restrict__ deg, int* __restrict__ cursor, int n) {
    int i = blockIdx.x * blockDim.x + threadIdx.x;
    if (i < n) { deg[i] = 1; cursor[i] = 0; }   // deg starts at 1: self loop
}

__global__ void count_kernel(const int* __restrict__ dst, int* __restrict__ deg, int E) {
    int i = blockIdx.x * blockDim.x + threadIdx.x;
    if (i < E) atomicAdd(&deg[dst[i]], 1);
}

__global__ __launch_bounds__(1024) void scan_kernel(const int* __restrict__ deg,
                                                    int* __restrict__ rowstart, int n) {
    __shared__ int sh[1024];
    __shared__ int carry_sh;
    if (threadIdx.x == 0) { carry_sh = 0; rowstart[0] = 0; }
    __syncthreads();
    for (int base = 0; base < n; base += 8192) {
        int vals[8];
        int sum = 0;
        int i0 = base + threadIdx.x * 8;
        #pragma unroll
        for (int j = 0; j < 8; ++j) {
            int i = i0 + j;
            int v = (i < n) ? deg[i] : 0;
            sum += v;
            vals[j] = sum;               // local inclusive
        }
        sh[threadIdx.x] = sum;
        __syncthreads();
        for (int off = 1; off < 1024; off <<= 1) {
            int t = (threadIdx.x >= (unsigned)off) ? sh[threadIdx.x - off] : 0;
            __syncthreads();
            sh[threadIdx.x] += t;
            __syncthreads();
        }
        int excl = sh[threadIdx.x] - sum + carry_sh;
        #pragma unroll
        for (int j = 0; j < 8; ++j) {
            int i = i0 + j;
            if (i < n) rowstart[i + 1] = excl + vals[j];
        }
        __syncthreads();
        if (threadIdx.x == 0) carry_sh += sh[1023];
        __syncthreads();
    }
}

__global__ void scatter_kernel(const int* __restrict__ src, const int* __restrict__ dst,
                               const int* __restrict__ rowstart, int* __restrict__ cursor,
                               int* __restrict__ csr, int E, int n) {
    int i = blockIdx.x * blockDim.x + threadIdx.x;
    if (i >= E + n) return;
    int s, d;
    if (i < E) { s = src[i]; d = dst[i]; }
    else       { s = d = i - E; }          // self loop
    int p = atomicAdd(&cursor[d], 1);
    csr[rowstart[d] + p] = s;
}

// ---------------- fp32 GEMM: C[M,Nc] = A[M,K] @ B[K,Nc] ----------------
// Tile 128x64, 256 threads, 8x4 microtile. K % 16 == 0 (128 or 256).

__global__ __launch_bounds__(256) void gemm_kernel(const float* __restrict__ A,
                                                   const float* __restrict__ B,
                                                   float* __restrict__ C,
                                                   int M, int K, int Nc) {
    __shared__ float As[16][136];   // 128 + 8 pad, 16B-aligned rows
    __shared__ float Bs[16][64];
    int tid = threadIdx.x;
    int row0 = blockIdx.y * 128;
    int col0 = blockIdx.x * 64;
    int tx = tid & 15, ty = tid >> 4;

    float acc[8][4];
    #pragma unroll
    for (int i = 0; i < 8; ++i)
        #pragma unroll
        for (int j = 0; j < 4; ++j) acc[i][j] = 0.f;

    for (int k0 = 0; k0 < K; k0 += 16) {
        #pragma unroll
        for (int i = 0; i < 8; ++i) {          // 128x16 A tile
            int idx = tid + i * 256;
            int r = idx >> 4, kk = idx & 15;
            int gr = row0 + r;
            As[kk][r] = (gr < M) ? A[(size_t)gr * K + k0 + kk] : 0.f;
        }
        #pragma unroll
        for (int i = 0; i < 4; ++i) {          // 16x64 B tile
            int idx = tid + i * 256;
            int kk = idx >> 6, c = idx & 63;
            int gc = col0 + c;
            Bs[kk][c] = (gc < Nc) ? B[(size_t)(k0 + kk) * Nc + gc] : 0.f;
        }
        __syncthreads();
        #pragma unroll
        for (int kk = 0; kk < 16; ++kk) {
            float4 a0 = *(const float4*)&As[kk][ty * 8];
            float4 a1 = *(const float4*)&As[kk][ty * 8 + 4];
            float4 b  = *(const float4*)&Bs[kk][tx * 4];
            float av[8] = {a0.x, a0.y, a0.z, a0.w, a1.x, a1.y, a1.z, a1.w};
            float bv[4] = {b.x, b.y, b.z, b.w};
            #pragma unroll
            for (int i = 0; i < 8; ++i)
                #pragma unroll
                for (int j = 0; j < 4; ++j) acc[i][j] += av[i] * bv[j];
        }
        __syncthreads();
    }
    #pragma unroll
    for (int i = 0; i < 8; ++i) {
        int gr = row0 + ty * 8 + i;
        if (gr >= M) continue;
        #pragma unroll
        for (int j = 0; j < 4; ++j) {
            int gc = col0 + tx * 4 + j;
            if (gc < Nc) C[(size_t)gr * Nc + gc] = acc[i][j];
        }
    }
}

// ---------------- per-node attention coefficients (8 heads) ----------------

__global__ void node_alphas_kernel(const float* __restrict__ h,
                                   const float* __restrict__ a_s, const float* __restrict__ a_d,
                                   float* __restrict__ als, float* __restrict__ ald, int n) {
    int t = blockIdx.x * blockDim.x + threadIdx.x;
    if (t >= n * 8) return;
    int d = t >> 3, hh = t & 7;
    const float* hp  = h + (size_t)d * 256 + hh * 32;
    const float* asp = a_s + hh * 32;
    const float* adp = a_d + hh * 32;
    float ss = 0.f, sd = 0.f;
    #pragma unroll
    for (int c = 0; c < 32; ++c) {
        float v = hp[c];
        ss += v * asp[c];
        sd += v * adp[c];
    }
    als[t] = ss;
    ald[t] = sd;
}

// ---------------- GAT aggregation (8 heads x 32 ch), one wave per dst ------

__global__ __launch_bounds__(256) void gat_aggregate_kernel(
        const float* __restrict__ h, const float* __restrict__ als, const float* __restrict__ ald,
        const int* __restrict__ rowstart, const int* __restrict__ csr,
        const float* __restrict__ bias, float* __restrict__ out, int n, int elu) {
    int wid  = blockIdx.x * 4 + (threadIdx.x >> 6);
    int lane = threadIdx.x & 63;
    if (wid >= n) return;
    int d = wid;
    int row = rowstart[d];
    int deg = rowstart[d + 1] - row;

    // pass 1: online softmax stats, lane = esub*8 + head
    int hh = lane & 7, esub = lane >> 3;
    float adv = ald[d * 8 + hh];
    float mx = -1e30f, sm = 0.f;
    for (int base = 0; base < deg; base += 8) {
        int e = base + esub;
        if (e < deg) {
            int s = csr[row + e];
            float v = als[s * 8 + hh] + adv;
            v = (v > 0.f) ? v : NEG_SLOPE * v;
            float nm = fmaxf(mx, v);
            sm = sm * __expf(mx - nm) + __expf(v - nm);
            mx = nm;
        }
    }
    #pragma unroll
    for (int off = 8; off < 64; off <<= 1) {
        float om = __shfl_xor(mx, off);
        float os = __shfl_xor(sm, off);
        float nm = fmaxf(mx, om);
        sm = sm * __expf(mx - nm) + os * __expf(om - nm);
        mx = nm;
    }
    // pass 2: lane owns head lane>>3, channels (lane&7)*4 .. +3  (== lane*4 flat)
    int hp = lane >> 3;
    float m2  = __shfl(mx, hp);
    float den = __shfl(sm, hp);
    float inv = 1.f / (den + 1e-16f);
    float adv2 = ald[d * 8 + hp];
    int chbase = lane * 4;
    float4 acc = {0.f, 0.f, 0.f, 0.f};
    for (int e = 0; e < deg; ++e) {
        int s = csr[row + e];
        float v = als[s * 8 + hp] + adv2;
        v = (v > 0.f) ? v : NEG_SLOPE * v;
        float w = __expf(v - m2) * inv;
        float4 hv = *(const float4*)(h + (size_t)s * 256 + chbase);
        acc.x += w * hv.x; acc.y += w * hv.y; acc.z += w * hv.z; acc.w += w * hv.w;
    }
    acc.x += bias[chbase]; acc.y += bias[chbase + 1];
    acc.z += bias[chbase + 2]; acc.w += bias[chbase + 3];
    if (elu) {
        acc.x = (acc.x > 0.f) ? acc.x : __expf(acc.x) - 1.f;
        acc.y = (acc.y > 0.f) ? acc.y : __expf(acc.y) - 1.f;
        acc.z = (acc.z > 0.f) ? acc.z : __expf(acc.z) - 1.f;
        acc.w = (acc.w > 0.f) ? acc.w : __expf(acc.w) - 1.f;
    }
    *(float4*)(out + (size_t)d * 256 + chbase) = acc;
}

// ---------------- task-head packing & alphas ----------------

__global__ void pack_w_kernel(const float* __restrict__ wTL, const float* __restrict__ wYL,
                              const float* __restrict__ wTS, const float* __restrict__ wTZ,
                              const float* __restrict__ bTL, const float* __restrict__ bYL,
                              const float* __restrict__ bTS, const float* __restrict__ bTZ,
                              float* __restrict__ Wcat, float* __restrict__ bcat) {
    int idx = blockIdx.x * blockDim.x + threadIdx.x;
    if (idx < 256 * 222) {
        int r = idx / 222, c = idx % 222;
        float v;
        if (c < 12)       v = wTL[r * 12 + c];
        else if (c < 42)  v = wYL[r * 30 + (c - 12)];
        else if (c < 102) v = wTS[r * 60 + (c - 42)];
        else              v = wTZ[r * 120 + (c - 102)];
        Wcat[idx] = v;
    }
    if (idx < 222) {
        bcat[idx] = (idx < 12) ? bTL[idx] : (idx < 42) ? bYL[idx - 12]
                  : (idx < 102) ? bTS[idx - 42] : bTZ[idx - 102];
    }
}

__global__ void task_alphas_kernel(const float* __restrict__ ht,
        const float* __restrict__ asTL, const float* __restrict__ adTL,
        const float* __restrict__ asYL, const float* __restrict__ adYL,
        const float* __restrict__ asTS, const float* __restrict__ adTS,
        const float* __restrict__ asTZ, const float* __restrict__ adTZ,
        float* __restrict__ ast, float* __restrict__ adt, int n) {
    int t = blockIdx.x * blockDim.x + threadIdx.x;
    if (t >= n * 4) return;
    int d = t >> 2, task = t & 3;
    const int CO[4] = {0, 12, 42, 102};
    const int CL[4] = {12, 30, 60, 120};
    const float* av; const float* dv;
    switch (task) {
        case 0: av = asTL; dv = adTL; break;
        case 1: av = asYL; dv = adYL; break;
        case 2: av = asTS; dv = adTS; break;
        default: av = asTZ; dv = adTZ; break;
    }
    const float* hp = ht + (size_t)d * 222 + CO[task];
    float ss = 0.f, sd = 0.f;
    for (int c = 0; c < CL[task]; ++c) {
        float v = hp[c];
        ss += v * av[c];
        sd += v * dv[c];
    }
    ast[t] = ss;
    adt[t] = sd;
}

// ---------------- 4-task aggregation (channels 12|30|60|120 = 222) --------

__global__ __launch_bounds__(256) void task_aggregate_kernel(
        const float* __restrict__ ht, const float* __restrict__ ast, const float* __restrict__ adt,
        const int* __restrict__ rowstart, const int* __restrict__ csr,
        const float* __restrict__ bcat, float* __restrict__ agg, int n) {
    int wid  = blockIdx.x * 4 + (threadIdx.x >> 6);
    int lane = threadIdx.x & 63;
    if (wid >= n) return;
    int d = wid;
    int row = rowstart[d];
    int deg = rowstart[d + 1] - row;

    // pass 1: lane = esub*4 + task
    int t = lane & 3, esub = lane >> 2;
    float adv = adt[d * 4 + t];
    float mx = -1e30f, sm = 0.f;
    for (int base = 0; base < deg; base += 16) {
        int e = base + esub;
        if (e < deg) {
            int s = csr[row + e];
            float v = ast[s * 4 + t] + adv;
            v = (v > 0.f) ? v : NEG_SLOPE * v;
            float nm = fmaxf(mx, v);
            sm = sm * __expf(mx - nm) + __expf(v - nm);
            mx = nm;
        }
    }
    #pragma unroll
    for (int off = 4; off < 64; off <<= 1) {
        float om = __shfl_xor(mx, off);
        float os = __shfl_xor(sm, off);
        float nm = fmaxf(mx, om);
        sm = sm * __expf(mx - nm) + os * __expf(om - nm);
        mx = nm;
    }
    float mt[4], idt[4], advv[4];
    #pragma unroll
    for (int tt = 0; tt < 4; ++tt) {
        mt[tt] = __shfl(mx, tt);
        float dd = __shfl(sm, tt);
        idt[tt] = 1.f / (dd + 1e-16f);
        advv[tt] = adt[d * 4 + tt];
    }
    // pass 2: lane owns flat channels lane*4 .. +3 of 222
    int ch0 = lane * 4;
    float acc[4] = {0.f, 0.f, 0.f, 0.f};
    int tj[4]; bool valj[4];
    #pragma unroll
    for (int j = 0; j < 4; ++j) {
        int ch = ch0 + j;
        valj[j] = (ch < 222);
        tj[j] = (ch >= 102) ? 3 : (ch >= 42) ? 2 : (ch >= 12) ? 1 : 0;
    }
    for (int e = 0; e < deg; ++e) {
        int s = csr[row + e];
        float w[4];
        #pragma unroll
        for (int tt = 0; tt < 4; ++tt) {
            float v = ast[s * 4 + tt] + advv[tt];
            v = (v > 0.f) ? v : NEG_SLOPE * v;
            w[tt] = __expf(v - mt[tt]) * idt[tt];
        }
        const float* hs = ht + (size_t)s * 222;
        #pragma unroll
        for (int j = 0; j < 4; ++j)
            if (valj[j]) acc[j] += w[tj[j]] * hs[ch0 + j];
    }
    #pragma unroll
    for (int j = 0; j < 4; ++j) {
        int ch = ch0 + j;
        if (ch < 222) agg[(size_t)d * 222 + ch] = acc[j] + bcat[ch];
    }
}

// ---------------- log_softmax over each task segment ----------------

__global__ __launch_bounds__(256) void logsoftmax_kernel(const float* __restrict__ agg,
                                                         float* __restrict__ out, int n) {
    int wid  = blockIdx.x * 4 + (threadIdx.x >> 6);
    int lane = threadIdx.x & 63;
    if (wid >= n) return;
    const int CO[4] = {0, 12, 42, 102};
    const int CL[4] = {12, 30, 60, 120};
    const float* a = agg + (size_t)wid * 222;
    #pragma unroll
    for (int t = 0; t < 4; ++t) {
        int c = CL[t];
        float v0 = (lane < c)      ? a[CO[t] + lane]      : -1e30f;
        float v1 = (lane + 64 < c) ? a[CO[t] + lane + 64] : -1e30f;
        float mx = fmaxf(v0, v1);
        #pragma unroll
        for (int off = 1; off < 64; off <<= 1) mx = fmaxf(mx, __shfl_xor(mx, off));
        float s = ((lane < c) ? __expf(v0 - mx) : 0.f) +
                  ((lane + 64 < c) ? __expf(v1 - mx) : 0.f);
        #pragma unroll
        for (int off = 1; off < 64; off <<= 1) s += __shfl_xor(s, off);
        float lse = mx + __logf(s);
        float* op = out + (size_t)CO[t] * n + (size_t)wid * c;
        if (lane < c)      op[lane]      = v0 - lse;
        if (lane + 64 < c) op[lane + 64] = v1 - lse;
    }
}

// ---------------- launcher ----------------

extern "C" void kernel_launch(void* const* d_in, const int* in_sizes, int n_in,
                              void* d_out, int out_size, void* d_ws, size_t ws_size,
                              hipStream_t stream) {
    const float* x   = (const float*)d_in[0];
    const int*   ei  = (const int*)d_in[1];
    const float* W1  = (const float*)d_in[2];
    const float* a1s = (const float*)d_in[3];
    const float* a1d = (const float*)d_in[4];
    const float* b1  = (const float*)d_in[5];
    const float* W2  = (const float*)d_in[6];
    const float* a2s = (const float*)d_in[7];
    const float* a2d = (const float*)d_in[8];
    const float* b2  = (const float*)d_in[9];
    const float* W_TL = (const float*)d_in[10]; const float* as_TL = (const float*)d_in[11];
    const float* ad_TL = (const float*)d_in[12]; const float* b_TL = (const float*)d_in[13];
    const float* W_YL = (const float*)d_in[14]; const float* as_YL = (const float*)d_in[15];
    const float* ad_YL = (const float*)d_in[16]; const float* b_YL = (const float*)d_in[17];
    const float* W_TS = (const float*)d_in[18]; const float* as_TS = (const float*)d_in[19];
    const float* ad_TS = (const float*)d_in[20]; const float* b_TS = (const float*)d_in[21];
    const float* W_TZ = (const float*)d_in[22]; const float* as_TZ = (const float*)d_in[23];
    const float* ad_TZ = (const float*)d_in[24]; const float* b_TZ = (const float*)d_in[25];

    const int N = in_sizes[0] / 128;
    const int E = in_sizes[1] / 2;
    const int* e_src = ei;
    const int* e_dst = ei + E;

    float* ws = (float*)d_ws;
    float* B1   = ws;                      // N*256 : h1 gemm; later ht (N*222)
    float* B2   = B1 + (size_t)N * 256;    // N*256 : conv1 out (ELU); later conv2 out
    float* B3   = B2 + (size_t)N * 256;    // N*256 : h2 gemm; later task agg (N*222)
    float* as1  = B3 + (size_t)N * 256;    // N*8
    float* ad1  = as1 + (size_t)N * 8;
    float* as2  = ad1 + (size_t)N * 8;
    float* ad2  = as2 + (size_t)N * 8;
    float* ast  = ad2 + (size_t)N * 8;     // N*4
    float* adt  = ast + (size_t)N * 4;
    float* Wcat = adt + (size_t)N * 4;     // 256*222
    float* bcat = Wcat + 256 * 222;        // 222 (+2 pad)
    int* deg      = (int*)(bcat + 224);    // N
    int* rowstart = deg + N;               // N+1
    int* cursor   = rowstart + (N + 1);    // N
    int* csr      = cursor + N;            // E+N

    float* out = (float*)d_out;

    const int B = 256;
    // --- CSR build ---
    init_kernel<<<(N + B - 1) / B, B, 0, stream>>>(deg, cursor, N);
    count_kernel<<<(E + B - 1) / B, B, 0, stream>>>(e_dst, deg, E);
    scan_kernel<<<1, 1024, 0, stream>>>(deg, rowstart, N);
    scatter_kernel<<<(E + N + B - 1) / B, B, 0, stream>>>(e_src, e_dst, rowstart, cursor, csr, E, N);
    // --- pack task weights (independent of graph) ---
    pack_w_kernel<<<(256 * 222 + B - 1) / B, B, 0, stream>>>(W_TL, W_YL, W_TS, W_TZ,
                                                             b_TL, b_YL, b_TS, b_TZ, Wcat, bcat);
    // --- conv1 ---
    {
        dim3 g((256 + 63) / 64, (N + 127) / 128);
        gemm_kernel<<<g, 256, 0, stream>>>(x, W1, B1, N, 128, 256);
    }
    node_alphas_kernel<<<(N * 8 + B - 1) / B, B, 0, stream>>>(B1, a1s, a1d, as1, ad1, N);
    gat_aggregate_kernel<<<(N + 3) / 4, 256, 0, stream>>>(B1, as1, ad1, rowstart, csr, b1, B2, N, 1);
    // --- conv2 ---
    {
        dim3 g((256 + 63) / 64, (N + 127) / 128);
        gemm_kernel<<<g, 256, 0, stream>>>(B2, W2, B3, N, 256, 256);
    }
    node_alphas_kernel<<<(N * 8 + B - 1) / B, B, 0, stream>>>(B3, a2s, a2d, as2, ad2, N);
    gat_aggregate_kernel<<<(N + 3) / 4, 256, 0, stream>>>(B3, as2, ad2, rowstart, csr, b2, B2, N, 0);
    // --- task heads (fused GEMM over concat 222 cols) ---
    {
        dim3 g((222 + 63) / 64, (N + 127) / 128);
        gemm_kernel<<<g, 256, 0, stream>>>(B2, Wcat, B1, N, 256, 222);
    }
    task_alphas_kernel<<<(N * 4 + B - 1) / B, B, 0, stream>>>(B1, as_TL, ad_TL, as_YL, ad_YL,
                                                              as_TS, ad_TS, as_TZ, ad_TZ, ast, adt, N);
    task_aggregate_kernel<<<(N + 3) / 4, 256, 0, stream>>>(B1, ast, adt, rowstart, csr, bcat, B3, N);
    logsoftmax_kernel<<<(N + 3) / 4, 256, 0, stream>>>(B3, out, N);
}

// Round 2
// 1277.462 us; speedup vs baseline: 1.0322x; 1.0322x over previous
//
#include <hip/hip_runtime.h>
#include <math.h>

// ---------------------------------------------------------------------------
// MultiTaskGAT: 2x GATConv(8 heads x 32ch, concat) + 4 task heads (1 head)
// N=50000 nodes, E=800000 edges (+N self loops), F_IN=128, DH=256.
//
// R2: softmax restructured. out = (sum_e w_e * h_src) / (sum_e w_e) with
// unnormalized w = exp(leaky(...)) — max-subtraction dropped (logits are
// O(10), exp fits fp32 easily; result identical to stable softmax).
// Weights precomputed once per edge (coalesced, CSR slot order); gather
// kernels are single-pass with no transcendentals in the loop.
// ---------------------------------------------------------------------------

#define NEG_SLOPE 0.2f

// ---------------- CSR build ----------------

__global__ void init_kernel(int* __restrict__ deg, int* __restrict__ cursor, int n) {
    int i = blockIdx.x * blockDim.x + threadIdx.x;
    if (i < n) { deg[i] = 1; cursor[i] = 0; }   // deg starts at 1: self loop
}

__global__ void count_kernel(const int* __restrict__ dst, int* __restrict__ deg, int E) {
    int i = blockIdx.x * blockDim.x + threadIdx.x;
    if (i < E) atomicAdd(&deg[dst[i]], 1);
}

__global__ __launch_bounds__(1024) void scan_kernel(const int* __restrict__ deg,
                                                    int* __restrict__ rowstart, int n) {
    __shared__ int sh[1024];
    __shared__ int carry_sh;
    if (threadIdx.x == 0) { carry_sh = 0; rowstart[0] = 0; }
    __syncthreads();
    for (int base = 0; base < n; base += 8192) {
        int vals[8];
        int sum = 0;
        int i0 = base + threadIdx.x * 8;
        #pragma unroll
        for (int j = 0; j < 8; ++j) {
            int i = i0 + j;
            int v = (i < n) ? deg[i] : 0;
            sum += v;
            vals[j] = sum;               // local inclusive
        }
        sh[threadIdx.x] = sum;
        __syncthreads();
        for (int off = 1; off < 1024; off <<= 1) {
            int t = (threadIdx.x >= (unsigned)off) ? sh[threadIdx.x - off] : 0;
            __syncthreads();
            sh[threadIdx.x] += t;
            __syncthreads();
        }
        int excl = sh[threadIdx.x] - sum + carry_sh;
        #pragma unroll
        for (int j = 0; j < 8; ++j) {
            int i = i0 + j;
            if (i < n) rowstart[i + 1] = excl + vals[j];
        }
        __syncthreads();
        if (threadIdx.x == 0) carry_sh += sh[1023];
        __syncthreads();
    }
}

__global__ void scatter_kernel(const int* __restrict__ src, const int* __restrict__ dst,
                               const int* __restrict__ rowstart, int* __restrict__ cursor,
                               int* __restrict__ csr, int* __restrict__ csrd, int E, int n) {
    int i = blockIdx.x * blockDim.x + threadIdx.x;
    if (i >= E + n) return;
    int s, d;
    if (i < E) { s = src[i]; d = dst[i]; }
    else       { s = d = i - E; }          // self loop
    int p = atomicAdd(&cursor[d], 1);
    int slot = rowstart[d] + p;
    csr[slot] = s;
    csrd[slot] = d;
}

// ---------------- fp32 GEMM: C[M,Nc] = A[M,K] @ B[K,Nc] ----------------
// Tile 128x64, 256 threads, 8x4 microtile. K % 16 == 0 (128 or 256).

__global__ __launch_bounds__(256) void gemm_kernel(const float* __restrict__ A,
                                                   const float* __restrict__ B,
                                                   float* __restrict__ C,
                                                   int M, int K, int Nc) {
    __shared__ float As[16][136];   // 128 + 8 pad
    __shared__ float Bs[16][64];
    int tid = threadIdx.x;
    int row0 = blockIdx.y * 128;
    int col0 = blockIdx.x * 64;
    int tx = tid & 15, ty = tid >> 4;

    float acc[8][4];
    #pragma unroll
    for (int i = 0; i < 8; ++i)
        #pragma unroll
        for (int j = 0; j < 4; ++j) acc[i][j] = 0.f;

    for (int k0 = 0; k0 < K; k0 += 16) {
        #pragma unroll
        for (int i = 0; i < 8; ++i) {          // 128x16 A tile
            int idx = tid + i * 256;
            int r = idx >> 4, kk = idx & 15;
            int gr = row0 + r;
            As[kk][r] = (gr < M) ? A[(size_t)gr * K + k0 + kk] : 0.f;
        }
        #pragma unroll
        for (int i = 0; i < 4; ++i) {          // 16x64 B tile
            int idx = tid + i * 256;
            int kk = idx >> 6, c = idx & 63;
            int gc = col0 + c;
            Bs[kk][c] = (gc < Nc) ? B[(size_t)(k0 + kk) * Nc + gc] : 0.f;
        }
        __syncthreads();
        #pragma unroll
        for (int kk = 0; kk < 16; ++kk) {
            float4 a0 = *(const float4*)&As[kk][ty * 8];
            float4 a1 = *(const float4*)&As[kk][ty * 8 + 4];
            float4 b  = *(const float4*)&Bs[kk][tx * 4];
            float av[8] = {a0.x, a0.y, a0.z, a0.w, a1.x, a1.y, a1.z, a1.w};
            float bv[4] = {b.x, b.y, b.z, b.w};
            #pragma unroll
            for (int i = 0; i < 8; ++i)
                #pragma unroll
                for (int j = 0; j < 4; ++j) acc[i][j] += av[i] * bv[j];
        }
        __syncthreads();
    }
    #pragma unroll
    for (int i = 0; i < 8; ++i) {
        int gr = row0 + ty * 8 + i;
        if (gr >= M) continue;
        #pragma unroll
        for (int j = 0; j < 4; ++j) {
            int gc = col0 + tx * 4 + j;
            if (gc < Nc) C[(size_t)gr * Nc + gc] = acc[i][j];
        }
    }
}

// ---------------- per-node attention coefficients (8 heads) ----------------

__global__ void node_alphas_kernel(const float* __restrict__ h,
                                   const float* __restrict__ a_s, const float* __restrict__ a_d,
                                   float* __restrict__ als, float* __restrict__ ald, int n) {
    int t = blockIdx.x * blockDim.x + threadIdx.x;
    if (t >= n * 8) return;
    int d = t >> 3, hh = t & 7;
    const float* hp  = h + (size_t)d * 256 + hh * 32;
    const float* asp = a_s + hh * 32;
    const float* adp = a_d + hh * 32;
    float ss = 0.f, sd = 0.f;
    #pragma unroll
    for (int c = 0; c < 32; ++c) {
        float v = hp[c];
        ss += v * asp[c];
        sd += v * adp[c];
    }
    als[t] = ss;
    ald[t] = sd;
}

// ---------------- edge weights, 8 heads (unnormalized softmax) -------------

__global__ void ew8_kernel(const float* __restrict__ als, const float* __restrict__ ald,
                           const int* __restrict__ csr, const int* __restrict__ csrd,
                           float* __restrict__ ew, int M) {
    int i = blockIdx.x * blockDim.x + threadIdx.x;
    if (i >= M) return;
    int s = csr[i], d = csrd[i];
    const float4* ap = (const float4*)(als + (size_t)s * 8);
    const float4* dp = (const float4*)(ald + (size_t)d * 8);
    float4 a0 = ap[0], a1 = ap[1];
    float4 d0 = dp[0], d1 = dp[1];
    float v[8] = {a0.x + d0.x, a0.y + d0.y, a0.z + d0.z, a0.w + d0.w,
                  a1.x + d1.x, a1.y + d1.y, a1.z + d1.z, a1.w + d1.w};
    float w[8];
    #pragma unroll
    for (int h = 0; h < 8; ++h) {
        float x = v[h];
        x = (x > 0.f) ? x : NEG_SLOPE * x;
        w[h] = __expf(x);
    }
    float4* op = (float4*)(ew + (size_t)i * 8);
    op[0] = make_float4(w[0], w[1], w[2], w[3]);
    op[1] = make_float4(w[4], w[5], w[6], w[7]);
}

// ---------------- GAT gather (8 heads x 32 ch), one wave per dst -----------
// lane owns head lane>>3, flat channels lane*4 .. +3. Single pass, no exp.

__global__ __launch_bounds__(256) void gat_gather_kernel(
        const float* __restrict__ h, const float* __restrict__ ew,
        const int* __restrict__ rowstart, const int* __restrict__ csr,
        const float* __restrict__ bias, float* __restrict__ out, int n, int elu) {
    int wid  = blockIdx.x * 4 + (threadIdx.x >> 6);
    int lane = threadIdx.x & 63;
    if (wid >= n) return;
    int row = rowstart[wid];
    int deg = rowstart[wid + 1] - row;
    int hp = lane >> 3;
    int ch = lane * 4;
    const int* cp = csr + row;
    const float* wp = ew + (size_t)row * 8 + hp;

    float4 acc = {0.f, 0.f, 0.f, 0.f};
    float wsum = 0.f;
    int e = 0;
    for (; e + 2 <= deg; e += 2) {
        int s0 = cp[e], s1 = cp[e + 1];
        float w0 = wp[(size_t)e * 8];
        float w1 = wp[(size_t)(e + 1) * 8];
        float4 h0 = *(const float4*)(h + (size_t)s0 * 256 + ch);
        float4 h1 = *(const float4*)(h + (size_t)s1 * 256 + ch);
        acc.x += w0 * h0.x + w1 * h1.x;
        acc.y += w0 * h0.y + w1 * h1.y;
        acc.z += w0 * h0.z + w1 * h1.z;
        acc.w += w0 * h0.w + w1 * h1.w;
        wsum += w0 + w1;
    }
    if (e < deg) {
        int s0 = cp[e];
        float w0 = wp[(size_t)e * 8];
        float4 h0 = *(const float4*)(h + (size_t)s0 * 256 + ch);
        acc.x += w0 * h0.x; acc.y += w0 * h0.y;
        acc.z += w0 * h0.z; acc.w += w0 * h0.w;
        wsum += w0;
    }
    float inv = 1.f / (wsum + 1e-16f);
    float4 b4 = *(const float4*)(bias + ch);
    acc.x = acc.x * inv + b4.x;
    acc.y = acc.y * inv + b4.y;
    acc.z = acc.z * inv + b4.z;
    acc.w = acc.w * inv + b4.w;
    if (elu) {
        acc.x = (acc.x > 0.f) ? acc.x : __expf(acc.x) - 1.f;
        acc.y = (acc.y > 0.f) ? acc.y : __expf(acc.y) - 1.f;
        acc.z = (acc.z > 0.f) ? acc.z : __expf(acc.z) - 1.f;
        acc.w = (acc.w > 0.f) ? acc.w : __expf(acc.w) - 1.f;
    }
    *(float4*)(out + (size_t)wid * 256 + ch) = acc;
}

// ---------------- task-head packing & alphas ----------------

__global__ void pack_w_kernel(const float* __restrict__ wTL, const float* __restrict__ wYL,
                              const float* __restrict__ wTS, const float* __restrict__ wTZ,
                              const float* __restrict__ bTL, const float* __restrict__ bYL,
                              const float* __restrict__ bTS, const float* __restrict__ bTZ,
                              float* __restrict__ Wcat, float* __restrict__ bcat) {
    int idx = blockIdx.x * blockDim.x + threadIdx.x;
    if (idx < 256 * 222) {
        int r = idx / 222, c = idx % 222;
        float v;
        if (c < 12)       v = wTL[r * 12 + c];
        else if (c < 42)  v = wYL[r * 30 + (c - 12)];
        else if (c < 102) v = wTS[r * 60 + (c - 42)];
        else              v = wTZ[r * 120 + (c - 102)];
        Wcat[idx] = v;
    }
    if (idx < 222) {
        bcat[idx] = (idx < 12) ? bTL[idx] : (idx < 42) ? bYL[idx - 12]
                  : (idx < 102) ? bTS[idx - 42] : bTZ[idx - 102];
    }
}

__global__ void task_alphas_kernel(const float* __restrict__ ht,
        const float* __restrict__ asTL, const float* __restrict__ adTL,
        const float* __restrict__ asYL, const float* __restrict__ adYL,
        const float* __restrict__ asTS, const float* __restrict__ adTS,
        const float* __restrict__ asTZ, const float* __restrict__ adTZ,
        float* __restrict__ ast, float* __restrict__ adt, int n) {
    int t = blockIdx.x * blockDim.x + threadIdx.x;
    if (t >= n * 4) return;
    int d = t >> 2, task = t & 3;
    const int CO[4] = {0, 12, 42, 102};
    const int CL[4] = {12, 30, 60, 120};
    const float* av; const float* dv;
    switch (task) {
        case 0: av = asTL; dv = adTL; break;
        case 1: av = asYL; dv = adYL; break;
        case 2: av = asTS; dv = adTS; break;
        default: av = asTZ; dv = adTZ; break;
    }
    const float* hp = ht + (size_t)d * 222 + CO[task];
    float ss = 0.f, sd = 0.f;
    for (int c = 0; c < CL[task]; ++c) {
        float v = hp[c];
        ss += v * av[c];
        sd += v * dv[c];
    }
    ast[t] = ss;
    adt[t] = sd;
}

// ---------------- edge weights, 4 tasks ----------------

__global__ void ew4_kernel(const float* __restrict__ ast, const float* __restrict__ adt,
                           const int* __restrict__ csr, const int* __restrict__ csrd,
                           float* __restrict__ ew, int M) {
    int i = blockIdx.x * blockDim.x + threadIdx.x;
    if (i >= M) return;
    int s = csr[i], d = csrd[i];
    float4 a = *(const float4*)(ast + (size_t)s * 4);
    float4 b = *(const float4*)(adt + (size_t)d * 4);
    float v[4] = {a.x + b.x, a.y + b.y, a.z + b.z, a.w + b.w};
    float w[4];
    #pragma unroll
    for (int t = 0; t < 4; ++t) {
        float x = v[t];
        x = (x > 0.f) ? x : NEG_SLOPE * x;
        w[t] = __expf(x);
    }
    *(float4*)(ew + (size_t)i * 4) = make_float4(w[0], w[1], w[2], w[3]);
}

// ---------------- 4-task gather (channels 12|30|60|120 = 222) --------------
// lane owns flat channels lane*4..+3; each lane touches at most 2 tasks
// (t_lo for j < split, t_hi after). Single pass, normalize at the end.

__global__ __launch_bounds__(256) void task_gather_kernel(
        const float* __restrict__ ht, const float* __restrict__ ew,
        const int* __restrict__ rowstart, const int* __restrict__ csr,
        const float* __restrict__ bcat, float* __restrict__ agg, int n) {
    int wid  = blockIdx.x * 4 + (threadIdx.x >> 6);
    int lane = threadIdx.x & 63;
    if (wid >= n) return;
    int row = rowstart[wid];
    int deg = rowstart[wid + 1] - row;
    int ch0 = lane * 4;

    int tj[4]; bool valj[4];
    #pragma unroll
    for (int j = 0; j < 4; ++j) {
        int ch = ch0 + j;
        valj[j] = (ch < 222);
        tj[j] = (ch >= 102) ? 3 : (ch >= 42) ? 2 : (ch >= 12) ? 1 : 0;
    }
    int t_lo = tj[0], t_hi = tj[3];
    bool use_lo[4];
    #pragma unroll
    for (int j = 0; j < 4; ++j) use_lo[j] = (tj[j] == t_lo);

    const int* cp = csr + row;
    const float* wp = ew + (size_t)row * 4;

    float acc[4] = {0.f, 0.f, 0.f, 0.f};
    float ws_lo = 0.f, ws_hi = 0.f;
    for (int e = 0; e < deg; ++e) {
        int s = cp[e];
        float wlo = wp[(size_t)e * 4 + t_lo];
        float whi = wp[(size_t)e * 4 + t_hi];
        ws_lo += wlo; ws_hi += whi;
        const float* hs = ht + (size_t)s * 222 + ch0;
        #pragma unroll
        for (int j = 0; j < 4; ++j) {
            float w = use_lo[j] ? wlo : whi;
            if (valj[j]) acc[j] += w * hs[j];
        }
    }
    float inv_lo = 1.f / (ws_lo + 1e-16f);
    float inv_hi = 1.f / (ws_hi + 1e-16f);
    #pragma unroll
    for (int j = 0; j < 4; ++j) {
        int ch = ch0 + j;
        if (ch < 222)
            agg[(size_t)wid * 222 + ch] = acc[j] * (use_lo[j] ? inv_lo : inv_hi) + bcat[ch];
    }
}

// ---------------- log_softmax over each task segment ----------------

__global__ __launch_bounds__(256) void logsoftmax_kernel(const float* __restrict__ agg,
                                                         float* __restrict__ out, int n) {
    int wid  = blockIdx.x * 4 + (threadIdx.x >> 6);
    int lane = threadIdx.x & 63;
    if (wid >= n) return;
    const int CO[4] = {0, 12, 42, 102};
    const int CL[4] = {12, 30, 60, 120};
    const float* a = agg + (size_t)wid * 222;
    #pragma unroll
    for (int t = 0; t < 4; ++t) {
        int c = CL[t];
        float v0 = (lane < c)      ? a[CO[t] + lane]      : -1e30f;
        float v1 = (lane + 64 < c) ? a[CO[t] + lane + 64] : -1e30f;
        float mx = fmaxf(v0, v1);
        #pragma unroll
        for (int off = 1; off < 64; off <<= 1) mx = fmaxf(mx, __shfl_xor(mx, off));
        float s = ((lane < c) ? __expf(v0 - mx) : 0.f) +
                  ((lane + 64 < c) ? __expf(v1 - mx) : 0.f);
        #pragma unroll
        for (int off = 1; off < 64; off <<= 1) s += __shfl_xor(s, off);
        float lse = mx + __logf(s);
        float* op = out + (size_t)CO[t] * n + (size_t)wid * c;
        if (lane < c)      op[lane]      = v0 - lse;
        if (lane + 64 < c) op[lane + 64] = v1 - lse;
    }
}

// ---------------- launcher ----------------

extern "C" void kernel_launch(void* const* d_in, const int* in_sizes, int n_in,
                              void* d_out, int out_size, void* d_ws, size_t ws_size,
                              hipStream_t stream) {
    const float* x   = (const float*)d_in[0];
    const int*   ei  = (const int*)d_in[1];
    const float* W1  = (const float*)d_in[2];
    const float* a1s = (const float*)d_in[3];
    const float* a1d = (const float*)d_in[4];
    const float* b1  = (const float*)d_in[5];
    const float* W2  = (const float*)d_in[6];
    const float* a2s = (const float*)d_in[7];
    const float* a2d = (const float*)d_in[8];
    const float* b2  = (const float*)d_in[9];
    const float* W_TL = (const float*)d_in[10]; const float* as_TL = (const float*)d_in[11];
    const float* ad_TL = (const float*)d_in[12]; const float* b_TL = (const float*)d_in[13];
    const float* W_YL = (const float*)d_in[14]; const float* as_YL = (const float*)d_in[15];
    const float* ad_YL = (const float*)d_in[16]; const float* b_YL = (const float*)d_in[17];
    const float* W_TS = (const float*)d_in[18]; const float* as_TS = (const float*)d_in[19];
    const float* ad_TS = (const float*)d_in[20]; const float* b_TS = (const float*)d_in[21];
    const float* W_TZ = (const float*)d_in[22]; const float* as_TZ = (const float*)d_in[23];
    const float* ad_TZ = (const float*)d_in[24]; const float* b_TZ = (const float*)d_in[25];

    const int N = in_sizes[0] / 128;
    const int E = in_sizes[1] / 2;
    const int* e_src = ei;
    const int* e_dst = ei + E;
    const int M = E + N;                   // CSR slots incl. self loops

    float* ws = (float*)d_ws;
    // Big buffers (N*256 floats each) with phase-based reuse:
    //  B1: h1 -> (gather2 out AG2) -> ew_t (task weights, 4M floats)
    //  B2: AG1 (conv1 out) -> ew2 (conv2 weights, 6.8M floats) -> ht (N*222)
    //  B3: ew1 (conv1 weights) -> h2 -> AGT (task agg out, N*222)
    float* B1   = ws;
    float* B2   = B1 + (size_t)N * 256;
    float* B3   = B2 + (size_t)N * 256;
    float* as1  = B3 + (size_t)N * 256;    // N*8
    float* ad1  = as1 + (size_t)N * 8;
    float* as2  = ad1 + (size_t)N * 8;
    float* ad2  = as2 + (size_t)N * 8;
    float* ast  = ad2 + (size_t)N * 8;     // N*4
    float* adt  = ast + (size_t)N * 4;
    float* Wcat = adt + (size_t)N * 4;     // 256*222
    float* bcat = Wcat + 256 * 222;        // 222 (+2 pad)
    int* deg      = (int*)(bcat + 224);    // N
    int* rowstart = deg + N;               // N+1
    int* cursor   = rowstart + (N + 1);    // N
    int* csr      = cursor + N;            // M (src per slot)
    int* csrd     = csr + M;               // M (dst per slot)

    float* out = (float*)d_out;

    const int B = 256;
    // --- CSR build ---
    init_kernel<<<(N + B - 1) / B, B, 0, stream>>>(deg, cursor, N);
    count_kernel<<<(E + B - 1) / B, B, 0, stream>>>(e_dst, deg, E);
    scan_kernel<<<1, 1024, 0, stream>>>(deg, rowstart, N);
    scatter_kernel<<<(M + B - 1) / B, B, 0, stream>>>(e_src, e_dst, rowstart, cursor, csr, csrd, E, N);
    // --- pack task weights ---
    pack_w_kernel<<<(256 * 222 + B - 1) / B, B, 0, stream>>>(W_TL, W_YL, W_TS, W_TZ,
                                                             b_TL, b_YL, b_TS, b_TZ, Wcat, bcat);
    // --- conv1 ---
    {
        dim3 g((256 + 63) / 64, (N + 127) / 128);
        gemm_kernel<<<g, 256, 0, stream>>>(x, W1, B1, N, 128, 256);
    }
    node_alphas_kernel<<<(N * 8 + B - 1) / B, B, 0, stream>>>(B1, a1s, a1d, as1, ad1, N);
    ew8_kernel<<<(M + B - 1) / B, B, 0, stream>>>(as1, ad1, csr, csrd, B3, M);          // ew1 in B3
    gat_gather_kernel<<<(N + 3) / 4, 256, 0, stream>>>(B1, B3, rowstart, csr, b1, B2, N, 1);
    // --- conv2 ---
    {
        dim3 g((256 + 63) / 64, (N + 127) / 128);
        gemm_kernel<<<g, 256, 0, stream>>>(B2, W2, B3, N, 256, 256);                    // h2 in B3
    }
    node_alphas_kernel<<<(N * 8 + B - 1) / B, B, 0, stream>>>(B3, a2s, a2d, as2, ad2, N);
    ew8_kernel<<<(M + B - 1) / B, B, 0, stream>>>(as2, ad2, csr, csrd, B2, M);          // ew2 in B2
    gat_gather_kernel<<<(N + 3) / 4, 256, 0, stream>>>(B3, B2, rowstart, csr, b2, B1, N, 0); // AG2 in B1
    // --- task heads (fused GEMM over concat 222 cols) ---
    {
        dim3 g((222 + 63) / 64, (N + 127) / 128);
        gemm_kernel<<<g, 256, 0, stream>>>(B1, Wcat, B2, N, 256, 222);                  // ht in B2
    }
    task_alphas_kernel<<<(N * 4 + B - 1) / B, B, 0, stream>>>(B2, as_TL, ad_TL, as_YL, ad_YL,
                                                              as_TS, ad_TS, as_TZ, ad_TZ, ast, adt, N);
    ew4_kernel<<<(M + B - 1) / B, B, 0, stream>>>(ast, adt, csr, csrd, B1, M);          // ew_t in B1
    task_gather_kernel<<<(N + 3) / 4, 256, 0, stream>>>(B2, B1, rowstart, csr, bcat, B3, N);
    logsoftmax_kernel<<<(N + 3) / 4, 256, 0, stream>>>(B3, out, N);
}

// Round 3
// 1171.914 us; speedup vs baseline: 1.1252x; 1.0901x over previous
//
#include <hip/hip_runtime.h>
#include <math.h>

// ---------------------------------------------------------------------------
// MultiTaskGAT: 2x GATConv(8 heads x 32ch, concat) + 4 task heads (1 head)
// N=50000 nodes, E=800000 edges (+N self loops), F_IN=128, DH=256.
//
// R2: unnormalized softmax (exp hoisted to edge-parallel ew kernels),
//     single-pass gathers.
// R3: gather loops unrolled x4 with explicit index/row prefetch — the R2
//     profile showed VGPR=12 / VALUBusy=12.6% / HBM 24%: pure latency bound,
//     compiler was not pipelining the dependent row-gathers. 4 outstanding
//     row loads per wave quadruples MLP.
// ---------------------------------------------------------------------------

#define NEG_SLOPE 0.2f

// ---------------- CSR build ----------------

__global__ void init_kernel(int* __restrict__ deg, int* __restrict__ cursor, int n) {
    int i = blockIdx.x * blockDim.x + threadIdx.x;
    if (i < n) { deg[i] = 1; cursor[i] = 0; }   // deg starts at 1: self loop
}

__global__ void count_kernel(const int* __restrict__ dst, int* __restrict__ deg, int E) {
    int i = blockIdx.x * blockDim.x + threadIdx.x;
    if (i < E) atomicAdd(&deg[dst[i]], 1);
}

__global__ __launch_bounds__(1024) void scan_kernel(const int* __restrict__ deg,
                                                    int* __restrict__ rowstart, int n) {
    __shared__ int sh[1024];
    __shared__ int carry_sh;
    if (threadIdx.x == 0) { carry_sh = 0; rowstart[0] = 0; }
    __syncthreads();
    for (int base = 0; base < n; base += 8192) {
        int vals[8];
        int sum = 0;
        int i0 = base + threadIdx.x * 8;
        #pragma unroll
        for (int j = 0; j < 8; ++j) {
            int i = i0 + j;
            int v = (i < n) ? deg[i] : 0;
            sum += v;
            vals[j] = sum;               // local inclusive
        }
        sh[threadIdx.x] = sum;
        __syncthreads();
        for (int off = 1; off < 1024; off <<= 1) {
            int t = (threadIdx.x >= (unsigned)off) ? sh[threadIdx.x - off] : 0;
            __syncthreads();
            sh[threadIdx.x] += t;
            __syncthreads();
        }
        int excl = sh[threadIdx.x] - sum + carry_sh;
        #pragma unroll
        for (int j = 0; j < 8; ++j) {
            int i = i0 + j;
            if (i < n) rowstart[i + 1] = excl + vals[j];
        }
        __syncthreads();
        if (threadIdx.x == 0) carry_sh += sh[1023];
        __syncthreads();
    }
}

__global__ void scatter_kernel(const int* __restrict__ src, const int* __restrict__ dst,
                               const int* __restrict__ rowstart, int* __restrict__ cursor,
                               int* __restrict__ csr, int* __restrict__ csrd, int E, int n) {
    int i = blockIdx.x * blockDim.x + threadIdx.x;
    if (i >= E + n) return;
    int s, d;
    if (i < E) { s = src[i]; d = dst[i]; }
    else       { s = d = i - E; }          // self loop
    int p = atomicAdd(&cursor[d], 1);
    int slot = rowstart[d] + p;
    csr[slot] = s;
    csrd[slot] = d;
}

// ---------------- fp32 GEMM: C[M,Nc] = A[M,K] @ B[K,Nc] ----------------

__global__ __launch_bounds__(256) void gemm_kernel(const float* __restrict__ A,
                                                   const float* __restrict__ B,
                                                   float* __restrict__ C,
                                                   int M, int K, int Nc) {
    __shared__ float As[16][136];   // 128 + 8 pad
    __shared__ float Bs[16][64];
    int tid = threadIdx.x;
    int row0 = blockIdx.y * 128;
    int col0 = blockIdx.x * 64;
    int tx = tid & 15, ty = tid >> 4;

    float acc[8][4];
    #pragma unroll
    for (int i = 0; i < 8; ++i)
        #pragma unroll
        for (int j = 0; j < 4; ++j) acc[i][j] = 0.f;

    for (int k0 = 0; k0 < K; k0 += 16) {
        #pragma unroll
        for (int i = 0; i < 8; ++i) {          // 128x16 A tile
            int idx = tid + i * 256;
            int r = idx >> 4, kk = idx & 15;
            int gr = row0 + r;
            As[kk][r] = (gr < M) ? A[(size_t)gr * K + k0 + kk] : 0.f;
        }
        #pragma unroll
        for (int i = 0; i < 4; ++i) {          // 16x64 B tile
            int idx = tid + i * 256;
            int kk = idx >> 6, c = idx & 63;
            int gc = col0 + c;
            Bs[kk][c] = (gc < Nc) ? B[(size_t)(k0 + kk) * Nc + gc] : 0.f;
        }
        __syncthreads();
        #pragma unroll
        for (int kk = 0; kk < 16; ++kk) {
            float4 a0 = *(const float4*)&As[kk][ty * 8];
            float4 a1 = *(const float4*)&As[kk][ty * 8 + 4];
            float4 b  = *(const float4*)&Bs[kk][tx * 4];
            float av[8] = {a0.x, a0.y, a0.z, a0.w, a1.x, a1.y, a1.z, a1.w};
            float bv[4] = {b.x, b.y, b.z, b.w};
            #pragma unroll
            for (int i = 0; i < 8; ++i)
                #pragma unroll
                for (int j = 0; j < 4; ++j) acc[i][j] += av[i] * bv[j];
        }
        __syncthreads();
    }
    #pragma unroll
    for (int i = 0; i < 8; ++i) {
        int gr = row0 + ty * 8 + i;
        if (gr >= M) continue;
        #pragma unroll
        for (int j = 0; j < 4; ++j) {
            int gc = col0 + tx * 4 + j;
            if (gc < Nc) C[(size_t)gr * Nc + gc] = acc[i][j];
        }
    }
}

// ---------------- per-node attention coefficients (8 heads) ----------------

__global__ void node_alphas_kernel(const float* __restrict__ h,
                                   const float* __restrict__ a_s, const float* __restrict__ a_d,
                                   float* __restrict__ als, float* __restrict__ ald, int n) {
    int t = blockIdx.x * blockDim.x + threadIdx.x;
    if (t >= n * 8) return;
    int d = t >> 3, hh = t & 7;
    const float* hp  = h + (size_t)d * 256 + hh * 32;
    const float* asp = a_s + hh * 32;
    const float* adp = a_d + hh * 32;
    float ss = 0.f, sd = 0.f;
    #pragma unroll
    for (int c = 0; c < 32; ++c) {
        float v = hp[c];
        ss += v * asp[c];
        sd += v * adp[c];
    }
    als[t] = ss;
    ald[t] = sd;
}

// ---------------- edge weights, 8 heads (unnormalized softmax) -------------

__global__ void ew8_kernel(const float* __restrict__ als, const float* __restrict__ ald,
                           const int* __restrict__ csr, const int* __restrict__ csrd,
                           float* __restrict__ ew, int M) {
    int i = blockIdx.x * blockDim.x + threadIdx.x;
    if (i >= M) return;
    int s = csr[i], d = csrd[i];
    const float4* ap = (const float4*)(als + (size_t)s * 8);
    const float4* dp = (const float4*)(ald + (size_t)d * 8);
    float4 a0 = ap[0], a1 = ap[1];
    float4 d0 = dp[0], d1 = dp[1];
    float v[8] = {a0.x + d0.x, a0.y + d0.y, a0.z + d0.z, a0.w + d0.w,
                  a1.x + d1.x, a1.y + d1.y, a1.z + d1.z, a1.w + d1.w};
    float w[8];
    #pragma unroll
    for (int h = 0; h < 8; ++h) {
        float x = v[h];
        x = (x > 0.f) ? x : NEG_SLOPE * x;
        w[h] = __expf(x);
    }
    float4* op = (float4*)(ew + (size_t)i * 8);
    op[0] = make_float4(w[0], w[1], w[2], w[3]);
    op[1] = make_float4(w[4], w[5], w[6], w[7]);
}

// ---------------- GAT gather (8 heads x 32 ch), one wave per dst -----------
// lane owns head lane>>3, flat channels lane*4 .. +3. Unroll x4 prefetch.

__global__ __launch_bounds__(256) void gat_gather_kernel(
        const float* __restrict__ h, const float* __restrict__ ew,
        const int* __restrict__ rowstart, const int* __restrict__ csr,
        const float* __restrict__ bias, float* __restrict__ out, int n, int elu) {
    int wid  = blockIdx.x * 4 + (threadIdx.x >> 6);
    int lane = threadIdx.x & 63;
    if (wid >= n) return;
    int row = rowstart[wid];
    int deg = rowstart[wid + 1] - row;
    int hp = lane >> 3;
    int ch = lane * 4;
    const int* cp = csr + row;
    const float* wp = ew + (size_t)row * 8 + hp;

    float4 acc = {0.f, 0.f, 0.f, 0.f};
    float wsum = 0.f;
    int e = 0;
    for (; e + 4 <= deg; e += 4) {
        int s0 = cp[e], s1 = cp[e + 1], s2 = cp[e + 2], s3 = cp[e + 3];
        float w0 = wp[(size_t)(e + 0) * 8];
        float w1 = wp[(size_t)(e + 1) * 8];
        float w2 = wp[(size_t)(e + 2) * 8];
        float w3 = wp[(size_t)(e + 3) * 8];
        float4 h0 = *(const float4*)(h + (size_t)s0 * 256 + ch);
        float4 h1 = *(const float4*)(h + (size_t)s1 * 256 + ch);
        float4 h2 = *(const float4*)(h + (size_t)s2 * 256 + ch);
        float4 h3 = *(const float4*)(h + (size_t)s3 * 256 + ch);
        acc.x += w0 * h0.x + w1 * h1.x + w2 * h2.x + w3 * h3.x;
        acc.y += w0 * h0.y + w1 * h1.y + w2 * h2.y + w3 * h3.y;
        acc.z += w0 * h0.z + w1 * h1.z + w2 * h2.z + w3 * h3.z;
        acc.w += w0 * h0.w + w1 * h1.w + w2 * h2.w + w3 * h3.w;
        wsum += (w0 + w1) + (w2 + w3);
    }
    for (; e < deg; ++e) {
        int s0 = cp[e];
        float w0 = wp[(size_t)e * 8];
        float4 h0 = *(const float4*)(h + (size_t)s0 * 256 + ch);
        acc.x += w0 * h0.x; acc.y += w0 * h0.y;
        acc.z += w0 * h0.z; acc.w += w0 * h0.w;
        wsum += w0;
    }
    float inv = 1.f / (wsum + 1e-16f);
    float4 b4 = *(const float4*)(bias + ch);
    acc.x = acc.x * inv + b4.x;
    acc.y = acc.y * inv + b4.y;
    acc.z = acc.z * inv + b4.z;
    acc.w = acc.w * inv + b4.w;
    if (elu) {
        acc.x = (acc.x > 0.f) ? acc.x : __expf(acc.x) - 1.f;
        acc.y = (acc.y > 0.f) ? acc.y : __expf(acc.y) - 1.f;
        acc.z = (acc.z > 0.f) ? acc.z : __expf(acc.z) - 1.f;
        acc.w = (acc.w > 0.f) ? acc.w : __expf(acc.w) - 1.f;
    }
    *(float4*)(out + (size_t)wid * 256 + ch) = acc;
}

// ---------------- task-head packing & alphas ----------------

__global__ void pack_w_kernel(const float* __restrict__ wTL, const float* __restrict__ wYL,
                              const float* __restrict__ wTS, const float* __restrict__ wTZ,
                              const float* __restrict__ bTL, const float* __restrict__ bYL,
                              const float* __restrict__ bTS, const float* __restrict__ bTZ,
                              float* __restrict__ Wcat, float* __restrict__ bcat) {
    int idx = blockIdx.x * blockDim.x + threadIdx.x;
    if (idx < 256 * 222) {
        int r = idx / 222, c = idx % 222;
        float v;
        if (c < 12)       v = wTL[r * 12 + c];
        else if (c < 42)  v = wYL[r * 30 + (c - 12)];
        else if (c < 102) v = wTS[r * 60 + (c - 42)];
        else              v = wTZ[r * 120 + (c - 102)];
        Wcat[idx] = v;
    }
    if (idx < 222) {
        bcat[idx] = (idx < 12) ? bTL[idx] : (idx < 42) ? bYL[idx - 12]
                  : (idx < 102) ? bTS[idx - 42] : bTZ[idx - 102];
    }
}

__global__ void task_alphas_kernel(const float* __restrict__ ht,
        const float* __restrict__ asTL, const float* __restrict__ adTL,
        const float* __restrict__ asYL, const float* __restrict__ adYL,
        const float* __restrict__ asTS, const float* __restrict__ adTS,
        const float* __restrict__ asTZ, const float* __restrict__ adTZ,
        float* __restrict__ ast, float* __restrict__ adt, int n) {
    int t = blockIdx.x * blockDim.x + threadIdx.x;
    if (t >= n * 4) return;
    int d = t >> 2, task = t & 3;
    const int CO[4] = {0, 12, 42, 102};
    const int CL[4] = {12, 30, 60, 120};
    const float* av; const float* dv;
    switch (task) {
        case 0: av = asTL; dv = adTL; break;
        case 1: av = asYL; dv = adYL; break;
        case 2: av = asTS; dv = adTS; break;
        default: av = asTZ; dv = adTZ; break;
    }
    const float* hp = ht + (size_t)d * 222 + CO[task];
    float ss = 0.f, sd = 0.f;
    for (int c = 0; c < CL[task]; ++c) {
        float v = hp[c];
        ss += v * av[c];
        sd += v * dv[c];
    }
    ast[t] = ss;
    adt[t] = sd;
}

// ---------------- edge weights, 4 tasks ----------------

__global__ void ew4_kernel(const float* __restrict__ ast, const float* __restrict__ adt,
                           const int* __restrict__ csr, const int* __restrict__ csrd,
                           float* __restrict__ ew, int M) {
    int i = blockIdx.x * blockDim.x + threadIdx.x;
    if (i >= M) return;
    int s = csr[i], d = csrd[i];
    float4 a = *(const float4*)(ast + (size_t)s * 4);
    float4 b = *(const float4*)(adt + (size_t)d * 4);
    float v[4] = {a.x + b.x, a.y + b.y, a.z + b.z, a.w + b.w};
    float w[4];
    #pragma unroll
    for (int t = 0; t < 4; ++t) {
        float x = v[t];
        x = (x > 0.f) ? x : NEG_SLOPE * x;
        w[t] = __expf(x);
    }
    *(float4*)(ew + (size_t)i * 4) = make_float4(w[0], w[1], w[2], w[3]);
}

// ---------------- 4-task gather (channels 12|30|60|120 = 222) --------------
// lane owns flat channels lane*4..+3; at most 2 tasks per lane. Unroll x4.

__global__ __launch_bounds__(256) void task_gather_kernel(
        const float* __restrict__ ht, const float* __restrict__ ew,
        const int* __restrict__ rowstart, const int* __restrict__ csr,
        const float* __restrict__ bcat, float* __restrict__ agg, int n) {
    int wid  = blockIdx.x * 4 + (threadIdx.x >> 6);
    int lane = threadIdx.x & 63;
    if (wid >= n) return;
    int row = rowstart[wid];
    int deg = rowstart[wid + 1] - row;
    int ch0 = lane * 4;

    int tj[4]; bool valj[4];
    #pragma unroll
    for (int j = 0; j < 4; ++j) {
        int ch = ch0 + j;
        valj[j] = (ch < 222);
        tj[j] = (ch >= 102) ? 3 : (ch >= 42) ? 2 : (ch >= 12) ? 1 : 0;
    }
    int t_lo = tj[0], t_hi = tj[3];
    bool use_lo[4];
    #pragma unroll
    for (int j = 0; j < 4; ++j) use_lo[j] = (tj[j] == t_lo);

    const int* cp = csr + row;
    const float* wp = ew + (size_t)row * 4;

    float acc[4] = {0.f, 0.f, 0.f, 0.f};
    float ws_lo = 0.f, ws_hi = 0.f;
    int e = 0;
    for (; e + 4 <= deg; e += 4) {
        int s0 = cp[e], s1 = cp[e + 1], s2 = cp[e + 2], s3 = cp[e + 3];
        float wlo0 = wp[(size_t)(e + 0) * 4 + t_lo], whi0 = wp[(size_t)(e + 0) * 4 + t_hi];
        float wlo1 = wp[(size_t)(e + 1) * 4 + t_lo], whi1 = wp[(size_t)(e + 1) * 4 + t_hi];
        float wlo2 = wp[(size_t)(e + 2) * 4 + t_lo], whi2 = wp[(size_t)(e + 2) * 4 + t_hi];
        float wlo3 = wp[(size_t)(e + 3) * 4 + t_lo], whi3 = wp[(size_t)(e + 3) * 4 + t_hi];
        float4 h0 = *(const float4*)(ht + (size_t)s0 * 222 + ch0);
        float4 h1 = *(const float4*)(ht + (size_t)s1 * 222 + ch0);
        float4 h2 = *(const float4*)(ht + (size_t)s2 * 222 + ch0);
        float4 h3 = *(const float4*)(ht + (size_t)s3 * 222 + ch0);
        ws_lo += (wlo0 + wlo1) + (wlo2 + wlo3);
        ws_hi += (whi0 + whi1) + (whi2 + whi3);
        float hv0[4] = {h0.x, h0.y, h0.z, h0.w};
        float hv1[4] = {h1.x, h1.y, h1.z, h1.w};
        float hv2[4] = {h2.x, h2.y, h2.z, h2.w};
        float hv3[4] = {h3.x, h3.y, h3.z, h3.w};
        #pragma unroll
        for (int j = 0; j < 4; ++j) {
            float w0 = use_lo[j] ? wlo0 : whi0;
            float w1 = use_lo[j] ? wlo1 : whi1;
            float w2 = use_lo[j] ? wlo2 : whi2;
            float w3 = use_lo[j] ? wlo3 : whi3;
            acc[j] += w0 * hv0[j] + w1 * hv1[j] + w2 * hv2[j] + w3 * hv3[j];
        }
    }
    for (; e < deg; ++e) {
        int s = cp[e];
        float wlo = wp[(size_t)e * 4 + t_lo];
        float whi = wp[(size_t)e * 4 + t_hi];
        ws_lo += wlo; ws_hi += whi;
        float4 h0 = *(const float4*)(ht + (size_t)s * 222 + ch0);
        float hv[4] = {h0.x, h0.y, h0.z, h0.w};
        #pragma unroll
        for (int j = 0; j < 4; ++j) {
            float w = use_lo[j] ? wlo : whi;
            acc[j] += w * hv[j];
        }
    }
    float inv_lo = 1.f / (ws_lo + 1e-16f);
    float inv_hi = 1.f / (ws_hi + 1e-16f);
    #pragma unroll
    for (int j = 0; j < 4; ++j) {
        int ch = ch0 + j;
        if (ch < 222)
            agg[(size_t)wid * 222 + ch] = acc[j] * (use_lo[j] ? inv_lo : inv_hi) + bcat[ch];
    }
}

// NOTE: task_gather reads float4 at ht + s*222 + ch0; for lanes 55 the load
// reaches ch 220..223 (2 floats past the row) — stays inside the ht buffer
// (next row's data, masked out by valj on accumulate? No: we accumulate then
// mask at store). acc[2],acc[3] for lane 55 are garbage but never stored
// (ch >= 222 masked). Buffer has N*256 capacity, so no OOB.

// ---------------- log_softmax over each task segment ----------------

__global__ __launch_bounds__(256) void logsoftmax_kernel(const float* __restrict__ agg,
                                                         float* __restrict__ out, int n) {
    int wid  = blockIdx.x * 4 + (threadIdx.x >> 6);
    int lane = threadIdx.x & 63;
    if (wid >= n) return;
    const int CO[4] = {0, 12, 42, 102};
    const int CL[4] = {12, 30, 60, 120};
    const float* a = agg + (size_t)wid * 222;
    #pragma unroll
    for (int t = 0; t < 4; ++t) {
        int c = CL[t];
        float v0 = (lane < c)      ? a[CO[t] + lane]      : -1e30f;
        float v1 = (lane + 64 < c) ? a[CO[t] + lane + 64] : -1e30f;
        float mx = fmaxf(v0, v1);
        #pragma unroll
        for (int off = 1; off < 64; off <<= 1) mx = fmaxf(mx, __shfl_xor(mx, off));
        float s = ((lane < c) ? __expf(v0 - mx) : 0.f) +
                  ((lane + 64 < c) ? __expf(v1 - mx) : 0.f);
        #pragma unroll
        for (int off = 1; off < 64; off <<= 1) s += __shfl_xor(s, off);
        float lse = mx + __logf(s);
        float* op = out + (size_t)CO[t] * n + (size_t)wid * c;
        if (lane < c)      op[lane]      = v0 - lse;
        if (lane + 64 < c) op[lane + 64] = v1 - lse;
    }
}

// ---------------- launcher ----------------

extern "C" void kernel_launch(void* const* d_in, const int* in_sizes, int n_in,
                              void* d_out, int out_size, void* d_ws, size_t ws_size,
                              hipStream_t stream) {
    const float* x   = (const float*)d_in[0];
    const int*   ei  = (const int*)d_in[1];
    const float* W1  = (const float*)d_in[2];
    const float* a1s = (const float*)d_in[3];
    const float* a1d = (const float*)d_in[4];
    const float* b1  = (const float*)d_in[5];
    const float* W2  = (const float*)d_in[6];
    const float* a2s = (const float*)d_in[7];
    const float* a2d = (const float*)d_in[8];
    const float* b2  = (const float*)d_in[9];
    const float* W_TL = (const float*)d_in[10]; const float* as_TL = (const float*)d_in[11];
    const float* ad_TL = (const float*)d_in[12]; const float* b_TL = (const float*)d_in[13];
    const float* W_YL = (const float*)d_in[14]; const float* as_YL = (const float*)d_in[15];
    const float* ad_YL = (const float*)d_in[16]; const float* b_YL = (const float*)d_in[17];
    const float* W_TS = (const float*)d_in[18]; const float* as_TS = (const float*)d_in[19];
    const float* ad_TS = (const float*)d_in[20]; const float* b_TS = (const float*)d_in[21];
    const float* W_TZ = (const float*)d_in[22]; const float* as_TZ = (const float*)d_in[23];
    const float* ad_TZ = (const float*)d_in[24]; const float* b_TZ = (const float*)d_in[25];

    const int N = in_sizes[0] / 128;
    const int E = in_sizes[1] / 2;
    const int* e_src = ei;
    const int* e_dst = ei + E;
    const int M = E + N;                   // CSR slots incl. self loops

    float* ws = (float*)d_ws;
    // Big buffers (N*256 floats each) with phase-based reuse:
    //  B1: h1 -> (gather2 out AG2) -> ew_t (task weights, 4M floats)
    //  B2: AG1 (conv1 out) -> ew2 (conv2 weights, 6.8M floats) -> ht (N*222)
    //  B3: ew1 (conv1 weights) -> h2 -> AGT (task agg out, N*222)
    float* B1   = ws;
    float* B2   = B1 + (size_t)N * 256;
    float* B3   = B2 + (size_t)N * 256;
    float* as1  = B3 + (size_t)N * 256;    // N*8
    float* ad1  = as1 + (size_t)N * 8;
    float* as2  = ad1 + (size_t)N * 8;
    float* ad2  = as2 + (size_t)N * 8;
    float* ast  = ad2 + (size_t)N * 8;     // N*4
    float* adt  = ast + (size_t)N * 4;
    float* Wcat = adt + (size_t)N * 4;     // 256*222
    float* bcat = Wcat + 256 * 222;        // 222 (+2 pad)
    int* deg      = (int*)(bcat + 224);    // N
    int* rowstart = deg + N;               // N+1
    int* cursor   = rowstart + (N + 1);    // N
    int* csr      = cursor + N;            // M (src per slot)
    int* csrd     = csr + M;               // M (dst per slot)

    float* out = (float*)d_out;

    const int B = 256;
    // --- CSR build ---
    init_kernel<<<(N + B - 1) / B, B, 0, stream>>>(deg, cursor, N);
    count_kernel<<<(E + B - 1) / B, B, 0, stream>>>(e_dst, deg, E);
    scan_kernel<<<1, 1024, 0, stream>>>(deg, rowstart, N);
    scatter_kernel<<<(M + B - 1) / B, B, 0, stream>>>(e_src, e_dst, rowstart, cursor, csr, csrd, E, N);
    // --- pack task weights ---
    pack_w_kernel<<<(256 * 222 + B - 1) / B, B, 0, stream>>>(W_TL, W_YL, W_TS, W_TZ,
                                                             b_TL, b_YL, b_TS, b_TZ, Wcat, bcat);
    // --- conv1 ---
    {
        dim3 g((256 + 63) / 64, (N + 127) / 128);
        gemm_kernel<<<g, 256, 0, stream>>>(x, W1, B1, N, 128, 256);
    }
    node_alphas_kernel<<<(N * 8 + B - 1) / B, B, 0, stream>>>(B1, a1s, a1d, as1, ad1, N);
    ew8_kernel<<<(M + B - 1) / B, B, 0, stream>>>(as1, ad1, csr, csrd, B3, M);          // ew1 in B3
    gat_gather_kernel<<<(N + 3) / 4, 256, 0, stream>>>(B1, B3, rowstart, csr, b1, B2, N, 1);
    // --- conv2 ---
    {
        dim3 g((256 + 63) / 64, (N + 127) / 128);
        gemm_kernel<<<g, 256, 0, stream>>>(B2, W2, B3, N, 256, 256);                    // h2 in B3
    }
    node_alphas_kernel<<<(N * 8 + B - 1) / B, B, 0, stream>>>(B3, a2s, a2d, as2, ad2, N);
    ew8_kernel<<<(M + B - 1) / B, B, 0, stream>>>(as2, ad2, csr, csrd, B2, M);          // ew2 in B2
    gat_gather_kernel<<<(N + 3) / 4, 256, 0, stream>>>(B3, B2, rowstart, csr, b2, B1, N, 0); // AG2 in B1
    // --- task heads (fused GEMM over concat 222 cols) ---
    {
        dim3 g((222 + 63) / 64, (N + 127) / 128);
        gemm_kernel<<<g, 256, 0, stream>>>(B1, Wcat, B2, N, 256, 222);                  // ht in B2
    }
    task_alphas_kernel<<<(N * 4 + B - 1) / B, B, 0, stream>>>(B2, as_TL, ad_TL, as_YL, ad_YL,
                                                              as_TS, ad_TS, as_TZ, ad_TZ, ast, adt, N);
    ew4_kernel<<<(M + B - 1) / B, B, 0, stream>>>(ast, adt, csr, csrd, B1, M);          // ew_t in B1
    task_gather_kernel<<<(N + 3) / 4, 256, 0, stream>>>(B2, B1, rowstart, csr, bcat, B3, N);
    logsoftmax_kernel<<<(N + 3) / 4, 256, 0, stream>>>(B3, out, N);
}

// Round 4
// 994.213 us; speedup vs baseline: 1.3263x; 1.1787x over previous
//
#include <hip/hip_runtime.h>
#include <math.h>

// ---------------------------------------------------------------------------
// MultiTaskGAT: 2x GATConv(8 heads x 32ch, concat) + 4 task heads (1 head)
// N=50000 nodes, E=800000 edges (+N self loops), F_IN=128, DH=256.
//
// R2: unnormalized softmax (exp hoisted), single-pass gathers.
// R3: gather loops unrolled x4 (latency/MLP).
// R4: GEMMs -> bf16 MFMA with hi/lo split (C = Ah*Bh + Ah*Bl + Al*Bh,
//     error ~2^-16 rel ≈ fp32). Features pre-split once per GEMM; weights
//     pre-split transposed (Bt[n][k]) so A/B fragments are contiguous
//     ds_read_b128. fp32 vector GEMM was 43 TF / 153 µs each with MfmaUtil=0.
// ---------------------------------------------------------------------------

#define NEG_SLOPE 0.2f

typedef short s8v __attribute__((ext_vector_type(8)));
typedef short s4v __attribute__((ext_vector_type(4)));
typedef float f4v __attribute__((ext_vector_type(4)));

__device__ __forceinline__ short f2bf(float x) {
    unsigned u = __float_as_uint(x);
    u += 0x7fffu + ((u >> 16) & 1u);
    return (short)(u >> 16);
}
__device__ __forceinline__ float bf2f(short b) {
    return __uint_as_float(((unsigned)(unsigned short)b) << 16);
}
__device__ __forceinline__ void split2(float x, short& h, short& l) {
    h = f2bf(x);
    l = f2bf(x - bf2f(h));
}

// ---------------- CSR build ----------------

__global__ void init_kernel(int* __restrict__ deg, int* __restrict__ cursor, int n) {
    int i = blockIdx.x * blockDim.x + threadIdx.x;
    if (i < n) { deg[i] = 1; cursor[i] = 0; }   // deg starts at 1: self loop
}

__global__ void count_kernel(const int* __restrict__ dst, int* __restrict__ deg, int E) {
    int i = blockIdx.x * blockDim.x + threadIdx.x;
    if (i < E) atomicAdd(&deg[dst[i]], 1);
}

__global__ __launch_bounds__(1024) void scan_kernel(const int* __restrict__ deg,
                                                    int* __restrict__ rowstart, int n) {
    __shared__ int sh[1024];
    __shared__ int carry_sh;
    if (threadIdx.x == 0) { carry_sh = 0; rowstart[0] = 0; }
    __syncthreads();
    for (int base = 0; base < n; base += 8192) {
        int vals[8];
        int sum = 0;
        int i0 = base + threadIdx.x * 8;
        #pragma unroll
        for (int j = 0; j < 8; ++j) {
            int i = i0 + j;
            int v = (i < n) ? deg[i] : 0;
            sum += v;
            vals[j] = sum;               // local inclusive
        }
        sh[threadIdx.x] = sum;
        __syncthreads();
        for (int off = 1; off < 1024; off <<= 1) {
            int t = (threadIdx.x >= (unsigned)off) ? sh[threadIdx.x - off] : 0;
            __syncthreads();
            sh[threadIdx.x] += t;
            __syncthreads();
        }
        int excl = sh[threadIdx.x] - sum + carry_sh;
        #pragma unroll
        for (int j = 0; j < 8; ++j) {
            int i = i0 + j;
            if (i < n) rowstart[i + 1] = excl + vals[j];
        }
        __syncthreads();
        if (threadIdx.x == 0) carry_sh += sh[1023];
        __syncthreads();
    }
}

__global__ void scatter_kernel(const int* __restrict__ src, const int* __restrict__ dst,
                               const int* __restrict__ rowstart, int* __restrict__ cursor,
                               int* __restrict__ csr, int* __restrict__ csrd, int E, int n) {
    int i = blockIdx.x * blockDim.x + threadIdx.x;
    if (i >= E + n) return;
    int s, d;
    if (i < E) { s = src[i]; d = dst[i]; }
    else       { s = d = i - E; }          // self loop
    int p = atomicAdd(&cursor[d], 1);
    int slot = rowstart[d] + p;
    csr[slot] = s;
    csrd[slot] = d;
}

// ---------------- hi/lo bf16 splits ----------------

__global__ void split_a_kernel(const float* __restrict__ A, short* __restrict__ Ah,
                               short* __restrict__ Al, int n4) {
    int i = blockIdx.x * blockDim.x + threadIdx.x;
    if (i >= n4) return;
    float4 v = ((const float4*)A)[i];
    short h0, h1, h2, h3, l0, l1, l2, l3;
    split2(v.x, h0, l0); split2(v.y, h1, l1);
    split2(v.z, h2, l2); split2(v.w, h3, l3);
    s4v hv = {h0, h1, h2, h3};
    s4v lv = {l0, l1, l2, l3};
    ((s4v*)Ah)[i] = hv;
    ((s4v*)Al)[i] = lv;
}

// B[K][Nc] fp32 -> Bt[n][k] bf16 hi/lo (k-contiguous for MFMA B-fragments)
__global__ void split_bt_kernel(const float* __restrict__ B, short* __restrict__ Bh,
                                short* __restrict__ Bl, int K, int Nc, int kshift) {
    int idx = blockIdx.x * blockDim.x + threadIdx.x;
    if (idx >= Nc * K) return;
    int n = idx >> kshift;          // K is a power of two (128/256)
    int k = idx & (K - 1);
    float v = B[(size_t)k * Nc + n];
    short h, l; split2(v, h, l);
    Bh[idx] = h;
    Bl[idx] = l;
}

// ---------------- bf16 MFMA GEMM: C[M,Nc] = A[M,K] @ B[K,Nc] ---------------
// A given as hi/lo bf16 [M][K]; B given as transposed hi/lo bf16 [Nc][K].
// Block 128x64 (4 waves x 32 rows), K-step 32, 16x16x32 MFMA, 3-term hi/lo.
// LDS stride 40 shorts (80B): fragment ds_read_b128 at 2-way conflict (free).

#define MB 128
#define NB 64
#define KS 32

__global__ __launch_bounds__(256) void gemm_mfma_kernel(
        const short* __restrict__ Ah_g, const short* __restrict__ Al_g,
        const short* __restrict__ Bth_g, const short* __restrict__ Btl_g,
        float* __restrict__ C, int M, int K, int Nc) {
    __shared__ __align__(16) short Ah[MB][40];
    __shared__ __align__(16) short Al[MB][40];
    __shared__ __align__(16) short Bh[NB][40];
    __shared__ __align__(16) short Bl[NB][40];

    int t = threadIdx.x;
    int lane = t & 63, w = t >> 6;
    int quad = lane >> 4, l16 = lane & 15;
    int row0 = blockIdx.y * MB, col0 = blockIdx.x * NB;

    f4v acc[2][4];
    #pragma unroll
    for (int mt = 0; mt < 2; ++mt)
        #pragma unroll
        for (int nt = 0; nt < 4; ++nt)
            acc[mt][nt] = (f4v){0.f, 0.f, 0.f, 0.f};

    for (int k0 = 0; k0 < K; k0 += KS) {
        __syncthreads();
        // stage A: 128x32 bf16 hi+lo. 512 8-elem units per array, 2/thread.
        #pragma unroll
        for (int i = 0; i < 2; ++i) {
            int u = i * 256 + t;
            int r = u >> 2, kk = (u & 3) * 8;
            int gr = row0 + r;
            s8v vh = {0, 0, 0, 0, 0, 0, 0, 0};
            s8v vl = {0, 0, 0, 0, 0, 0, 0, 0};
            if (gr < M) {
                vh = *(const s8v*)(Ah_g + (size_t)gr * K + k0 + kk);
                vl = *(const s8v*)(Al_g + (size_t)gr * K + k0 + kk);
            }
            *(s8v*)&Ah[r][kk] = vh;
            *(s8v*)&Al[r][kk] = vl;
        }
        // stage B: 64x32 bf16 hi+lo. 256 units per array, 1/thread.
        {
            int n = t >> 2, kk = (t & 3) * 8;
            int gc = col0 + n;
            s8v vh = {0, 0, 0, 0, 0, 0, 0, 0};
            s8v vl = {0, 0, 0, 0, 0, 0, 0, 0};
            if (gc < Nc) {
                vh = *(const s8v*)(Bth_g + (size_t)gc * K + k0 + kk);
                vl = *(const s8v*)(Btl_g + (size_t)gc * K + k0 + kk);
            }
            *(s8v*)&Bh[n][kk] = vh;
            *(s8v*)&Bl[n][kk] = vl;
        }
        __syncthreads();

        int kb = quad * 8;
        s8v a_h[2], a_l[2], b_h[4], b_l[4];
        #pragma unroll
        for (int mt = 0; mt < 2; ++mt) {
            int r = w * 32 + mt * 16 + l16;
            a_h[mt] = *(const s8v*)&Ah[r][kb];
            a_l[mt] = *(const s8v*)&Al[r][kb];
        }
        #pragma unroll
        for (int nt = 0; nt < 4; ++nt) {
            int c = nt * 16 + l16;
            b_h[nt] = *(const s8v*)&Bh[c][kb];
            b_l[nt] = *(const s8v*)&Bl[c][kb];
        }
        #pragma unroll
        for (int mt = 0; mt < 2; ++mt)
            #pragma unroll
            for (int nt = 0; nt < 4; ++nt) {
                acc[mt][nt] = __builtin_amdgcn_mfma_f32_16x16x32_bf16(
                    a_h[mt], b_h[nt], acc[mt][nt], 0, 0, 0);
                acc[mt][nt] = __builtin_amdgcn_mfma_f32_16x16x32_bf16(
                    a_h[mt], b_l[nt], acc[mt][nt], 0, 0, 0);
                acc[mt][nt] = __builtin_amdgcn_mfma_f32_16x16x32_bf16(
                    a_l[mt], b_h[nt], acc[mt][nt], 0, 0, 0);
            }
    }

    // epilogue: C/D layout col=lane&15, row=quad*4+reg
    #pragma unroll
    for (int mt = 0; mt < 2; ++mt) {
        #pragma unroll
        for (int nt = 0; nt < 4; ++nt) {
            int gc = col0 + nt * 16 + l16;
            if (gc >= Nc) continue;
            #pragma unroll
            for (int r = 0; r < 4; ++r) {
                int gr = row0 + w * 32 + mt * 16 + quad * 4 + r;
                if (gr < M) C[(size_t)gr * Nc + gc] = acc[mt][nt][r];
            }
        }
    }
}

// ---------------- per-node attention coefficients (8 heads) ----------------

__global__ void node_alphas_kernel(const float* __restrict__ h,
                                   const float* __restrict__ a_s, const float* __restrict__ a_d,
                                   float* __restrict__ als, float* __restrict__ ald, int n) {
    int t = blockIdx.x * blockDim.x + threadIdx.x;
    if (t >= n * 8) return;
    int d = t >> 3, hh = t & 7;
    const float* hp  = h + (size_t)d * 256 + hh * 32;
    const float* asp = a_s + hh * 32;
    const float* adp = a_d + hh * 32;
    float ss = 0.f, sd = 0.f;
    #pragma unroll
    for (int c = 0; c < 32; ++c) {
        float v = hp[c];
        ss += v * asp[c];
        sd += v * adp[c];
    }
    als[t] = ss;
    ald[t] = sd;
}

// ---------------- edge weights, 8 heads (unnormalized softmax) -------------

__global__ void ew8_kernel(const float* __restrict__ als, const float* __restrict__ ald,
                           const int* __restrict__ csr, const int* __restrict__ csrd,
                           float* __restrict__ ew, int M) {
    int i = blockIdx.x * blockDim.x + threadIdx.x;
    if (i >= M) return;
    int s = csr[i], d = csrd[i];
    const float4* ap = (const float4*)(als + (size_t)s * 8);
    const float4* dp = (const float4*)(ald + (size_t)d * 8);
    float4 a0 = ap[0], a1 = ap[1];
    float4 d0 = dp[0], d1 = dp[1];
    float v[8] = {a0.x + d0.x, a0.y + d0.y, a0.z + d0.z, a0.w + d0.w,
                  a1.x + d1.x, a1.y + d1.y, a1.z + d1.z, a1.w + d1.w};
    float w[8];
    #pragma unroll
    for (int h = 0; h < 8; ++h) {
        float x = v[h];
        x = (x > 0.f) ? x : NEG_SLOPE * x;
        w[h] = __expf(x);
    }
    float4* op = (float4*)(ew + (size_t)i * 8);
    op[0] = make_float4(w[0], w[1], w[2], w[3]);
    op[1] = make_float4(w[4], w[5], w[6], w[7]);
}

// ---------------- GAT gather (8 heads x 32 ch), one wave per dst -----------
// lane owns head lane>>3, flat channels lane*4 .. +3. Unroll x4 prefetch.

__global__ __launch_bounds__(256) void gat_gather_kernel(
        const float* __restrict__ h, const float* __restrict__ ew,
        const int* __restrict__ rowstart, const int* __restrict__ csr,
        const float* __restrict__ bias, float* __restrict__ out, int n, int elu) {
    int wid  = blockIdx.x * 4 + (threadIdx.x >> 6);
    int lane = threadIdx.x & 63;
    if (wid >= n) return;
    int row = rowstart[wid];
    int deg = rowstart[wid + 1] - row;
    int hp = lane >> 3;
    int ch = lane * 4;
    const int* cp = csr + row;
    const float* wp = ew + (size_t)row * 8 + hp;

    float4 acc = {0.f, 0.f, 0.f, 0.f};
    float wsum = 0.f;
    int e = 0;
    for (; e + 4 <= deg; e += 4) {
        int s0 = cp[e], s1 = cp[e + 1], s2 = cp[e + 2], s3 = cp[e + 3];
        float w0 = wp[(size_t)(e + 0) * 8];
        float w1 = wp[(size_t)(e + 1) * 8];
        float w2 = wp[(size_t)(e + 2) * 8];
        float w3 = wp[(size_t)(e + 3) * 8];
        float4 h0 = *(const float4*)(h + (size_t)s0 * 256 + ch);
        float4 h1 = *(const float4*)(h + (size_t)s1 * 256 + ch);
        float4 h2 = *(const float4*)(h + (size_t)s2 * 256 + ch);
        float4 h3 = *(const float4*)(h + (size_t)s3 * 256 + ch);
        acc.x += w0 * h0.x + w1 * h1.x + w2 * h2.x + w3 * h3.x;
        acc.y += w0 * h0.y + w1 * h1.y + w2 * h2.y + w3 * h3.y;
        acc.z += w0 * h0.z + w1 * h1.z + w2 * h2.z + w3 * h3.z;
        acc.w += w0 * h0.w + w1 * h1.w + w2 * h2.w + w3 * h3.w;
        wsum += (w0 + w1) + (w2 + w3);
    }
    for (; e < deg; ++e) {
        int s0 = cp[e];
        float w0 = wp[(size_t)e * 8];
        float4 h0 = *(const float4*)(h + (size_t)s0 * 256 + ch);
        acc.x += w0 * h0.x; acc.y += w0 * h0.y;
        acc.z += w0 * h0.z; acc.w += w0 * h0.w;
        wsum += w0;
    }
    float inv = 1.f / (wsum + 1e-16f);
    float4 b4 = *(const float4*)(bias + ch);
    acc.x = acc.x * inv + b4.x;
    acc.y = acc.y * inv + b4.y;
    acc.z = acc.z * inv + b4.z;
    acc.w = acc.w * inv + b4.w;
    if (elu) {
        acc.x = (acc.x > 0.f) ? acc.x : __expf(acc.x) - 1.f;
        acc.y = (acc.y > 0.f) ? acc.y : __expf(acc.y) - 1.f;
        acc.z = (acc.z > 0.f) ? acc.z : __expf(acc.z) - 1.f;
        acc.w = (acc.w > 0.f) ? acc.w : __expf(acc.w) - 1.f;
    }
    *(float4*)(out + (size_t)wid * 256 + ch) = acc;
}

// ---------------- task-head packing & alphas ----------------

__global__ void pack_w_kernel(const float* __restrict__ wTL, const float* __restrict__ wYL,
                              const float* __restrict__ wTS, const float* __restrict__ wTZ,
                              const float* __restrict__ bTL, const float* __restrict__ bYL,
                              const float* __restrict__ bTS, const float* __restrict__ bTZ,
                              float* __restrict__ Wcat, float* __restrict__ bcat) {
    int idx = blockIdx.x * blockDim.x + threadIdx.x;
    if (idx < 256 * 222) {
        int r = idx / 222, c = idx % 222;
        float v;
        if (c < 12)       v = wTL[r * 12 + c];
        else if (c < 42)  v = wYL[r * 30 + (c - 12)];
        else if (c < 102) v = wTS[r * 60 + (c - 42)];
        else              v = wTZ[r * 120 + (c - 102)];
        Wcat[idx] = v;
    }
    if (idx < 222) {
        bcat[idx] = (idx < 12) ? bTL[idx] : (idx < 42) ? bYL[idx - 12]
                  : (idx < 102) ? bTS[idx - 42] : bTZ[idx - 102];
    }
}

__global__ void task_alphas_kernel(const float* __restrict__ ht,
        const float* __restrict__ asTL, const float* __restrict__ adTL,
        const float* __restrict__ asYL, const float* __restrict__ adYL,
        const float* __restrict__ asTS, const float* __restrict__ adTS,
        const float* __restrict__ asTZ, const float* __restrict__ adTZ,
        float* __restrict__ ast, float* __restrict__ adt, int n) {
    int t = blockIdx.x * blockDim.x + threadIdx.x;
    if (t >= n * 4) return;
    int d = t >> 2, task = t & 3;
    const int CO[4] = {0, 12, 42, 102};
    const int CL[4] = {12, 30, 60, 120};
    const float* av; const float* dv;
    switch (task) {
        case 0: av = asTL; dv = adTL; break;
        case 1: av = asYL; dv = adYL; break;
        case 2: av = asTS; dv = adTS; break;
        default: av = asTZ; dv = adTZ; break;
    }
    const float* hp = ht + (size_t)d * 222 + CO[task];
    float ss = 0.f, sd = 0.f;
    for (int c = 0; c < CL[task]; ++c) {
        float v = hp[c];
        ss += v * av[c];
        sd += v * dv[c];
    }
    ast[t] = ss;
    adt[t] = sd;
}

// ---------------- edge weights, 4 tasks ----------------

__global__ void ew4_kernel(const float* __restrict__ ast, const float* __restrict__ adt,
                           const int* __restrict__ csr, const int* __restrict__ csrd,
                           float* __restrict__ ew, int M) {
    int i = blockIdx.x * blockDim.x + threadIdx.x;
    if (i >= M) return;
    int s = csr[i], d = csrd[i];
    float4 a = *(const float4*)(ast + (size_t)s * 4);
    float4 b = *(const float4*)(adt + (size_t)d * 4);
    float v[4] = {a.x + b.x, a.y + b.y, a.z + b.z, a.w + b.w};
    float w[4];
    #pragma unroll
    for (int t = 0; t < 4; ++t) {
        float x = v[t];
        x = (x > 0.f) ? x : NEG_SLOPE * x;
        w[t] = __expf(x);
    }
    *(float4*)(ew + (size_t)i * 4) = make_float4(w[0], w[1], w[2], w[3]);
}

// ---------------- 4-task gather (channels 12|30|60|120 = 222) --------------
// lane owns flat channels lane*4..+3; at most 2 tasks per lane. Unroll x4.

__global__ __launch_bounds__(256) void task_gather_kernel(
        const float* __restrict__ ht, const float* __restrict__ ew,
        const int* __restrict__ rowstart, const int* __restrict__ csr,
        const float* __restrict__ bcat, float* __restrict__ agg, int n) {
    int wid  = blockIdx.x * 4 + (threadIdx.x >> 6);
    int lane = threadIdx.x & 63;
    if (wid >= n) return;
    int row = rowstart[wid];
    int deg = rowstart[wid + 1] - row;
    int ch0 = lane * 4;

    int tj[4]; bool valj[4];
    #pragma unroll
    for (int j = 0; j < 4; ++j) {
        int ch = ch0 + j;
        valj[j] = (ch < 222);
        tj[j] = (ch >= 102) ? 3 : (ch >= 42) ? 2 : (ch >= 12) ? 1 : 0;
    }
    int t_lo = tj[0], t_hi = tj[3];
    bool use_lo[4];
    #pragma unroll
    for (int j = 0; j < 4; ++j) use_lo[j] = (tj[j] == t_lo);

    const int* cp = csr + row;
    const float* wp = ew + (size_t)row * 4;

    float acc[4] = {0.f, 0.f, 0.f, 0.f};
    float ws_lo = 0.f, ws_hi = 0.f;
    int e = 0;
    for (; e + 4 <= deg; e += 4) {
        int s0 = cp[e], s1 = cp[e + 1], s2 = cp[e + 2], s3 = cp[e + 3];
        float wlo0 = wp[(size_t)(e + 0) * 4 + t_lo], whi0 = wp[(size_t)(e + 0) * 4 + t_hi];
        float wlo1 = wp[(size_t)(e + 1) * 4 + t_lo], whi1 = wp[(size_t)(e + 1) * 4 + t_hi];
        float wlo2 = wp[(size_t)(e + 2) * 4 + t_lo], whi2 = wp[(size_t)(e + 2) * 4 + t_hi];
        float wlo3 = wp[(size_t)(e + 3) * 4 + t_lo], whi3 = wp[(size_t)(e + 3) * 4 + t_hi];
        float4 h0 = *(const float4*)(ht + (size_t)s0 * 222 + ch0);
        float4 h1 = *(const float4*)(ht + (size_t)s1 * 222 + ch0);
        float4 h2 = *(const float4*)(ht + (size_t)s2 * 222 + ch0);
        float4 h3 = *(const float4*)(ht + (size_t)s3 * 222 + ch0);
        ws_lo += (wlo0 + wlo1) + (wlo2 + wlo3);
        ws_hi += (whi0 + whi1) + (whi2 + whi3);
        float hv0[4] = {h0.x, h0.y, h0.z, h0.w};
        float hv1[4] = {h1.x, h1.y, h1.z, h1.w};
        float hv2[4] = {h2.x, h2.y, h2.z, h2.w};
        float hv3[4] = {h3.x, h3.y, h3.z, h3.w};
        #pragma unroll
        for (int j = 0; j < 4; ++j) {
            float w0 = use_lo[j] ? wlo0 : whi0;
            float w1 = use_lo[j] ? wlo1 : whi1;
            float w2 = use_lo[j] ? wlo2 : whi2;
            float w3 = use_lo[j] ? wlo3 : whi3;
            acc[j] += w0 * hv0[j] + w1 * hv1[j] + w2 * hv2[j] + w3 * hv3[j];
        }
    }
    for (; e < deg; ++e) {
        int s = cp[e];
        float wlo = wp[(size_t)e * 4 + t_lo];
        float whi = wp[(size_t)e * 4 + t_hi];
        ws_lo += wlo; ws_hi += whi;
        float4 h0 = *(const float4*)(ht + (size_t)s * 222 + ch0);
        float hv[4] = {h0.x, h0.y, h0.z, h0.w};
        #pragma unroll
        for (int j = 0; j < 4; ++j) {
            float w = use_lo[j] ? wlo : whi;
            acc[j] += w * hv[j];
        }
    }
    float inv_lo = 1.f / (ws_lo + 1e-16f);
    float inv_hi = 1.f / (ws_hi + 1e-16f);
    #pragma unroll
    for (int j = 0; j < 4; ++j) {
        int ch = ch0 + j;
        if (ch < 222)
            agg[(size_t)wid * 222 + ch] = acc[j] * (use_lo[j] ? inv_lo : inv_hi) + bcat[ch];
    }
}

// ---------------- log_softmax over each task segment ----------------

__global__ __launch_bounds__(256) void logsoftmax_kernel(const float* __restrict__ agg,
                                                         float* __restrict__ out, int n) {
    int wid  = blockIdx.x * 4 + (threadIdx.x >> 6);
    int lane = threadIdx.x & 63;
    if (wid >= n) return;
    const int CO[4] = {0, 12, 42, 102};
    const int CL[4] = {12, 30, 60, 120};
    const float* a = agg + (size_t)wid * 222;
    #pragma unroll
    for (int t = 0; t < 4; ++t) {
        int c = CL[t];
        float v0 = (lane < c)      ? a[CO[t] + lane]      : -1e30f;
        float v1 = (lane + 64 < c) ? a[CO[t] + lane + 64] : -1e30f;
        float mx = fmaxf(v0, v1);
        #pragma unroll
        for (int off = 1; off < 64; off <<= 1) mx = fmaxf(mx, __shfl_xor(mx, off));
        float s = ((lane < c) ? __expf(v0 - mx) : 0.f) +
                  ((lane + 64 < c) ? __expf(v1 - mx) : 0.f);
        #pragma unroll
        for (int off = 1; off < 64; off <<= 1) s += __shfl_xor(s, off);
        float lse = mx + __logf(s);
        float* op = out + (size_t)CO[t] * n + (size_t)wid * c;
        if (lane < c)      op[lane]      = v0 - lse;
        if (lane + 64 < c) op[lane + 64] = v1 - lse;
    }
}

// ---------------- launcher ----------------

extern "C" void kernel_launch(void* const* d_in, const int* in_sizes, int n_in,
                              void* d_out, int out_size, void* d_ws, size_t ws_size,
                              hipStream_t stream) {
    const float* x   = (const float*)d_in[0];
    const int*   ei  = (const int*)d_in[1];
    const float* W1  = (const float*)d_in[2];
    const float* a1s = (const float*)d_in[3];
    const float* a1d = (const float*)d_in[4];
    const float* b1  = (const float*)d_in[5];
    const float* W2  = (const float*)d_in[6];
    const float* a2s = (const float*)d_in[7];
    const float* a2d = (const float*)d_in[8];
    const float* b2  = (const float*)d_in[9];
    const float* W_TL = (const float*)d_in[10]; const float* as_TL = (const float*)d_in[11];
    const float* ad_TL = (const float*)d_in[12]; const float* b_TL = (const float*)d_in[13];
    const float* W_YL = (const float*)d_in[14]; const float* as_YL = (const float*)d_in[15];
    const float* ad_YL = (const float*)d_in[16]; const float* b_YL = (const float*)d_in[17];
    const float* W_TS = (const float*)d_in[18]; const float* as_TS = (const float*)d_in[19];
    const float* ad_TS = (const float*)d_in[20]; const float* b_TS = (const float*)d_in[21];
    const float* W_TZ = (const float*)d_in[22]; const float* as_TZ = (const float*)d_in[23];
    const float* ad_TZ = (const float*)d_in[24]; const float* b_TZ = (const float*)d_in[25];

    const int N = in_sizes[0] / 128;
    const int E = in_sizes[1] / 2;
    const int* e_src = ei;
    const int* e_dst = ei + E;
    const int M = E + N;                   // CSR slots incl. self loops

    float* ws = (float*)d_ws;
    // Big buffers (N*256 floats each) with phase-based reuse:
    //  B1: h1 -> Sh/Sl (split of AG1, bf16) -> AG2 -> ew_t
    //  B2: Xh/Xl (split of x) -> AG1 -> ew2 -> ht (N*222)
    //  B3: ew1 -> h2 -> Th/Tl (split of AG2) -> AGT (N*222)
    float* B1   = ws;
    float* B2   = B1 + (size_t)N * 256;
    float* B3   = B2 + (size_t)N * 256;
    float* as1  = B3 + (size_t)N * 256;    // N*8
    float* ad1  = as1 + (size_t)N * 8;
    float* as2  = ad1 + (size_t)N * 8;
    float* ad2  = as2 + (size_t)N * 8;
    float* ast  = ad2 + (size_t)N * 8;     // N*4
    float* adt  = ast + (size_t)N * 4;
    float* Wcat = adt + (size_t)N * 4;     // 256*222
    float* bcat = Wcat + 256 * 222;        // 222 (+2 pad)
    int* deg      = (int*)(bcat + 224);    // N
    int* rowstart = deg + N;               // N+1
    int* cursor   = rowstart + (N + 1);    // N
    int* csr      = cursor + N;            // M (src per slot)
    int* csrd     = csr + M;               // M (dst per slot)
    // weight splits (bf16 hi/lo, transposed [n][k]); 16B-align
    uintptr_t wsp = (uintptr_t)(csrd + M);
    wsp = (wsp + 15) & ~(uintptr_t)15;
    short* W1h = (short*)wsp;              // 256*128
    short* W1l = W1h + 256 * 128;
    short* W2h = W1l + 256 * 128;          // 256*256
    short* W2l = W2h + 256 * 256;
    short* Wth = W2l + 256 * 256;          // 222*256
    short* Wtl = Wth + 222 * 256;
    // feature splits overlay the big buffers (see phase plan above)
    short* Xh = (short*)B2;  short* Xl = Xh + (size_t)N * 128;
    short* Sh = (short*)B1;  short* Sl = Sh + (size_t)N * 256;
    short* Th = (short*)B3;  short* Tl = Th + (size_t)N * 256;

    float* out = (float*)d_out;

    const int B = 256;
    // --- CSR build ---
    init_kernel<<<(N + B - 1) / B, B, 0, stream>>>(deg, cursor, N);
    count_kernel<<<(E + B - 1) / B, B, 0, stream>>>(e_dst, deg, E);
    scan_kernel<<<1, 1024, 0, stream>>>(deg, rowstart, N);
    scatter_kernel<<<(M + B - 1) / B, B, 0, stream>>>(e_src, e_dst, rowstart, cursor, csr, csrd, E, N);
    // --- pack + split weights ---
    pack_w_kernel<<<(256 * 222 + B - 1) / B, B, 0, stream>>>(W_TL, W_YL, W_TS, W_TZ,
                                                             b_TL, b_YL, b_TS, b_TZ, Wcat, bcat);
    split_bt_kernel<<<(256 * 128 + B - 1) / B, B, 0, stream>>>(W1, W1h, W1l, 128, 256, 7);
    split_bt_kernel<<<(256 * 256 + B - 1) / B, B, 0, stream>>>(W2, W2h, W2l, 256, 256, 8);
    split_bt_kernel<<<(222 * 256 + B - 1) / B, B, 0, stream>>>(Wcat, Wth, Wtl, 256, 222, 8);
    // --- conv1 ---
    split_a_kernel<<<((N * 128 / 4) + B - 1) / B, B, 0, stream>>>(x, Xh, Xl, N * 128 / 4);
    {
        dim3 g((256 + NB - 1) / NB, (N + MB - 1) / MB);
        gemm_mfma_kernel<<<g, 256, 0, stream>>>(Xh, Xl, W1h, W1l, B1, N, 128, 256);   // h1 in B1
    }
    node_alphas_kernel<<<(N * 8 + B - 1) / B, B, 0, stream>>>(B1, a1s, a1d, as1, ad1, N);
    ew8_kernel<<<(M + B - 1) / B, B, 0, stream>>>(as1, ad1, csr, csrd, B3, M);          // ew1 in B3
    gat_gather_kernel<<<(N + 3) / 4, 256, 0, stream>>>(B1, B3, rowstart, csr, b1, B2, N, 1); // AG1 in B2
    // --- conv2 ---
    split_a_kernel<<<((N * 256 / 4) + B - 1) / B, B, 0, stream>>>(B2, Sh, Sl, N * 256 / 4);
    {
        dim3 g((256 + NB - 1) / NB, (N + MB - 1) / MB);
        gemm_mfma_kernel<<<g, 256, 0, stream>>>(Sh, Sl, W2h, W2l, B3, N, 256, 256);   // h2 in B3
    }
    node_alphas_kernel<<<(N * 8 + B - 1) / B, B, 0, stream>>>(B3, a2s, a2d, as2, ad2, N);
    ew8_kernel<<<(M + B - 1) / B, B, 0, stream>>>(as2, ad2, csr, csrd, B2, M);          // ew2 in B2
    gat_gather_kernel<<<(N + 3) / 4, 256, 0, stream>>>(B3, B2, rowstart, csr, b2, B1, N, 0); // AG2 in B1
    // --- task heads (fused GEMM over concat 222 cols) ---
    split_a_kernel<<<((N * 256 / 4) + B - 1) / B, B, 0, stream>>>(B1, Th, Tl, N * 256 / 4);
    {
        dim3 g((222 + NB - 1) / NB, (N + MB - 1) / MB);
        gemm_mfma_kernel<<<g, 256, 0, stream>>>(Th, Tl, Wth, Wtl, B2, N, 256, 222);   // ht in B2
    }
    task_alphas_kernel<<<(N * 4 + B - 1) / B, B, 0, stream>>>(B2, as_TL, ad_TL, as_YL, ad_YL,
                                                              as_TS, ad_TS, as_TZ, ad_TZ, ast, adt, N);
    ew4_kernel<<<(M + B - 1) / B, B, 0, stream>>>(ast, adt, csr, csrd, B1, M);          // ew_t in B1
    task_gather_kernel<<<(N + 3) / 4, 256, 0, stream>>>(B2, B1, rowstart, csr, bcat, B3, N); // AGT in B3
    logsoftmax_kernel<<<(N + 3) / 4, 256, 0, stream>>>(B3, out, N);
}

// Round 5
// 827.309 us; speedup vs baseline: 1.5939x; 1.2017x over previous
//
#include <hip/hip_runtime.h>
#include <math.h>

// ---------------------------------------------------------------------------
// MultiTaskGAT: 2x GATConv(8 heads x 32ch, concat) + 4 task heads (1 head)
// N=50000 nodes, E=800000 edges (+N self loops), F_IN=128, DH=256.
//
// R2: unnormalized softmax (exp hoisted), single-pass gathers.
// R3: gather loops unrolled x4 (latency/MLP).
// R4: GEMMs -> bf16 MFMA hi/lo split (error ~2^-16 rel).
// R5: gathers read bf16 feature rows (half the bytes — R4 profile showed
//     gathers at 3.6 TB/s, 45% peak, bytes-bound). GEMM epilogue dual-writes
//     fp32 C (alpha dot-products) + bf16 copy (gather source). Weighted
//     average still accumulated in fp32.
// ---------------------------------------------------------------------------

#define NEG_SLOPE 0.2f

typedef short s8v __attribute__((ext_vector_type(8)));
typedef short s4v __attribute__((ext_vector_type(4)));
typedef float f4v __attribute__((ext_vector_type(4)));

__device__ __forceinline__ short f2bf(float x) {
    unsigned u = __float_as_uint(x);
    u += 0x7fffu + ((u >> 16) & 1u);
    return (short)(u >> 16);
}
__device__ __forceinline__ float bf2f(short b) {
    return __uint_as_float(((unsigned)(unsigned short)b) << 16);
}
__device__ __forceinline__ void split2(float x, short& h, short& l) {
    h = f2bf(x);
    l = f2bf(x - bf2f(h));
}
__device__ __forceinline__ float4 bf4_to_f4(s4v v) {
    return make_float4(bf2f(v[0]), bf2f(v[1]), bf2f(v[2]), bf2f(v[3]));
}

// ---------------- CSR build ----------------

__global__ void init_kernel(int* __restrict__ deg, int* __restrict__ cursor, int n) {
    int i = blockIdx.x * blockDim.x + threadIdx.x;
    if (i < n) { deg[i] = 1; cursor[i] = 0; }   // deg starts at 1: self loop
}

__global__ void count_kernel(const int* __restrict__ dst, int* __restrict__ deg, int E) {
    int i = blockIdx.x * blockDim.x + threadIdx.x;
    if (i < E) atomicAdd(&deg[dst[i]], 1);
}

__global__ __launch_bounds__(1024) void scan_kernel(const int* __restrict__ deg,
                                                    int* __restrict__ rowstart, int n) {
    __shared__ int sh[1024];
    __shared__ int carry_sh;
    if (threadIdx.x == 0) { carry_sh = 0; rowstart[0] = 0; }
    __syncthreads();
    for (int base = 0; base < n; base += 8192) {
        int vals[8];
        int sum = 0;
        int i0 = base + threadIdx.x * 8;
        #pragma unroll
        for (int j = 0; j < 8; ++j) {
            int i = i0 + j;
            int v = (i < n) ? deg[i] : 0;
            sum += v;
            vals[j] = sum;               // local inclusive
        }
        sh[threadIdx.x] = sum;
        __syncthreads();
        for (int off = 1; off < 1024; off <<= 1) {
            int t = (threadIdx.x >= (unsigned)off) ? sh[threadIdx.x - off] : 0;
            __syncthreads();
            sh[threadIdx.x] += t;
            __syncthreads();
        }
        int excl = sh[threadIdx.x] - sum + carry_sh;
        #pragma unroll
        for (int j = 0; j < 8; ++j) {
            int i = i0 + j;
            if (i < n) rowstart[i + 1] = excl + vals[j];
        }
        __syncthreads();
        if (threadIdx.x == 0) carry_sh += sh[1023];
        __syncthreads();
    }
}

__global__ void scatter_kernel(const int* __restrict__ src, const int* __restrict__ dst,
                               const int* __restrict__ rowstart, int* __restrict__ cursor,
                               int* __restrict__ csr, int* __restrict__ csrd, int E, int n) {
    int i = blockIdx.x * blockDim.x + threadIdx.x;
    if (i >= E + n) return;
    int s, d;
    if (i < E) { s = src[i]; d = dst[i]; }
    else       { s = d = i - E; }          // self loop
    int p = atomicAdd(&cursor[d], 1);
    int slot = rowstart[d] + p;
    csr[slot] = s;
    csrd[slot] = d;
}

// ---------------- hi/lo bf16 splits ----------------

__global__ void split_a_kernel(const float* __restrict__ A, short* __restrict__ Ah,
                               short* __restrict__ Al, int n4) {
    int i = blockIdx.x * blockDim.x + threadIdx.x;
    if (i >= n4) return;
    float4 v = ((const float4*)A)[i];
    short h0, h1, h2, h3, l0, l1, l2, l3;
    split2(v.x, h0, l0); split2(v.y, h1, l1);
    split2(v.z, h2, l2); split2(v.w, h3, l3);
    s4v hv = {h0, h1, h2, h3};
    s4v lv = {l0, l1, l2, l3};
    ((s4v*)Ah)[i] = hv;
    ((s4v*)Al)[i] = lv;
}

// B[K][Nc] fp32 -> Bt[n][k] bf16 hi/lo (k-contiguous for MFMA B-fragments)
__global__ void split_bt_kernel(const float* __restrict__ B, short* __restrict__ Bh,
                                short* __restrict__ Bl, int K, int Nc, int kshift) {
    int idx = blockIdx.x * blockDim.x + threadIdx.x;
    if (idx >= Nc * K) return;
    int n = idx >> kshift;          // K is a power of two (128/256)
    int k = idx & (K - 1);
    float v = B[(size_t)k * Nc + n];
    short h, l; split2(v, h, l);
    Bh[idx] = h;
    Bl[idx] = l;
}

// ---------------- bf16 MFMA GEMM: C[M,Nc] = A[M,K] @ B[K,Nc] ---------------
// A given as hi/lo bf16 [M][K]; B given as transposed hi/lo bf16 [Nc][K].
// Block 128x64 (4 waves x 32 rows), K-step 32, 16x16x32 MFMA, 3-term hi/lo.
// Dual epilogue: fp32 C + rounded bf16 Cb (row stride cb_stride shorts).

#define MB 128
#define NB 64
#define KS 32

__global__ __launch_bounds__(256) void gemm_mfma_kernel(
        const short* __restrict__ Ah_g, const short* __restrict__ Al_g,
        const short* __restrict__ Bth_g, const short* __restrict__ Btl_g,
        float* __restrict__ C, short* __restrict__ Cb, int cb_stride,
        int M, int K, int Nc) {
    __shared__ __align__(16) short Ah[MB][40];
    __shared__ __align__(16) short Al[MB][40];
    __shared__ __align__(16) short Bh[NB][40];
    __shared__ __align__(16) short Bl[NB][40];

    int t = threadIdx.x;
    int lane = t & 63, w = t >> 6;
    int quad = lane >> 4, l16 = lane & 15;
    int row0 = blockIdx.y * MB, col0 = blockIdx.x * NB;

    f4v acc[2][4];
    #pragma unroll
    for (int mt = 0; mt < 2; ++mt)
        #pragma unroll
        for (int nt = 0; nt < 4; ++nt)
            acc[mt][nt] = (f4v){0.f, 0.f, 0.f, 0.f};

    for (int k0 = 0; k0 < K; k0 += KS) {
        __syncthreads();
        #pragma unroll
        for (int i = 0; i < 2; ++i) {
            int u = i * 256 + t;
            int r = u >> 2, kk = (u & 3) * 8;
            int gr = row0 + r;
            s8v vh = {0, 0, 0, 0, 0, 0, 0, 0};
            s8v vl = {0, 0, 0, 0, 0, 0, 0, 0};
            if (gr < M) {
                vh = *(const s8v*)(Ah_g + (size_t)gr * K + k0 + kk);
                vl = *(const s8v*)(Al_g + (size_t)gr * K + k0 + kk);
            }
            *(s8v*)&Ah[r][kk] = vh;
            *(s8v*)&Al[r][kk] = vl;
        }
        {
            int n = t >> 2, kk = (t & 3) * 8;
            int gc = col0 + n;
            s8v vh = {0, 0, 0, 0, 0, 0, 0, 0};
            s8v vl = {0, 0, 0, 0, 0, 0, 0, 0};
            if (gc < Nc) {
                vh = *(const s8v*)(Bth_g + (size_t)gc * K + k0 + kk);
                vl = *(const s8v*)(Btl_g + (size_t)gc * K + k0 + kk);
            }
            *(s8v*)&Bh[n][kk] = vh;
            *(s8v*)&Bl[n][kk] = vl;
        }
        __syncthreads();

        int kb = quad * 8;
        s8v a_h[2], a_l[2], b_h[4], b_l[4];
        #pragma unroll
        for (int mt = 0; mt < 2; ++mt) {
            int r = w * 32 + mt * 16 + l16;
            a_h[mt] = *(const s8v*)&Ah[r][kb];
            a_l[mt] = *(const s8v*)&Al[r][kb];
        }
        #pragma unroll
        for (int nt = 0; nt < 4; ++nt) {
            int c = nt * 16 + l16;
            b_h[nt] = *(const s8v*)&Bh[c][kb];
            b_l[nt] = *(const s8v*)&Bl[c][kb];
        }
        #pragma unroll
        for (int mt = 0; mt < 2; ++mt)
            #pragma unroll
            for (int nt = 0; nt < 4; ++nt) {
                acc[mt][nt] = __builtin_amdgcn_mfma_f32_16x16x32_bf16(
                    a_h[mt], b_h[nt], acc[mt][nt], 0, 0, 0);
                acc[mt][nt] = __builtin_amdgcn_mfma_f32_16x16x32_bf16(
                    a_h[mt], b_l[nt], acc[mt][nt], 0, 0, 0);
                acc[mt][nt] = __builtin_amdgcn_mfma_f32_16x16x32_bf16(
                    a_l[mt], b_h[nt], acc[mt][nt], 0, 0, 0);
            }
    }

    // epilogue: C/D layout col=lane&15, row=quad*4+reg
    #pragma unroll
    for (int mt = 0; mt < 2; ++mt) {
        #pragma unroll
        for (int nt = 0; nt < 4; ++nt) {
            int gc = col0 + nt * 16 + l16;
            if (gc >= Nc) continue;
            #pragma unroll
            for (int r = 0; r < 4; ++r) {
                int gr = row0 + w * 32 + mt * 16 + quad * 4 + r;
                if (gr < M) {
                    float v = acc[mt][nt][r];
                    C[(size_t)gr * Nc + gc] = v;
                    Cb[(size_t)gr * cb_stride + gc] = f2bf(v);
                }
            }
        }
    }
}

// ---------------- per-node attention coefficients (8 heads) ----------------

__global__ void node_alphas_kernel(const float* __restrict__ h,
                                   const float* __restrict__ a_s, const float* __restrict__ a_d,
                                   float* __restrict__ als, float* __restrict__ ald, int n) {
    int t = blockIdx.x * blockDim.x + threadIdx.x;
    if (t >= n * 8) return;
    int d = t >> 3, hh = t & 7;
    const float* hp  = h + (size_t)d * 256 + hh * 32;
    const float* asp = a_s + hh * 32;
    const float* adp = a_d + hh * 32;
    float ss = 0.f, sd = 0.f;
    #pragma unroll
    for (int c = 0; c < 32; ++c) {
        float v = hp[c];
        ss += v * asp[c];
        sd += v * adp[c];
    }
    als[t] = ss;
    ald[t] = sd;
}

// ---------------- edge weights, 8 heads (unnormalized softmax) -------------

__global__ void ew8_kernel(const float* __restrict__ als, const float* __restrict__ ald,
                           const int* __restrict__ csr, const int* __restrict__ csrd,
                           float* __restrict__ ew, int M) {
    int i = blockIdx.x * blockDim.x + threadIdx.x;
    if (i >= M) return;
    int s = csr[i], d = csrd[i];
    const float4* ap = (const float4*)(als + (size_t)s * 8);
    const float4* dp = (const float4*)(ald + (size_t)d * 8);
    float4 a0 = ap[0], a1 = ap[1];
    float4 d0 = dp[0], d1 = dp[1];
    float v[8] = {a0.x + d0.x, a0.y + d0.y, a0.z + d0.z, a0.w + d0.w,
                  a1.x + d1.x, a1.y + d1.y, a1.z + d1.z, a1.w + d1.w};
    float w[8];
    #pragma unroll
    for (int h = 0; h < 8; ++h) {
        float x = v[h];
        x = (x > 0.f) ? x : NEG_SLOPE * x;
        w[h] = __expf(x);
    }
    float4* op = (float4*)(ew + (size_t)i * 8);
    op[0] = make_float4(w[0], w[1], w[2], w[3]);
    op[1] = make_float4(w[4], w[5], w[6], w[7]);
}

// ---------------- GAT gather (8 heads x 32 ch), one wave per dst -----------
// Feature rows in bf16 (256 shorts/row); fp32 accumulate. Unroll x4.

__global__ __launch_bounds__(256) void gat_gather_kernel(
        const short* __restrict__ hb, const float* __restrict__ ew,
        const int* __restrict__ rowstart, const int* __restrict__ csr,
        const float* __restrict__ bias, float* __restrict__ out, int n, int elu) {
    int wid  = blockIdx.x * 4 + (threadIdx.x >> 6);
    int lane = threadIdx.x & 63;
    if (wid >= n) return;
    int row = rowstart[wid];
    int deg = rowstart[wid + 1] - row;
    int hp = lane >> 3;
    int ch = lane * 4;
    const int* cp = csr + row;
    const float* wp = ew + (size_t)row * 8 + hp;

    float4 acc = {0.f, 0.f, 0.f, 0.f};
    float wsum = 0.f;
    int e = 0;
    for (; e + 4 <= deg; e += 4) {
        int s0 = cp[e], s1 = cp[e + 1], s2 = cp[e + 2], s3 = cp[e + 3];
        float w0 = wp[(size_t)(e + 0) * 8];
        float w1 = wp[(size_t)(e + 1) * 8];
        float w2 = wp[(size_t)(e + 2) * 8];
        float w3 = wp[(size_t)(e + 3) * 8];
        s4v r0 = *(const s4v*)(hb + (size_t)s0 * 256 + ch);
        s4v r1 = *(const s4v*)(hb + (size_t)s1 * 256 + ch);
        s4v r2 = *(const s4v*)(hb + (size_t)s2 * 256 + ch);
        s4v r3 = *(const s4v*)(hb + (size_t)s3 * 256 + ch);
        float4 h0 = bf4_to_f4(r0), h1 = bf4_to_f4(r1);
        float4 h2 = bf4_to_f4(r2), h3 = bf4_to_f4(r3);
        acc.x += w0 * h0.x + w1 * h1.x + w2 * h2.x + w3 * h3.x;
        acc.y += w0 * h0.y + w1 * h1.y + w2 * h2.y + w3 * h3.y;
        acc.z += w0 * h0.z + w1 * h1.z + w2 * h2.z + w3 * h3.z;
        acc.w += w0 * h0.w + w1 * h1.w + w2 * h2.w + w3 * h3.w;
        wsum += (w0 + w1) + (w2 + w3);
    }
    for (; e < deg; ++e) {
        int s0 = cp[e];
        float w0 = wp[(size_t)e * 8];
        float4 h0 = bf4_to_f4(*(const s4v*)(hb + (size_t)s0 * 256 + ch));
        acc.x += w0 * h0.x; acc.y += w0 * h0.y;
        acc.z += w0 * h0.z; acc.w += w0 * h0.w;
        wsum += w0;
    }
    float inv = 1.f / (wsum + 1e-16f);
    float4 b4 = *(const float4*)(bias + ch);
    acc.x = acc.x * inv + b4.x;
    acc.y = acc.y * inv + b4.y;
    acc.z = acc.z * inv + b4.z;
    acc.w = acc.w * inv + b4.w;
    if (elu) {
        acc.x = (acc.x > 0.f) ? acc.x : __expf(acc.x) - 1.f;
        acc.y = (acc.y > 0.f) ? acc.y : __expf(acc.y) - 1.f;
        acc.z = (acc.z > 0.f) ? acc.z : __expf(acc.z) - 1.f;
        acc.w = (acc.w > 0.f) ? acc.w : __expf(acc.w) - 1.f;
    }
    *(float4*)(out + (size_t)wid * 256 + ch) = acc;
}

// ---------------- task-head packing & alphas ----------------

__global__ void pack_w_kernel(const float* __restrict__ wTL, const float* __restrict__ wYL,
                              const float* __restrict__ wTS, const float* __restrict__ wTZ,
                              const float* __restrict__ bTL, const float* __restrict__ bYL,
                              const float* __restrict__ bTS, const float* __restrict__ bTZ,
                              float* __restrict__ Wcat, float* __restrict__ bcat) {
    int idx = blockIdx.x * blockDim.x + threadIdx.x;
    if (idx < 256 * 222) {
        int r = idx / 222, c = idx % 222;
        float v;
        if (c < 12)       v = wTL[r * 12 + c];
        else if (c < 42)  v = wYL[r * 30 + (c - 12)];
        else if (c < 102) v = wTS[r * 60 + (c - 42)];
        else              v = wTZ[r * 120 + (c - 102)];
        Wcat[idx] = v;
    }
    if (idx < 222) {
        bcat[idx] = (idx < 12) ? bTL[idx] : (idx < 42) ? bYL[idx - 12]
                  : (idx < 102) ? bTS[idx - 42] : bTZ[idx - 102];
    }
}

__global__ void task_alphas_kernel(const float* __restrict__ ht,
        const float* __restrict__ asTL, const float* __restrict__ adTL,
        const float* __restrict__ asYL, const float* __restrict__ adYL,
        const float* __restrict__ asTS, const float* __restrict__ adTS,
        const float* __restrict__ asTZ, const float* __restrict__ adTZ,
        float* __restrict__ ast, float* __restrict__ adt, int n) {
    int t = blockIdx.x * blockDim.x + threadIdx.x;
    if (t >= n * 4) return;
    int d = t >> 2, task = t & 3;
    const int CO[4] = {0, 12, 42, 102};
    const int CL[4] = {12, 30, 60, 120};
    const float* av; const float* dv;
    switch (task) {
        case 0: av = asTL; dv = adTL; break;
        case 1: av = asYL; dv = adYL; break;
        case 2: av = asTS; dv = adTS; break;
        default: av = asTZ; dv = adTZ; break;
    }
    const float* hp = ht + (size_t)d * 222 + CO[task];
    float ss = 0.f, sd = 0.f;
    for (int c = 0; c < CL[task]; ++c) {
        float v = hp[c];
        ss += v * av[c];
        sd += v * dv[c];
    }
    ast[t] = ss;
    adt[t] = sd;
}

// ---------------- edge weights, 4 tasks ----------------

__global__ void ew4_kernel(const float* __restrict__ ast, const float* __restrict__ adt,
                           const int* __restrict__ csr, const int* __restrict__ csrd,
                           float* __restrict__ ew, int M) {
    int i = blockIdx.x * blockDim.x + threadIdx.x;
    if (i >= M) return;
    int s = csr[i], d = csrd[i];
    float4 a = *(const float4*)(ast + (size_t)s * 4);
    float4 b = *(const float4*)(adt + (size_t)d * 4);
    float v[4] = {a.x + b.x, a.y + b.y, a.z + b.z, a.w + b.w};
    float w[4];
    #pragma unroll
    for (int t = 0; t < 4; ++t) {
        float x = v[t];
        x = (x > 0.f) ? x : NEG_SLOPE * x;
        w[t] = __expf(x);
    }
    *(float4*)(ew + (size_t)i * 4) = make_float4(w[0], w[1], w[2], w[3]);
}

// ---------------- 4-task gather (channels 12|30|60|120 = 222) --------------
// Feature rows in bf16, stride 224 shorts (8B-aligned lanes). Unroll x4.

__global__ __launch_bounds__(256) void task_gather_kernel(
        const short* __restrict__ htb, const float* __restrict__ ew,
        const int* __restrict__ rowstart, const int* __restrict__ csr,
        const float* __restrict__ bcat, float* __restrict__ agg, int n) {
    int wid  = blockIdx.x * 4 + (threadIdx.x >> 6);
    int lane = threadIdx.x & 63;
    if (wid >= n) return;
    int row = rowstart[wid];
    int deg = rowstart[wid + 1] - row;
    int ch0 = lane * 4;

    int tj[4];
    #pragma unroll
    for (int j = 0; j < 4; ++j) {
        int ch = ch0 + j;
        tj[j] = (ch >= 102) ? 3 : (ch >= 42) ? 2 : (ch >= 12) ? 1 : 0;
    }
    int t_lo = tj[0], t_hi = tj[3];
    bool use_lo[4];
    #pragma unroll
    for (int j = 0; j < 4; ++j) use_lo[j] = (tj[j] == t_lo);

    const int* cp = csr + row;
    const float* wp = ew + (size_t)row * 4;

    float acc[4] = {0.f, 0.f, 0.f, 0.f};
    float ws_lo = 0.f, ws_hi = 0.f;
    int e = 0;
    for (; e + 4 <= deg; e += 4) {
        int s0 = cp[e], s1 = cp[e + 1], s2 = cp[e + 2], s3 = cp[e + 3];
        float wlo0 = wp[(size_t)(e + 0) * 4 + t_lo], whi0 = wp[(size_t)(e + 0) * 4 + t_hi];
        float wlo1 = wp[(size_t)(e + 1) * 4 + t_lo], whi1 = wp[(size_t)(e + 1) * 4 + t_hi];
        float wlo2 = wp[(size_t)(e + 2) * 4 + t_lo], whi2 = wp[(size_t)(e + 2) * 4 + t_hi];
        float wlo3 = wp[(size_t)(e + 3) * 4 + t_lo], whi3 = wp[(size_t)(e + 3) * 4 + t_hi];
        float4 h0 = bf4_to_f4(*(const s4v*)(htb + (size_t)s0 * 224 + ch0));
        float4 h1 = bf4_to_f4(*(const s4v*)(htb + (size_t)s1 * 224 + ch0));
        float4 h2 = bf4_to_f4(*(const s4v*)(htb + (size_t)s2 * 224 + ch0));
        float4 h3 = bf4_to_f4(*(const s4v*)(htb + (size_t)s3 * 224 + ch0));
        ws_lo += (wlo0 + wlo1) + (wlo2 + wlo3);
        ws_hi += (whi0 + whi1) + (whi2 + whi3);
        float hv0[4] = {h0.x, h0.y, h0.z, h0.w};
        float hv1[4] = {h1.x, h1.y, h1.z, h1.w};
        float hv2[4] = {h2.x, h2.y, h2.z, h2.w};
        float hv3[4] = {h3.x, h3.y, h3.z, h3.w};
        #pragma unroll
        for (int j = 0; j < 4; ++j) {
            float w0 = use_lo[j] ? wlo0 : whi0;
            float w1 = use_lo[j] ? wlo1 : whi1;
            float w2 = use_lo[j] ? wlo2 : whi2;
            float w3 = use_lo[j] ? wlo3 : whi3;
            acc[j] += w0 * hv0[j] + w1 * hv1[j] + w2 * hv2[j] + w3 * hv3[j];
        }
    }
    for (; e < deg; ++e) {
        int s = cp[e];
        float wlo = wp[(size_t)e * 4 + t_lo];
        float whi = wp[(size_t)e * 4 + t_hi];
        ws_lo += wlo; ws_hi += whi;
        float4 h0 = bf4_to_f4(*(const s4v*)(htb + (size_t)s * 224 + ch0));
        float hv[4] = {h0.x, h0.y, h0.z, h0.w};
        #pragma unroll
        for (int j = 0; j < 4; ++j) {
            float w = use_lo[j] ? wlo : whi;
            acc[j] += w * hv[j];
        }
    }
    float inv_lo = 1.f / (ws_lo + 1e-16f);
    float inv_hi = 1.f / (ws_hi + 1e-16f);
    #pragma unroll
    for (int j = 0; j < 4; ++j) {
        int ch = ch0 + j;
        if (ch < 222)
            agg[(size_t)wid * 222 + ch] = acc[j] * (use_lo[j] ? inv_lo : inv_hi) + bcat[ch];
    }
}

// ---------------- log_softmax over each task segment ----------------

__global__ __launch_bounds__(256) void logsoftmax_kernel(const float* __restrict__ agg,
                                                         float* __restrict__ out, int n) {
    int wid  = blockIdx.x * 4 + (threadIdx.x >> 6);
    int lane = threadIdx.x & 63;
    if (wid >= n) return;
    const int CO[4] = {0, 12, 42, 102};
    const int CL[4] = {12, 30, 60, 120};
    const float* a = agg + (size_t)wid * 222;
    #pragma unroll
    for (int t = 0; t < 4; ++t) {
        int c = CL[t];
        float v0 = (lane < c)      ? a[CO[t] + lane]      : -1e30f;
        float v1 = (lane + 64 < c) ? a[CO[t] + lane + 64] : -1e30f;
        float mx = fmaxf(v0, v1);
        #pragma unroll
        for (int off = 1; off < 64; off <<= 1) mx = fmaxf(mx, __shfl_xor(mx, off));
        float s = ((lane < c) ? __expf(v0 - mx) : 0.f) +
                  ((lane + 64 < c) ? __expf(v1 - mx) : 0.f);
        #pragma unroll
        for (int off = 1; off < 64; off <<= 1) s += __shfl_xor(s, off);
        float lse = mx + __logf(s);
        float* op = out + (size_t)CO[t] * n + (size_t)wid * c;
        if (lane < c)      op[lane]      = v0 - lse;
        if (lane + 64 < c) op[lane + 64] = v1 - lse;
    }
}

// ---------------- launcher ----------------

extern "C" void kernel_launch(void* const* d_in, const int* in_sizes, int n_in,
                              void* d_out, int out_size, void* d_ws, size_t ws_size,
                              hipStream_t stream) {
    const float* x   = (const float*)d_in[0];
    const int*   ei  = (const int*)d_in[1];
    const float* W1  = (const float*)d_in[2];
    const float* a1s = (const float*)d_in[3];
    const float* a1d = (const float*)d_in[4];
    const float* b1  = (const float*)d_in[5];
    const float* W2  = (const float*)d_in[6];
    const float* a2s = (const float*)d_in[7];
    const float* a2d = (const float*)d_in[8];
    const float* b2  = (const float*)d_in[9];
    const float* W_TL = (const float*)d_in[10]; const float* as_TL = (const float*)d_in[11];
    const float* ad_TL = (const float*)d_in[12]; const float* b_TL = (const float*)d_in[13];
    const float* W_YL = (const float*)d_in[14]; const float* as_YL = (const float*)d_in[15];
    const float* ad_YL = (const float*)d_in[16]; const float* b_YL = (const float*)d_in[17];
    const float* W_TS = (const float*)d_in[18]; const float* as_TS = (const float*)d_in[19];
    const float* ad_TS = (const float*)d_in[20]; const float* b_TS = (const float*)d_in[21];
    const float* W_TZ = (const float*)d_in[22]; const float* as_TZ = (const float*)d_in[23];
    const float* ad_TZ = (const float*)d_in[24]; const float* b_TZ = (const float*)d_in[25];

    const int N = in_sizes[0] / 128;
    const int E = in_sizes[1] / 2;
    const int* e_src = ei;
    const int* e_dst = ei + E;
    const int M = E + N;                   // CSR slots incl. self loops

    float* ws = (float*)d_ws;
    // Big buffers (N*256 floats each; N*512 shorts) — phase plan:
    //  B1: h1 fp32 -> AG1 fp32 -> h2b bf16 -> ht fp32 (N*222)
    //  B2: [Xh|Xl (N*128sh ea) | h1b (N*256sh)] -> Sh/Sl -> ew2 -> Th/Tl -> AGT
    //  B3: ew1 -> h2 fp32 -> AG2 fp32 -> [htb (N*224sh) | ew_t (M*4 f)]
    float* B1   = ws;
    float* B2   = B1 + (size_t)N * 256;
    float* B3   = B2 + (size_t)N * 256;
    float* as1  = B3 + (size_t)N * 256;    // N*8
    float* ad1  = as1 + (size_t)N * 8;
    float* as2  = ad1 + (size_t)N * 8;
    float* ad2  = as2 + (size_t)N * 8;
    float* ast  = ad2 + (size_t)N * 8;     // N*4
    float* adt  = ast + (size_t)N * 4;
    float* Wcat = adt + (size_t)N * 4;     // 256*222
    float* bcat = Wcat + 256 * 222;        // 222 (+2 pad)
    int* deg      = (int*)(bcat + 224);    // N
    int* rowstart = deg + N;               // N+1
    int* cursor   = rowstart + (N + 1);    // N
    int* csr      = cursor + N;            // M (src per slot)
    int* csrd     = csr + M;               // M (dst per slot)
    uintptr_t wsp = (uintptr_t)(csrd + M);
    wsp = (wsp + 15) & ~(uintptr_t)15;
    short* W1h = (short*)wsp;              // 256*128
    short* W1l = W1h + 256 * 128;
    short* W2h = W1l + 256 * 128;          // 256*256
    short* W2l = W2h + 256 * 256;
    short* Wth = W2l + 256 * 256;          // 222*256
    short* Wtl = Wth + 222 * 256;
    // overlays
    short* Xh  = (short*)B2;                       // N*128
    short* Xl  = Xh + (size_t)N * 128;             // N*128
    short* h1b = (short*)B2 + (size_t)N * 256;     // N*256 (stride 256)
    short* Sh  = (short*)B2;                       // N*256
    short* Sl  = Sh + (size_t)N * 256;             // N*256
    short* h2b = (short*)B1;                       // N*256 (stride 256)
    short* Th  = (short*)B2;                       // N*256
    short* Tl  = Th + (size_t)N * 256;             // N*256
    short* htb = (short*)B3;                       // N*224 (stride 224)
    float* ewt = B3 + (size_t)N * 112;             // M*4
    float* AGT = B2;                               // N*222

    float* out = (float*)d_out;

    const int B = 256;
    // --- CSR build ---
    init_kernel<<<(N + B - 1) / B, B, 0, stream>>>(deg, cursor, N);
    count_kernel<<<(E + B - 1) / B, B, 0, stream>>>(e_dst, deg, E);
    scan_kernel<<<1, 1024, 0, stream>>>(deg, rowstart, N);
    scatter_kernel<<<(M + B - 1) / B, B, 0, stream>>>(e_src, e_dst, rowstart, cursor, csr, csrd, E, N);
    // --- pack + split weights ---
    pack_w_kernel<<<(256 * 222 + B - 1) / B, B, 0, stream>>>(W_TL, W_YL, W_TS, W_TZ,
                                                             b_TL, b_YL, b_TS, b_TZ, Wcat, bcat);
    split_bt_kernel<<<(256 * 128 + B - 1) / B, B, 0, stream>>>(W1, W1h, W1l, 128, 256, 7);
    split_bt_kernel<<<(256 * 256 + B - 1) / B, B, 0, stream>>>(W2, W2h, W2l, 256, 256, 8);
    split_bt_kernel<<<(222 * 256 + B - 1) / B, B, 0, stream>>>(Wcat, Wth, Wtl, 256, 222, 8);
    // --- conv1 ---
    split_a_kernel<<<((N * 128 / 4) + B - 1) / B, B, 0, stream>>>(x, Xh, Xl, N * 128 / 4);
    {
        dim3 g((256 + NB - 1) / NB, (N + MB - 1) / MB);
        gemm_mfma_kernel<<<g, 256, 0, stream>>>(Xh, Xl, W1h, W1l, B1, h1b, 256, N, 128, 256);
    }
    node_alphas_kernel<<<(N * 8 + B - 1) / B, B, 0, stream>>>(B1, a1s, a1d, as1, ad1, N);
    ew8_kernel<<<(M + B - 1) / B, B, 0, stream>>>(as1, ad1, csr, csrd, B3, M);          // ew1 in B3
    gat_gather_kernel<<<(N + 3) / 4, 256, 0, stream>>>(h1b, B3, rowstart, csr, b1, B1, N, 1); // AG1 in B1
    // --- conv2 ---
    split_a_kernel<<<((N * 256 / 4) + B - 1) / B, B, 0, stream>>>(B1, Sh, Sl, N * 256 / 4);
    {
        dim3 g((256 + NB - 1) / NB, (N + MB - 1) / MB);
        gemm_mfma_kernel<<<g, 256, 0, stream>>>(Sh, Sl, W2h, W2l, B3, h2b, 256, N, 256, 256);
    }
    node_alphas_kernel<<<(N * 8 + B - 1) / B, B, 0, stream>>>(B3, a2s, a2d, as2, ad2, N);
    ew8_kernel<<<(M + B - 1) / B, B, 0, stream>>>(as2, ad2, csr, csrd, B2, M);          // ew2 in B2
    gat_gather_kernel<<<(N + 3) / 4, 256, 0, stream>>>(h2b, B2, rowstart, csr, b2, B3, N, 0); // AG2 in B3
    // --- task heads (fused GEMM over concat 222 cols) ---
    split_a_kernel<<<((N * 256 / 4) + B - 1) / B, B, 0, stream>>>(B3, Th, Tl, N * 256 / 4);
    {
        dim3 g((222 + NB - 1) / NB, (N + MB - 1) / MB);
        gemm_mfma_kernel<<<g, 256, 0, stream>>>(Th, Tl, Wth, Wtl, B1, htb, 224, N, 256, 222); // ht in B1
    }
    task_alphas_kernel<<<(N * 4 + B - 1) / B, B, 0, stream>>>(B1, as_TL, ad_TL, as_YL, ad_YL,
                                                              as_TS, ad_TS, as_TZ, ad_TZ, ast, adt, N);
    ew4_kernel<<<(M + B - 1) / B, B, 0, stream>>>(ast, adt, csr, csrd, ewt, M);
    task_gather_kernel<<<(N + 3) / 4, 256, 0, stream>>>(htb, ewt, rowstart, csr, bcat, AGT, N);
    logsoftmax_kernel<<<(N + 3) / 4, 256, 0, stream>>>(AGT, out, N);
}

// Round 6
// 710.392 us; speedup vs baseline: 1.8562x; 1.1646x over previous
//
#include <hip/hip_runtime.h>
#include <math.h>

// ---------------------------------------------------------------------------
// MultiTaskGAT: 2x GATConv(8 heads x 32ch, concat) + 4 task heads (1 head)
// N=50000 nodes, E=800000 edges (+N self loops), F_IN=128, DH=256.
//
// R2: unnormalized softmax (exp hoisted), single-pass gathers.
// R3: gather loops unrolled x4 (latency/MLP).
// R4: GEMMs -> bf16 MFMA hi/lo split (error ~2^-16 rel).
// R5: gathers read bf16 feature rows (bytes-bound fix).
// R6: fusion round. (a) attention alphas are LINEAR in transformed feats:
//     alpha = x @ (W @ A) -> folded as extra GEMM B-columns; GEMM emits
//     als/ald directly and writes ONLY bf16 feature rows (no fp32 C at all).
//     (b) gathers write hi/lo bf16 directly (next GEMM's A operand) —
//     split_a kernels for intermediates deleted. (c) log_softmax fused into
//     task_gather via 4-task butterfly shuffles (one wave holds the row).
// ---------------------------------------------------------------------------

#define NEG_SLOPE 0.2f

typedef short s8v __attribute__((ext_vector_type(8)));
typedef short s4v __attribute__((ext_vector_type(4)));
typedef float f4v __attribute__((ext_vector_type(4)));

__device__ __forceinline__ short f2bf(float x) {
    unsigned u = __float_as_uint(x);
    u += 0x7fffu + ((u >> 16) & 1u);
    return (short)(u >> 16);
}
__device__ __forceinline__ float bf2f(short b) {
    return __uint_as_float(((unsigned)(unsigned short)b) << 16);
}
__device__ __forceinline__ void split2(float x, short& h, short& l) {
    h = f2bf(x);
    l = f2bf(x - bf2f(h));
}
__device__ __forceinline__ float4 bf4_to_f4(s4v v) {
    return make_float4(bf2f(v[0]), bf2f(v[1]), bf2f(v[2]), bf2f(v[3]));
}

// ---------------- CSR build ----------------

__global__ void init_kernel(int* __restrict__ deg, int* __restrict__ cursor, int n) {
    int i = blockIdx.x * blockDim.x + threadIdx.x;
    if (i < n) { deg[i] = 1; cursor[i] = 0; }   // deg starts at 1: self loop
}

__global__ void count_kernel(const int* __restrict__ dst, int* __restrict__ deg, int E) {
    int i = blockIdx.x * blockDim.x + threadIdx.x;
    if (i < E) atomicAdd(&deg[dst[i]], 1);
}

__global__ __launch_bounds__(1024) void scan_kernel(const int* __restrict__ deg,
                                                    int* __restrict__ rowstart, int n) {
    __shared__ int sh[1024];
    __shared__ int carry_sh;
    if (threadIdx.x == 0) { carry_sh = 0; rowstart[0] = 0; }
    __syncthreads();
    for (int base = 0; base < n; base += 8192) {
        int vals[8];
        int sum = 0;
        int i0 = base + threadIdx.x * 8;
        #pragma unroll
        for (int j = 0; j < 8; ++j) {
            int i = i0 + j;
            int v = (i < n) ? deg[i] : 0;
            sum += v;
            vals[j] = sum;               // local inclusive
        }
        sh[threadIdx.x] = sum;
        __syncthreads();
        for (int off = 1; off < 1024; off <<= 1) {
            int t = (threadIdx.x >= (unsigned)off) ? sh[threadIdx.x - off] : 0;
            __syncthreads();
            sh[threadIdx.x] += t;
            __syncthreads();
        }
        int excl = sh[threadIdx.x] - sum + carry_sh;
        #pragma unroll
        for (int j = 0; j < 8; ++j) {
            int i = i0 + j;
            if (i < n) rowstart[i + 1] = excl + vals[j];
        }
        __syncthreads();
        if (threadIdx.x == 0) carry_sh += sh[1023];
        __syncthreads();
    }
}

__global__ void scatter_kernel(const int* __restrict__ src, const int* __restrict__ dst,
                               const int* __restrict__ rowstart, int* __restrict__ cursor,
                               int* __restrict__ csr, int* __restrict__ csrd, int E, int n) {
    int i = blockIdx.x * blockDim.x + threadIdx.x;
    if (i >= E + n) return;
    int s, d;
    if (i < E) { s = src[i]; d = dst[i]; }
    else       { s = d = i - E; }          // self loop
    int p = atomicAdd(&cursor[d], 1);
    int slot = rowstart[d] + p;
    csr[slot] = s;
    csrd[slot] = d;
}

// ---------------- hi/lo bf16 splits ----------------

__global__ void split_a_kernel(const float* __restrict__ A, short* __restrict__ Ah,
                               short* __restrict__ Al, int n4) {
    int i = blockIdx.x * blockDim.x + threadIdx.x;
    if (i >= n4) return;
    float4 v = ((const float4*)A)[i];
    short h0, h1, h2, h3, l0, l1, l2, l3;
    split2(v.x, h0, l0); split2(v.y, h1, l1);
    split2(v.z, h2, l2); split2(v.w, h3, l3);
    s4v hv = {h0, h1, h2, h3};
    s4v lv = {l0, l1, l2, l3};
    ((s4v*)Ah)[i] = hv;
    ((s4v*)Al)[i] = lv;
}

// B[K][Nc] fp32 -> Bt[n][k] bf16 hi/lo (k-contiguous for MFMA B-fragments)
__global__ void split_bt_kernel(const float* __restrict__ B, short* __restrict__ Bh,
                                short* __restrict__ Bl, int K, int Nc, int kshift) {
    int idx = blockIdx.x * blockDim.x + threadIdx.x;
    if (idx >= Nc * K) return;
    int n = idx >> kshift;          // K is a power of two (128/256)
    int k = idx & (K - 1);
    float v = B[(size_t)k * Nc + n];
    short h, l; split2(v, h, l);
    Bh[idx] = h;
    Bl[idx] = l;
}

// fold alphas into extra B-columns: col Nfeat+j (j<8: a_s head j, j>=8: a_d)
// Wfold[k][j] = sum_{c<32} W[k][32*(j&7)+c] * a[(j&7)][c]
__global__ void fold_alpha8_kernel(const float* __restrict__ W,
                                   const float* __restrict__ a_s, const float* __restrict__ a_d,
                                   short* __restrict__ Bth, short* __restrict__ Btl,
                                   int K, int Nfeat) {
    int idx = blockIdx.x * blockDim.x + threadIdx.x;
    if (idx >= K * 16) return;
    int j = idx / K, k = idx % K;
    int h = j & 7;
    const float* av = ((j < 8) ? a_s : a_d) + h * 32;
    const float* wp = W + (size_t)k * 256 + h * 32;
    float s = 0.f;
    #pragma unroll
    for (int c = 0; c < 32; ++c) s += wp[c] * av[c];
    short hi, lo; split2(s, hi, lo);
    size_t off = (size_t)(Nfeat + j) * K + k;
    Bth[off] = hi; Btl[off] = lo;
}

// task version: 4 tasks, segments CO/CL over 222 channels, K=256
__global__ void fold_alpha4_kernel(const float* __restrict__ Wcat,
                                   const float* __restrict__ ascat, const float* __restrict__ adcat,
                                   short* __restrict__ Bth, short* __restrict__ Btl) {
    int idx = blockIdx.x * blockDim.x + threadIdx.x;
    if (idx >= 256 * 8) return;
    int j = idx >> 8, k = idx & 255;
    const int CO[4] = {0, 12, 42, 102};
    const int CL[4] = {12, 30, 60, 120};
    int t = j & 3;
    const float* av = ((j < 4) ? ascat : adcat) + CO[t];
    const float* wp = Wcat + (size_t)k * 222 + CO[t];
    float s = 0.f;
    for (int c = 0; c < CL[t]; ++c) s += wp[c] * av[c];
    short hi, lo; split2(s, hi, lo);
    size_t off = (size_t)(222 + j) * 256 + k;
    Bth[off] = hi; Btl[off] = lo;
}

// ---------------- bf16 MFMA GEMM + fused alpha output ----------------------
// A hi/lo bf16 [M][K]; B transposed hi/lo bf16 [NcExt][K] where cols
// [0,Nfeat) are features (written as bf16, stride cb_stride) and cols
// [Nfeat, NcExt) are folded alphas -> als/ald fp32 (nsplit per array).

#define MB 128
#define NB 64
#define KS 32

__global__ __launch_bounds__(256) void gemm_mfma_kernel(
        const short* __restrict__ Ah_g, const short* __restrict__ Al_g,
        const short* __restrict__ Bth_g, const short* __restrict__ Btl_g,
        short* __restrict__ Cb, int cb_stride,
        float* __restrict__ als, float* __restrict__ ald, int nsplit,
        int M, int K, int Nfeat, int NcExt) {
    __shared__ __align__(16) short Ah[MB][40];
    __shared__ __align__(16) short Al[MB][40];
    __shared__ __align__(16) short Bh[NB][40];
    __shared__ __align__(16) short Bl[NB][40];

    int t = threadIdx.x;
    int lane = t & 63, w = t >> 6;
    int quad = lane >> 4, l16 = lane & 15;
    int row0 = blockIdx.y * MB, col0 = blockIdx.x * NB;

    f4v acc[2][4];
    #pragma unroll
    for (int mt = 0; mt < 2; ++mt)
        #pragma unroll
        for (int nt = 0; nt < 4; ++nt)
            acc[mt][nt] = (f4v){0.f, 0.f, 0.f, 0.f};

    for (int k0 = 0; k0 < K; k0 += KS) {
        __syncthreads();
        #pragma unroll
        for (int i = 0; i < 2; ++i) {
            int u = i * 256 + t;
            int r = u >> 2, kk = (u & 3) * 8;
            int gr = row0 + r;
            s8v vh = {0, 0, 0, 0, 0, 0, 0, 0};
            s8v vl = {0, 0, 0, 0, 0, 0, 0, 0};
            if (gr < M) {
                vh = *(const s8v*)(Ah_g + (size_t)gr * K + k0 + kk);
                vl = *(const s8v*)(Al_g + (size_t)gr * K + k0 + kk);
            }
            *(s8v*)&Ah[r][kk] = vh;
            *(s8v*)&Al[r][kk] = vl;
        }
        {
            int n = t >> 2, kk = (t & 3) * 8;
            int gc = col0 + n;
            s8v vh = {0, 0, 0, 0, 0, 0, 0, 0};
            s8v vl = {0, 0, 0, 0, 0, 0, 0, 0};
            if (gc < NcExt) {
                vh = *(const s8v*)(Bth_g + (size_t)gc * K + k0 + kk);
                vl = *(const s8v*)(Btl_g + (size_t)gc * K + k0 + kk);
            }
            *(s8v*)&Bh[n][kk] = vh;
            *(s8v*)&Bl[n][kk] = vl;
        }
        __syncthreads();

        int kb = quad * 8;
        s8v a_h[2], a_l[2], b_h[4], b_l[4];
        #pragma unroll
        for (int mt = 0; mt < 2; ++mt) {
            int r = w * 32 + mt * 16 + l16;
            a_h[mt] = *(const s8v*)&Ah[r][kb];
            a_l[mt] = *(const s8v*)&Al[r][kb];
        }
        #pragma unroll
        for (int nt = 0; nt < 4; ++nt) {
            int c = nt * 16 + l16;
            b_h[nt] = *(const s8v*)&Bh[c][kb];
            b_l[nt] = *(const s8v*)&Bl[c][kb];
        }
        #pragma unroll
        for (int mt = 0; mt < 2; ++mt)
            #pragma unroll
            for (int nt = 0; nt < 4; ++nt) {
                acc[mt][nt] = __builtin_amdgcn_mfma_f32_16x16x32_bf16(
                    a_h[mt], b_h[nt], acc[mt][nt], 0, 0, 0);
                acc[mt][nt] = __builtin_amdgcn_mfma_f32_16x16x32_bf16(
                    a_h[mt], b_l[nt], acc[mt][nt], 0, 0, 0);
                acc[mt][nt] = __builtin_amdgcn_mfma_f32_16x16x32_bf16(
                    a_l[mt], b_h[nt], acc[mt][nt], 0, 0, 0);
            }
    }

    // epilogue: C/D layout col=lane&15, row=quad*4+reg
    #pragma unroll
    for (int mt = 0; mt < 2; ++mt) {
        #pragma unroll
        for (int nt = 0; nt < 4; ++nt) {
            int gc = col0 + nt * 16 + l16;
            if (gc >= NcExt) continue;
            #pragma unroll
            for (int r = 0; r < 4; ++r) {
                int gr = row0 + w * 32 + mt * 16 + quad * 4 + r;
                if (gr >= M) continue;
                float v = acc[mt][nt][r];
                if (gc < Nfeat) {
                    Cb[(size_t)gr * cb_stride + gc] = f2bf(v);
                } else {
                    int j = gc - Nfeat;
                    if (j < nsplit)            als[(size_t)gr * nsplit + j] = v;
                    else if (j < 2 * nsplit)   ald[(size_t)gr * nsplit + (j - nsplit)] = v;
                }
            }
        }
    }
}

// ---------------- edge weights, 8 heads (unnormalized softmax) -------------

__global__ void ew8_kernel(const float* __restrict__ als, const float* __restrict__ ald,
                           const int* __restrict__ csr, const int* __restrict__ csrd,
                           float* __restrict__ ew, int M) {
    int i = blockIdx.x * blockDim.x + threadIdx.x;
    if (i >= M) return;
    int s = csr[i], d = csrd[i];
    const float4* ap = (const float4*)(als + (size_t)s * 8);
    const float4* dp = (const float4*)(ald + (size_t)d * 8);
    float4 a0 = ap[0], a1 = ap[1];
    float4 d0 = dp[0], d1 = dp[1];
    float v[8] = {a0.x + d0.x, a0.y + d0.y, a0.z + d0.z, a0.w + d0.w,
                  a1.x + d1.x, a1.y + d1.y, a1.z + d1.z, a1.w + d1.w};
    float w[8];
    #pragma unroll
    for (int h = 0; h < 8; ++h) {
        float x = v[h];
        x = (x > 0.f) ? x : NEG_SLOPE * x;
        w[h] = __expf(x);
    }
    float4* op = (float4*)(ew + (size_t)i * 8);
    op[0] = make_float4(w[0], w[1], w[2], w[3]);
    op[1] = make_float4(w[4], w[5], w[6], w[7]);
}

// ---------------- GAT gather (8 heads x 32 ch), one wave per dst -----------
// bf16 rows in, hi/lo bf16 rows out (next GEMM's A operand). Unroll x4.

__global__ __launch_bounds__(256) void gat_gather_kernel(
        const short* __restrict__ hb, const float* __restrict__ ew,
        const int* __restrict__ rowstart, const int* __restrict__ csr,
        const float* __restrict__ bias, short* __restrict__ oh, short* __restrict__ ol,
        int n, int elu) {
    int wid  = blockIdx.x * 4 + (threadIdx.x >> 6);
    int lane = threadIdx.x & 63;
    if (wid >= n) return;
    int row = rowstart[wid];
    int deg = rowstart[wid + 1] - row;
    int hp = lane >> 3;
    int ch = lane * 4;
    const int* cp = csr + row;
    const float* wp = ew + (size_t)row * 8 + hp;

    float4 acc = {0.f, 0.f, 0.f, 0.f};
    float wsum = 0.f;
    int e = 0;
    for (; e + 4 <= deg; e += 4) {
        int s0 = cp[e], s1 = cp[e + 1], s2 = cp[e + 2], s3 = cp[e + 3];
        float w0 = wp[(size_t)(e + 0) * 8];
        float w1 = wp[(size_t)(e + 1) * 8];
        float w2 = wp[(size_t)(e + 2) * 8];
        float w3 = wp[(size_t)(e + 3) * 8];
        float4 h0 = bf4_to_f4(*(const s4v*)(hb + (size_t)s0 * 256 + ch));
        float4 h1 = bf4_to_f4(*(const s4v*)(hb + (size_t)s1 * 256 + ch));
        float4 h2 = bf4_to_f4(*(const s4v*)(hb + (size_t)s2 * 256 + ch));
        float4 h3 = bf4_to_f4(*(const s4v*)(hb + (size_t)s3 * 256 + ch));
        acc.x += w0 * h0.x + w1 * h1.x + w2 * h2.x + w3 * h3.x;
        acc.y += w0 * h0.y + w1 * h1.y + w2 * h2.y + w3 * h3.y;
        acc.z += w0 * h0.z + w1 * h1.z + w2 * h2.z + w3 * h3.z;
        acc.w += w0 * h0.w + w1 * h1.w + w2 * h2.w + w3 * h3.w;
        wsum += (w0 + w1) + (w2 + w3);
    }
    for (; e < deg; ++e) {
        int s0 = cp[e];
        float w0 = wp[(size_t)e * 8];
        float4 h0 = bf4_to_f4(*(const s4v*)(hb + (size_t)s0 * 256 + ch));
        acc.x += w0 * h0.x; acc.y += w0 * h0.y;
        acc.z += w0 * h0.z; acc.w += w0 * h0.w;
        wsum += w0;
    }
    float inv = 1.f / (wsum + 1e-16f);
    float4 b4 = *(const float4*)(bias + ch);
    float v[4] = {acc.x * inv + b4.x, acc.y * inv + b4.y,
                  acc.z * inv + b4.z, acc.w * inv + b4.w};
    if (elu) {
        #pragma unroll
        for (int j = 0; j < 4; ++j)
            v[j] = (v[j] > 0.f) ? v[j] : __expf(v[j]) - 1.f;
    }
    s4v hv, lv;
    #pragma unroll
    for (int j = 0; j < 4; ++j) { short hh, ll; split2(v[j], hh, ll); hv[j] = hh; lv[j] = ll; }
    *(s4v*)(oh + (size_t)wid * 256 + ch) = hv;
    *(s4v*)(ol + (size_t)wid * 256 + ch) = lv;
}

// ---------------- task-head packing (Wcat, bcat, ascat, adcat) -------------

__global__ void pack_w_kernel(const float* __restrict__ wTL, const float* __restrict__ wYL,
                              const float* __restrict__ wTS, const float* __restrict__ wTZ,
                              const float* __restrict__ bTL, const float* __restrict__ bYL,
                              const float* __restrict__ bTS, const float* __restrict__ bTZ,
                              const float* __restrict__ asTL, const float* __restrict__ asYL,
                              const float* __restrict__ asTS, const float* __restrict__ asTZ,
                              const float* __restrict__ adTL, const float* __restrict__ adYL,
                              const float* __restrict__ adTS, const float* __restrict__ adTZ,
                              float* __restrict__ Wcat, float* __restrict__ bcat,
                              float* __restrict__ ascat, float* __restrict__ adcat) {
    int idx = blockIdx.x * blockDim.x + threadIdx.x;
    if (idx < 256 * 222) {
        int r = idx / 222, c = idx % 222;
        float v;
        if (c < 12)       v = wTL[r * 12 + c];
        else if (c < 42)  v = wYL[r * 30 + (c - 12)];
        else if (c < 102) v = wTS[r * 60 + (c - 42)];
        else              v = wTZ[r * 120 + (c - 102)];
        Wcat[idx] = v;
    }
    if (idx < 222) {
        bcat[idx]  = (idx < 12) ? bTL[idx] : (idx < 42) ? bYL[idx - 12]
                   : (idx < 102) ? bTS[idx - 42] : bTZ[idx - 102];
        ascat[idx] = (idx < 12) ? asTL[idx] : (idx < 42) ? asYL[idx - 12]
                   : (idx < 102) ? asTS[idx - 42] : asTZ[idx - 102];
        adcat[idx] = (idx < 12) ? adTL[idx] : (idx < 42) ? adYL[idx - 12]
                   : (idx < 102) ? adTS[idx - 42] : adTZ[idx - 102];
    }
}

// ---------------- edge weights, 4 tasks ----------------

__global__ void ew4_kernel(const float* __restrict__ ast, const float* __restrict__ adt,
                           const int* __restrict__ csr, const int* __restrict__ csrd,
                           float* __restrict__ ew, int M) {
    int i = blockIdx.x * blockDim.x + threadIdx.x;
    if (i >= M) return;
    int s = csr[i], d = csrd[i];
    float4 a = *(const float4*)(ast + (size_t)s * 4);
    float4 b = *(const float4*)(adt + (size_t)d * 4);
    float v[4] = {a.x + b.x, a.y + b.y, a.z + b.z, a.w + b.w};
    float w[4];
    #pragma unroll
    for (int t = 0; t < 4; ++t) {
        float x = v[t];
        x = (x > 0.f) ? x : NEG_SLOPE * x;
        w[t] = __expf(x);
    }
    *(float4*)(ew + (size_t)i * 4) = make_float4(w[0], w[1], w[2], w[3]);
}

// ---------------- 4-task gather + fused log_softmax ------------------------
// bf16 rows (stride 224). One wave holds all 222 channels of a dst; per-task
// max/sum via 4-vector butterfly shuffles; writes d_out directly.

__global__ __launch_bounds__(256) void task_gather_ls_kernel(
        const short* __restrict__ htb, const float* __restrict__ ew,
        const int* __restrict__ rowstart, const int* __restrict__ csr,
        const float* __restrict__ bcat, float* __restrict__ out, int n) {
    int wid  = blockIdx.x * 4 + (threadIdx.x >> 6);
    int lane = threadIdx.x & 63;
    if (wid >= n) return;
    int row = rowstart[wid];
    int deg = rowstart[wid + 1] - row;
    int ch0 = lane * 4;
    const int CO[4] = {0, 12, 42, 102};
    const int CL[4] = {12, 30, 60, 120};

    int tj[4]; bool valj[4];
    #pragma unroll
    for (int j = 0; j < 4; ++j) {
        int ch = ch0 + j;
        valj[j] = (ch < 222);
        tj[j] = (ch >= 102) ? 3 : (ch >= 42) ? 2 : (ch >= 12) ? 1 : 0;
    }
    int t_lo = tj[0], t_hi = tj[3];
    bool use_lo[4];
    #pragma unroll
    for (int j = 0; j < 4; ++j) use_lo[j] = (tj[j] == t_lo);

    const int* cp = csr + row;
    const float* wp = ew + (size_t)row * 4;

    float acc[4] = {0.f, 0.f, 0.f, 0.f};
    float ws_lo = 0.f, ws_hi = 0.f;
    int e = 0;
    for (; e + 4 <= deg; e += 4) {
        int s0 = cp[e], s1 = cp[e + 1], s2 = cp[e + 2], s3 = cp[e + 3];
        float wlo0 = wp[(size_t)(e + 0) * 4 + t_lo], whi0 = wp[(size_t)(e + 0) * 4 + t_hi];
        float wlo1 = wp[(size_t)(e + 1) * 4 + t_lo], whi1 = wp[(size_t)(e + 1) * 4 + t_hi];
        float wlo2 = wp[(size_t)(e + 2) * 4 + t_lo], whi2 = wp[(size_t)(e + 2) * 4 + t_hi];
        float wlo3 = wp[(size_t)(e + 3) * 4 + t_lo], whi3 = wp[(size_t)(e + 3) * 4 + t_hi];
        float4 h0 = bf4_to_f4(*(const s4v*)(htb + (size_t)s0 * 224 + ch0));
        float4 h1 = bf4_to_f4(*(const s4v*)(htb + (size_t)s1 * 224 + ch0));
        float4 h2 = bf4_to_f4(*(const s4v*)(htb + (size_t)s2 * 224 + ch0));
        float4 h3 = bf4_to_f4(*(const s4v*)(htb + (size_t)s3 * 224 + ch0));
        ws_lo += (wlo0 + wlo1) + (wlo2 + wlo3);
        ws_hi += (whi0 + whi1) + (whi2 + whi3);
        float hv0[4] = {h0.x, h0.y, h0.z, h0.w};
        float hv1[4] = {h1.x, h1.y, h1.z, h1.w};
        float hv2[4] = {h2.x, h2.y, h2.z, h2.w};
        float hv3[4] = {h3.x, h3.y, h3.z, h3.w};
        #pragma unroll
        for (int j = 0; j < 4; ++j) {
            float w0 = use_lo[j] ? wlo0 : whi0;
            float w1 = use_lo[j] ? wlo1 : whi1;
            float w2 = use_lo[j] ? wlo2 : whi2;
            float w3 = use_lo[j] ? wlo3 : whi3;
            acc[j] += w0 * hv0[j] + w1 * hv1[j] + w2 * hv2[j] + w3 * hv3[j];
        }
    }
    for (; e < deg; ++e) {
        int s = cp[e];
        float wlo = wp[(size_t)e * 4 + t_lo];
        float whi = wp[(size_t)e * 4 + t_hi];
        ws_lo += wlo; ws_hi += whi;
        float4 h0 = bf4_to_f4(*(const s4v*)(htb + (size_t)s * 224 + ch0));
        float hv[4] = {h0.x, h0.y, h0.z, h0.w};
        #pragma unroll
        for (int j = 0; j < 4; ++j) {
            float w = use_lo[j] ? wlo : whi;
            acc[j] += w * hv[j];
        }
    }
    float inv_lo = 1.f / (ws_lo + 1e-16f);
    float inv_hi = 1.f / (ws_hi + 1e-16f);

    // normalized logits + fused 4-task log_softmax
    float vout[4];
    float m4[4] = {-1e30f, -1e30f, -1e30f, -1e30f};
    #pragma unroll
    for (int j = 0; j < 4; ++j) {
        if (valj[j]) {
            float v = acc[j] * (use_lo[j] ? inv_lo : inv_hi) + bcat[ch0 + j];
            vout[j] = v;
            m4[tj[j]] = fmaxf(m4[tj[j]], v);
        } else vout[j] = 0.f;
    }
    #pragma unroll
    for (int off = 1; off < 64; off <<= 1)
        #pragma unroll
        for (int t = 0; t < 4; ++t) m4[t] = fmaxf(m4[t], __shfl_xor(m4[t], off));
    float s4a[4] = {0.f, 0.f, 0.f, 0.f};
    #pragma unroll
    for (int j = 0; j < 4; ++j)
        if (valj[j]) s4a[tj[j]] += __expf(vout[j] - m4[tj[j]]);
    #pragma unroll
    for (int off = 1; off < 64; off <<= 1)
        #pragma unroll
        for (int t = 0; t < 4; ++t) s4a[t] += __shfl_xor(s4a[t], off);
    float lse[4];
    #pragma unroll
    for (int t = 0; t < 4; ++t) lse[t] = m4[t] + __logf(s4a[t]);
    #pragma unroll
    for (int j = 0; j < 4; ++j) {
        if (!valj[j]) continue;
        int t = tj[j];
        out[(size_t)CO[t] * n + (size_t)wid * CL[t] + (ch0 + j - CO[t])] = vout[j] - lse[t];
    }
}

// ---------------- launcher ----------------

extern "C" void kernel_launch(void* const* d_in, const int* in_sizes, int n_in,
                              void* d_out, int out_size, void* d_ws, size_t ws_size,
                              hipStream_t stream) {
    const float* x   = (const float*)d_in[0];
    const int*   ei  = (const int*)d_in[1];
    const float* W1  = (const float*)d_in[2];
    const float* a1s = (const float*)d_in[3];
    const float* a1d = (const float*)d_in[4];
    const float* b1  = (const float*)d_in[5];
    const float* W2  = (const float*)d_in[6];
    const float* a2s = (const float*)d_in[7];
    const float* a2d = (const float*)d_in[8];
    const float* b2  = (const float*)d_in[9];
    const float* W_TL = (const float*)d_in[10]; const float* as_TL = (const float*)d_in[11];
    const float* ad_TL = (const float*)d_in[12]; const float* b_TL = (const float*)d_in[13];
    const float* W_YL = (const float*)d_in[14]; const float* as_YL = (const float*)d_in[15];
    const float* ad_YL = (const float*)d_in[16]; const float* b_YL = (const float*)d_in[17];
    const float* W_TS = (const float*)d_in[18]; const float* as_TS = (const float*)d_in[19];
    const float* ad_TS = (const float*)d_in[20]; const float* b_TS = (const float*)d_in[21];
    const float* W_TZ = (const float*)d_in[22]; const float* as_TZ = (const float*)d_in[23];
    const float* ad_TZ = (const float*)d_in[24]; const float* b_TZ = (const float*)d_in[25];

    const int N = in_sizes[0] / 128;
    const int E = in_sizes[1] / 2;
    const int* e_src = ei;
    const int* e_dst = ei + E;
    const int M = E + N;                   // CSR slots incl. self loops

    float* ws = (float*)d_ws;
    // Phase plan (B1/B2/B3 each N*256 floats = N*512 shorts):
    //  B1: Xh|Xl (N*128sh ea) -> Sh|Sl (N*256sh ea) -> Th|Tl
    //  B2: h1b -> h2b (stride 256sh) -> htb (stride 224sh)   [first half]
    //  B3: ew1 (M*8 f) -> ew2 -> ewt (M*4 f)
    float* B1   = ws;
    float* B2   = B1 + (size_t)N * 256;
    float* B3   = B2 + (size_t)N * 256;
    float* as1  = B3 + (size_t)N * 256;    // N*8
    float* ad1  = as1 + (size_t)N * 8;
    float* as2  = ad1 + (size_t)N * 8;
    float* ad2  = as2 + (size_t)N * 8;
    float* ast  = ad2 + (size_t)N * 8;     // N*4
    float* adt  = ast + (size_t)N * 4;
    float* Wcat = adt + (size_t)N * 4;     // 256*222
    float* bcat = Wcat + 256 * 222;        // 222 (+pad)
    float* ascat = bcat + 224;             // 222 (+pad)
    float* adcat = ascat + 224;            // 222 (+pad)
    int* deg      = (int*)(adcat + 224);   // N
    int* rowstart = deg + N;               // N+1
    int* cursor   = rowstart + (N + 1);    // N
    int* csr      = cursor + N;            // M (src per slot)
    int* csrd     = csr + M;               // M (dst per slot)
    uintptr_t wsp = (uintptr_t)(csrd + M);
    wsp = (wsp + 15) & ~(uintptr_t)15;
    short* W1h = (short*)wsp;              // 272*128 (256 feat + 16 alpha)
    short* W1l = W1h + 272 * 128;
    short* W2h = W1l + 272 * 128;          // 272*256
    short* W2l = W2h + 272 * 256;
    short* Wth = W2l + 272 * 256;          // 230*256 (222 feat + 8 alpha)
    short* Wtl = Wth + 230 * 256;
    // overlays
    short* Xh  = (short*)B1;                       // N*128
    short* Xl  = Xh + (size_t)N * 128;
    short* Sh  = (short*)B1;                       // N*256
    short* Sl  = Sh + (size_t)N * 256;
    short* Th  = (short*)B1;
    short* Tl  = Th + (size_t)N * 256;
    short* h1b = (short*)B2;                       // stride 256
    short* h2b = (short*)B2;                       // stride 256
    short* htb = (short*)B2;                       // stride 224
    float* ew1 = B3;                               // M*8
    float* ew2 = B3;                               // M*8
    float* ewt = B3;                               // M*4

    float* out = (float*)d_out;

    const int B = 256;
    // --- CSR build ---
    init_kernel<<<(N + B - 1) / B, B, 0, stream>>>(deg, cursor, N);
    count_kernel<<<(E + B - 1) / B, B, 0, stream>>>(e_dst, deg, E);
    scan_kernel<<<1, 1024, 0, stream>>>(deg, rowstart, N);
    scatter_kernel<<<(M + B - 1) / B, B, 0, stream>>>(e_src, e_dst, rowstart, cursor, csr, csrd, E, N);
    // --- pack + split + fold weights ---
    pack_w_kernel<<<(256 * 222 + B - 1) / B, B, 0, stream>>>(W_TL, W_YL, W_TS, W_TZ,
        b_TL, b_YL, b_TS, b_TZ, as_TL, as_YL, as_TS, as_TZ, ad_TL, ad_YL, ad_TS, ad_TZ,
        Wcat, bcat, ascat, adcat);
    split_bt_kernel<<<(256 * 128 + B - 1) / B, B, 0, stream>>>(W1, W1h, W1l, 128, 256, 7);
    split_bt_kernel<<<(256 * 256 + B - 1) / B, B, 0, stream>>>(W2, W2h, W2l, 256, 256, 8);
    split_bt_kernel<<<(222 * 256 + B - 1) / B, B, 0, stream>>>(Wcat, Wth, Wtl, 256, 222, 8);
    fold_alpha8_kernel<<<(128 * 16 + B - 1) / B, B, 0, stream>>>(W1, a1s, a1d, W1h, W1l, 128, 256);
    fold_alpha8_kernel<<<(256 * 16 + B - 1) / B, B, 0, stream>>>(W2, a2s, a2d, W2h, W2l, 256, 256);
    fold_alpha4_kernel<<<(256 * 8 + B - 1) / B, B, 0, stream>>>(Wcat, ascat, adcat, Wth, Wtl);
    // --- conv1: GEMM emits h1b bf16 + als1/ald1 directly ---
    split_a_kernel<<<((N * 128 / 4) + B - 1) / B, B, 0, stream>>>(x, Xh, Xl, N * 128 / 4);
    {
        dim3 g((272 + NB - 1) / NB, (N + MB - 1) / MB);
        gemm_mfma_kernel<<<g, 256, 0, stream>>>(Xh, Xl, W1h, W1l, h1b, 256,
                                                as1, ad1, 8, N, 128, 256, 272);
    }
    ew8_kernel<<<(M + B - 1) / B, B, 0, stream>>>(as1, ad1, csr, csrd, ew1, M);
    gat_gather_kernel<<<(N + 3) / 4, 256, 0, stream>>>(h1b, ew1, rowstart, csr, b1, Sh, Sl, N, 1);
    // --- conv2 ---
    {
        dim3 g((272 + NB - 1) / NB, (N + MB - 1) / MB);
        gemm_mfma_kernel<<<g, 256, 0, stream>>>(Sh, Sl, W2h, W2l, h2b, 256,
                                                as2, ad2, 8, N, 256, 256, 272);
    }
    ew8_kernel<<<(M + B - 1) / B, B, 0, stream>>>(as2, ad2, csr, csrd, ew2, M);
    gat_gather_kernel<<<(N + 3) / 4, 256, 0, stream>>>(h2b, ew2, rowstart, csr, b2, Th, Tl, N, 0);
    // --- task heads: GEMM emits htb bf16 + ast/adt ---
    {
        dim3 g((230 + NB - 1) / NB, (N + MB - 1) / MB);
        gemm_mfma_kernel<<<g, 256, 0, stream>>>(Th, Tl, Wth, Wtl, htb, 224,
                                                ast, adt, 4, N, 256, 222, 230);
    }
    ew4_kernel<<<(M + B - 1) / B, B, 0, stream>>>(ast, adt, csr, csrd, ewt, M);
    task_gather_ls_kernel<<<(N + 3) / 4, 256, 0, stream>>>(htb, ewt, rowstart, csr, bcat, out, N);
}

// Round 7
// 642.651 us; speedup vs baseline: 2.0519x; 1.1054x over previous
//
#include <hip/hip_runtime.h>
#include <math.h>

// ---------------------------------------------------------------------------
// MultiTaskGAT: 2x GATConv(8 heads x 32ch, concat) + 4 task heads (1 head)
// N=50000 nodes, E=800000 edges (+N self loops), F_IN=128, DH=256.
//
// R2: unnormalized softmax (exp hoisted), single-pass gathers.
// R3: gather loops unrolled x4 (latency/MLP).
// R4: GEMMs -> bf16 MFMA hi/lo split.
// R5: gathers read bf16 feature rows (bytes-bound fix).
// R6: alphas folded into GEMM B-columns; gathers emit GEMM A-operand;
//     log_softmax fused into task gather.
// R7: (a) fused-softmax epilogue de-LDS'd — R6 dynamic local-array indexing
//     (m4[tj[j]], CO[t]) was promoted to LDS (LDS_Block_Size=4096, 1.8M bank
//     conflicts): replaced with scalars + static select chains.
//     (b) A-operand is single bf16 (B stays hi/lo): 2 MFMA terms not 3 —
//     gather path already bf16, same error class; halves A staging.
// ---------------------------------------------------------------------------

#define NEG_SLOPE 0.2f

typedef short s8v __attribute__((ext_vector_type(8)));
typedef short s4v __attribute__((ext_vector_type(4)));
typedef float f4v __attribute__((ext_vector_type(4)));

__device__ __forceinline__ short f2bf(float x) {
    unsigned u = __float_as_uint(x);
    u += 0x7fffu + ((u >> 16) & 1u);
    return (short)(u >> 16);
}
__device__ __forceinline__ float bf2f(short b) {
    return __uint_as_float(((unsigned)(unsigned short)b) << 16);
}
__device__ __forceinline__ void split2(float x, short& h, short& l) {
    h = f2bf(x);
    l = f2bf(x - bf2f(h));
}
__device__ __forceinline__ float4 bf4_to_f4(s4v v) {
    return make_float4(bf2f(v[0]), bf2f(v[1]), bf2f(v[2]), bf2f(v[3]));
}

// ---------------- CSR build ----------------

__global__ void init_kernel(int* __restrict__ deg, int* __restrict__ cursor, int n) {
    int i = blockIdx.x * blockDim.x + threadIdx.x;
    if (i < n) { deg[i] = 1; cursor[i] = 0; }   // deg starts at 1: self loop
}

__global__ void count_kernel(const int* __restrict__ dst, int* __restrict__ deg, int E) {
    int i = blockIdx.x * blockDim.x + threadIdx.x;
    if (i < E) atomicAdd(&deg[dst[i]], 1);
}

__global__ __launch_bounds__(1024) void scan_kernel(const int* __restrict__ deg,
                                                    int* __restrict__ rowstart, int n) {
    __shared__ int sh[1024];
    __shared__ int carry_sh;
    if (threadIdx.x == 0) { carry_sh = 0; rowstart[0] = 0; }
    __syncthreads();
    for (int base = 0; base < n; base += 8192) {
        int vals[8];
        int sum = 0;
        int i0 = base + threadIdx.x * 8;
        #pragma unroll
        for (int j = 0; j < 8; ++j) {
            int i = i0 + j;
            int v = (i < n) ? deg[i] : 0;
            sum += v;
            vals[j] = sum;               // local inclusive
        }
        sh[threadIdx.x] = sum;
        __syncthreads();
        for (int off = 1; off < 1024; off <<= 1) {
            int t = (threadIdx.x >= (unsigned)off) ? sh[threadIdx.x - off] : 0;
            __syncthreads();
            sh[threadIdx.x] += t;
            __syncthreads();
        }
        int excl = sh[threadIdx.x] - sum + carry_sh;
        #pragma unroll
        for (int j = 0; j < 8; ++j) {
            int i = i0 + j;
            if (i < n) rowstart[i + 1] = excl + vals[j];
        }
        __syncthreads();
        if (threadIdx.x == 0) carry_sh += sh[1023];
        __syncthreads();
    }
}

__global__ void scatter_kernel(const int* __restrict__ src, const int* __restrict__ dst,
                               const int* __restrict__ rowstart, int* __restrict__ cursor,
                               int* __restrict__ csr, int* __restrict__ csrd, int E, int n) {
    int i = blockIdx.x * blockDim.x + threadIdx.x;
    if (i >= E + n) return;
    int s, d;
    if (i < E) { s = src[i]; d = dst[i]; }
    else       { s = d = i - E; }          // self loop
    int p = atomicAdd(&cursor[d], 1);
    int slot = rowstart[d] + p;
    csr[slot] = s;
    csrd[slot] = d;
}

// ---------------- bf16 conversions / splits ----------------

// fp32 -> bf16 (A operand; single bf16, no lo part)
__global__ void tobf_kernel(const float* __restrict__ A, short* __restrict__ Ah, int n4) {
    int i = blockIdx.x * blockDim.x + threadIdx.x;
    if (i >= n4) return;
    float4 v = ((const float4*)A)[i];
    s4v hv = {f2bf(v.x), f2bf(v.y), f2bf(v.z), f2bf(v.w)};
    ((s4v*)Ah)[i] = hv;
}

// B[K][Nc] fp32 -> Bt[n][k] bf16 hi/lo (k-contiguous for MFMA B-fragments)
__global__ void split_bt_kernel(const float* __restrict__ B, short* __restrict__ Bh,
                                short* __restrict__ Bl, int K, int Nc, int kshift) {
    int idx = blockIdx.x * blockDim.x + threadIdx.x;
    if (idx >= Nc * K) return;
    int n = idx >> kshift;          // K is a power of two (128/256)
    int k = idx & (K - 1);
    float v = B[(size_t)k * Nc + n];
    short h, l; split2(v, h, l);
    Bh[idx] = h;
    Bl[idx] = l;
}

// fold alphas into extra B-columns: col Nfeat+j (j<8: a_s head j, j>=8: a_d)
__global__ void fold_alpha8_kernel(const float* __restrict__ W,
                                   const float* __restrict__ a_s, const float* __restrict__ a_d,
                                   short* __restrict__ Bth, short* __restrict__ Btl,
                                   int K, int Nfeat) {
    int idx = blockIdx.x * blockDim.x + threadIdx.x;
    if (idx >= K * 16) return;
    int j = idx / K, k = idx % K;
    int h = j & 7;
    const float* av = ((j < 8) ? a_s : a_d) + h * 32;
    const float* wp = W + (size_t)k * 256 + h * 32;
    float s = 0.f;
    #pragma unroll
    for (int c = 0; c < 32; ++c) s += wp[c] * av[c];
    short hi, lo; split2(s, hi, lo);
    size_t off = (size_t)(Nfeat + j) * K + k;
    Bth[off] = hi; Btl[off] = lo;
}

// task version: 4 tasks, segments over 222 channels, K=256
__global__ void fold_alpha4_kernel(const float* __restrict__ Wcat,
                                   const float* __restrict__ ascat, const float* __restrict__ adcat,
                                   short* __restrict__ Bth, short* __restrict__ Btl) {
    int idx = blockIdx.x * blockDim.x + threadIdx.x;
    if (idx >= 256 * 8) return;
    int j = idx >> 8, k = idx & 255;
    const int CO[4] = {0, 12, 42, 102};
    const int CL[4] = {12, 30, 60, 120};
    int t = j & 3;
    const float* av = ((j < 4) ? ascat : adcat) + CO[t];
    const float* wp = Wcat + (size_t)k * 222 + CO[t];
    float s = 0.f;
    for (int c = 0; c < CL[t]; ++c) s += wp[c] * av[c];
    short hi, lo; split2(s, hi, lo);
    size_t off = (size_t)(222 + j) * 256 + k;
    Bth[off] = hi; Btl[off] = lo;
}

// ---------------- bf16 MFMA GEMM + fused alpha output ----------------------
// A bf16 [M][K] (single); B transposed hi/lo bf16 [NcExt][K]: cols [0,Nfeat)
// are features -> bf16 (stride cb_stride); [Nfeat,NcExt) folded alphas ->
// als/ald fp32 (nsplit per array). 2 MFMA terms: A*Bh + A*Bl.

#define MB 128
#define NB 64
#define KS 32

__global__ __launch_bounds__(256) void gemm_mfma_kernel(
        const short* __restrict__ Ah_g,
        const short* __restrict__ Bth_g, const short* __restrict__ Btl_g,
        short* __restrict__ Cb, int cb_stride,
        float* __restrict__ als, float* __restrict__ ald, int nsplit,
        int M, int K, int Nfeat, int NcExt) {
    __shared__ __align__(16) short Ah[MB][40];
    __shared__ __align__(16) short Bh[NB][40];
    __shared__ __align__(16) short Bl[NB][40];

    int t = threadIdx.x;
    int lane = t & 63, w = t >> 6;
    int quad = lane >> 4, l16 = lane & 15;
    int row0 = blockIdx.y * MB, col0 = blockIdx.x * NB;

    f4v acc[2][4];
    #pragma unroll
    for (int mt = 0; mt < 2; ++mt)
        #pragma unroll
        for (int nt = 0; nt < 4; ++nt)
            acc[mt][nt] = (f4v){0.f, 0.f, 0.f, 0.f};

    for (int k0 = 0; k0 < K; k0 += KS) {
        __syncthreads();
        // stage A: 128x32 bf16, 512 8-elem units, 2/thread
        #pragma unroll
        for (int i = 0; i < 2; ++i) {
            int u = i * 256 + t;
            int r = u >> 2, kk = (u & 3) * 8;
            int gr = row0 + r;
            s8v vh = {0, 0, 0, 0, 0, 0, 0, 0};
            if (gr < M) vh = *(const s8v*)(Ah_g + (size_t)gr * K + k0 + kk);
            *(s8v*)&Ah[r][kk] = vh;
        }
        // stage B hi+lo: 64x32 each, 1 unit/thread per array
        {
            int n = t >> 2, kk = (t & 3) * 8;
            int gc = col0 + n;
            s8v vh = {0, 0, 0, 0, 0, 0, 0, 0};
            s8v vl = {0, 0, 0, 0, 0, 0, 0, 0};
            if (gc < NcExt) {
                vh = *(const s8v*)(Bth_g + (size_t)gc * K + k0 + kk);
                vl = *(const s8v*)(Btl_g + (size_t)gc * K + k0 + kk);
            }
            *(s8v*)&Bh[n][kk] = vh;
            *(s8v*)&Bl[n][kk] = vl;
        }
        __syncthreads();

        int kb = quad * 8;
        s8v a_f[2], b_h[4], b_l[4];
        #pragma unroll
        for (int mt = 0; mt < 2; ++mt) {
            int r = w * 32 + mt * 16 + l16;
            a_f[mt] = *(const s8v*)&Ah[r][kb];
        }
        #pragma unroll
        for (int nt = 0; nt < 4; ++nt) {
            int c = nt * 16 + l16;
            b_h[nt] = *(const s8v*)&Bh[c][kb];
            b_l[nt] = *(const s8v*)&Bl[c][kb];
        }
        #pragma unroll
        for (int mt = 0; mt < 2; ++mt)
            #pragma unroll
            for (int nt = 0; nt < 4; ++nt) {
                acc[mt][nt] = __builtin_amdgcn_mfma_f32_16x16x32_bf16(
                    a_f[mt], b_h[nt], acc[mt][nt], 0, 0, 0);
                acc[mt][nt] = __builtin_amdgcn_mfma_f32_16x16x32_bf16(
                    a_f[mt], b_l[nt], acc[mt][nt], 0, 0, 0);
            }
    }

    // epilogue: C/D layout col=lane&15, row=quad*4+reg
    #pragma unroll
    for (int mt = 0; mt < 2; ++mt) {
        #pragma unroll
        for (int nt = 0; nt < 4; ++nt) {
            int gc = col0 + nt * 16 + l16;
            if (gc >= NcExt) continue;
            #pragma unroll
            for (int r = 0; r < 4; ++r) {
                int gr = row0 + w * 32 + mt * 16 + quad * 4 + r;
                if (gr >= M) continue;
                float v = acc[mt][nt][r];
                if (gc < Nfeat) {
                    Cb[(size_t)gr * cb_stride + gc] = f2bf(v);
                } else {
                    int j = gc - Nfeat;
                    if (j < nsplit)            als[(size_t)gr * nsplit + j] = v;
                    else if (j < 2 * nsplit)   ald[(size_t)gr * nsplit + (j - nsplit)] = v;
                }
            }
        }
    }
}

// ---------------- edge weights, 8 heads (unnormalized softmax) -------------

__global__ void ew8_kernel(const float* __restrict__ als, const float* __restrict__ ald,
                           const int* __restrict__ csr, const int* __restrict__ csrd,
                           float* __restrict__ ew, int M) {
    int i = blockIdx.x * blockDim.x + threadIdx.x;
    if (i >= M) return;
    int s = csr[i], d = csrd[i];
    const float4* ap = (const float4*)(als + (size_t)s * 8);
    const float4* dp = (const float4*)(ald + (size_t)d * 8);
    float4 a0 = ap[0], a1 = ap[1];
    float4 d0 = dp[0], d1 = dp[1];
    float v[8] = {a0.x + d0.x, a0.y + d0.y, a0.z + d0.z, a0.w + d0.w,
                  a1.x + d1.x, a1.y + d1.y, a1.z + d1.z, a1.w + d1.w};
    float w[8];
    #pragma unroll
    for (int h = 0; h < 8; ++h) {
        float x = v[h];
        x = (x > 0.f) ? x : NEG_SLOPE * x;
        w[h] = __expf(x);
    }
    float4* op = (float4*)(ew + (size_t)i * 8);
    op[0] = make_float4(w[0], w[1], w[2], w[3]);
    op[1] = make_float4(w[4], w[5], w[6], w[7]);
}

// ---------------- GAT gather (8 heads x 32 ch), one wave per dst -----------
// bf16 rows in, bf16 row out (next GEMM's A operand). Unroll x4.

__global__ __launch_bounds__(256) void gat_gather_kernel(
        const short* __restrict__ hb, const float* __restrict__ ew,
        const int* __restrict__ rowstart, const int* __restrict__ csr,
        const float* __restrict__ bias, short* __restrict__ oh, int n, int elu) {
    int wid  = blockIdx.x * 4 + (threadIdx.x >> 6);
    int lane = threadIdx.x & 63;
    if (wid >= n) return;
    int row = rowstart[wid];
    int deg = rowstart[wid + 1] - row;
    int hp = lane >> 3;
    int ch = lane * 4;
    const int* cp = csr + row;
    const float* wp = ew + (size_t)row * 8 + hp;

    float4 acc = {0.f, 0.f, 0.f, 0.f};
    float wsum = 0.f;
    int e = 0;
    for (; e + 4 <= deg; e += 4) {
        int s0 = cp[e], s1 = cp[e + 1], s2 = cp[e + 2], s3 = cp[e + 3];
        float w0 = wp[(size_t)(e + 0) * 8];
        float w1 = wp[(size_t)(e + 1) * 8];
        float w2 = wp[(size_t)(e + 2) * 8];
        float w3 = wp[(size_t)(e + 3) * 8];
        float4 h0 = bf4_to_f4(*(const s4v*)(hb + (size_t)s0 * 256 + ch));
        float4 h1 = bf4_to_f4(*(const s4v*)(hb + (size_t)s1 * 256 + ch));
        float4 h2 = bf4_to_f4(*(const s4v*)(hb + (size_t)s2 * 256 + ch));
        float4 h3 = bf4_to_f4(*(const s4v*)(hb + (size_t)s3 * 256 + ch));
        acc.x += w0 * h0.x + w1 * h1.x + w2 * h2.x + w3 * h3.x;
        acc.y += w0 * h0.y + w1 * h1.y + w2 * h2.y + w3 * h3.y;
        acc.z += w0 * h0.z + w1 * h1.z + w2 * h2.z + w3 * h3.z;
        acc.w += w0 * h0.w + w1 * h1.w + w2 * h2.w + w3 * h3.w;
        wsum += (w0 + w1) + (w2 + w3);
    }
    for (; e < deg; ++e) {
        int s0 = cp[e];
        float w0 = wp[(size_t)e * 8];
        float4 h0 = bf4_to_f4(*(const s4v*)(hb + (size_t)s0 * 256 + ch));
        acc.x += w0 * h0.x; acc.y += w0 * h0.y;
        acc.z += w0 * h0.z; acc.w += w0 * h0.w;
        wsum += w0;
    }
    float inv = 1.f / (wsum + 1e-16f);
    float4 b4 = *(const float4*)(bias + ch);
    float v[4] = {acc.x * inv + b4.x, acc.y * inv + b4.y,
                  acc.z * inv + b4.z, acc.w * inv + b4.w};
    if (elu) {
        #pragma unroll
        for (int j = 0; j < 4; ++j)
            v[j] = (v[j] > 0.f) ? v[j] : __expf(v[j]) - 1.f;
    }
    s4v hv = {f2bf(v[0]), f2bf(v[1]), f2bf(v[2]), f2bf(v[3])};
    *(s4v*)(oh + (size_t)wid * 256 + ch) = hv;
}

// ---------------- task-head packing (Wcat, bcat, ascat, adcat) -------------

__global__ void pack_w_kernel(const float* __restrict__ wTL, const float* __restrict__ wYL,
                              const float* __restrict__ wTS, const float* __restrict__ wTZ,
                              const float* __restrict__ bTL, const float* __restrict__ bYL,
                              const float* __restrict__ bTS, const float* __restrict__ bTZ,
                              const float* __restrict__ asTL, const float* __restrict__ asYL,
                              const float* __restrict__ asTS, const float* __restrict__ asTZ,
                              const float* __restrict__ adTL, const float* __restrict__ adYL,
                              const float* __restrict__ adTS, const float* __restrict__ adTZ,
                              float* __restrict__ Wcat, float* __restrict__ bcat,
                              float* __restrict__ ascat, float* __restrict__ adcat) {
    int idx = blockIdx.x * blockDim.x + threadIdx.x;
    if (idx < 256 * 222) {
        int r = idx / 222, c = idx % 222;
        float v;
        if (c < 12)       v = wTL[r * 12 + c];
        else if (c < 42)  v = wYL[r * 30 + (c - 12)];
        else if (c < 102) v = wTS[r * 60 + (c - 42)];
        else              v = wTZ[r * 120 + (c - 102)];
        Wcat[idx] = v;
    }
    if (idx < 222) {
        bcat[idx]  = (idx < 12) ? bTL[idx] : (idx < 42) ? bYL[idx - 12]
                   : (idx < 102) ? bTS[idx - 42] : bTZ[idx - 102];
        ascat[idx] = (idx < 12) ? asTL[idx] : (idx < 42) ? asYL[idx - 12]
                   : (idx < 102) ? asTS[idx - 42] : asTZ[idx - 102];
        adcat[idx] = (idx < 12) ? adTL[idx] : (idx < 42) ? adYL[idx - 12]
                   : (idx < 102) ? adTS[idx - 42] : adTZ[idx - 102];
    }
}

// ---------------- edge weights, 4 tasks ----------------

__global__ void ew4_kernel(const float* __restrict__ ast, const float* __restrict__ adt,
                           const int* __restrict__ csr, const int* __restrict__ csrd,
                           float* __restrict__ ew, int M) {
    int i = blockIdx.x * blockDim.x + threadIdx.x;
    if (i >= M) return;
    int s = csr[i], d = csrd[i];
    float4 a = *(const float4*)(ast + (size_t)s * 4);
    float4 b = *(const float4*)(adt + (size_t)d * 4);
    float v[4] = {a.x + b.x, a.y + b.y, a.z + b.z, a.w + b.w};
    float w[4];
    #pragma unroll
    for (int t = 0; t < 4; ++t) {
        float x = v[t];
        x = (x > 0.f) ? x : NEG_SLOPE * x;
        w[t] = __expf(x);
    }
    *(float4*)(ew + (size_t)i * 4) = make_float4(w[0], w[1], w[2], w[3]);
}

// ---------------- 4-task gather + fused log_softmax (register-only) --------
// bf16 rows (stride 224). NO dynamically-indexed local arrays — everything
// is scalars + static select chains (R6's m4[tj[j]] was promoted to LDS).

__device__ __forceinline__ float sel4(int t, float v0, float v1, float v2, float v3) {
    return (t == 0) ? v0 : (t == 1) ? v1 : (t == 2) ? v2 : v3;
}
__device__ __forceinline__ int sel4i(int t, int v0, int v1, int v2, int v3) {
    return (t == 0) ? v0 : (t == 1) ? v1 : (t == 2) ? v2 : v3;
}

__global__ __launch_bounds__(256) void task_gather_ls_kernel(
        const short* __restrict__ htb, const float* __restrict__ ew,
        const int* __restrict__ rowstart, const int* __restrict__ csr,
        const float* __restrict__ bcat, float* __restrict__ out, int n) {
    int wid  = blockIdx.x * 4 + (threadIdx.x >> 6);
    int lane = threadIdx.x & 63;
    if (wid >= n) return;
    int row = rowstart[wid];
    int deg = rowstart[wid + 1] - row;
    int ch0 = lane * 4;

    bool valj[4]; bool lo_j[4];
    int t_lo, t_hi;
    {
        int tj0 = (ch0 >= 102) ? 3 : (ch0 >= 42) ? 2 : (ch0 >= 12) ? 1 : 0;
        int ch3 = ch0 + 3;
        int tj3 = (ch3 >= 102) ? 3 : (ch3 >= 42) ? 2 : (ch3 >= 12) ? 1 : 0;
        t_lo = tj0; t_hi = tj3;
        #pragma unroll
        for (int j = 0; j < 4; ++j) {
            int ch = ch0 + j;
            valj[j] = (ch < 222);
            int tj = (ch >= 102) ? 3 : (ch >= 42) ? 2 : (ch >= 12) ? 1 : 0;
            lo_j[j] = (tj == t_lo);
        }
    }

    const int* cp = csr + row;
    const float* wp = ew + (size_t)row * 4;

    float acc[4] = {0.f, 0.f, 0.f, 0.f};
    float ws_lo = 0.f, ws_hi = 0.f;
    int e = 0;
    for (; e + 4 <= deg; e += 4) {
        int s0 = cp[e], s1 = cp[e + 1], s2 = cp[e + 2], s3 = cp[e + 3];
        float wlo0 = wp[(size_t)(e + 0) * 4 + t_lo], whi0 = wp[(size_t)(e + 0) * 4 + t_hi];
        float wlo1 = wp[(size_t)(e + 1) * 4 + t_lo], whi1 = wp[(size_t)(e + 1) * 4 + t_hi];
        float wlo2 = wp[(size_t)(e + 2) * 4 + t_lo], whi2 = wp[(size_t)(e + 2) * 4 + t_hi];
        float wlo3 = wp[(size_t)(e + 3) * 4 + t_lo], whi3 = wp[(size_t)(e + 3) * 4 + t_hi];
        float4 h0 = bf4_to_f4(*(const s4v*)(htb + (size_t)s0 * 224 + ch0));
        float4 h1 = bf4_to_f4(*(const s4v*)(htb + (size_t)s1 * 224 + ch0));
        float4 h2 = bf4_to_f4(*(const s4v*)(htb + (size_t)s2 * 224 + ch0));
        float4 h3 = bf4_to_f4(*(const s4v*)(htb + (size_t)s3 * 224 + ch0));
        ws_lo += (wlo0 + wlo1) + (wlo2 + wlo3);
        ws_hi += (whi0 + whi1) + (whi2 + whi3);
        float hv0[4] = {h0.x, h0.y, h0.z, h0.w};
        float hv1[4] = {h1.x, h1.y, h1.z, h1.w};
        float hv2[4] = {h2.x, h2.y, h2.z, h2.w};
        float hv3[4] = {h3.x, h3.y, h3.z, h3.w};
        #pragma unroll
        for (int j = 0; j < 4; ++j) {
            float w0 = lo_j[j] ? wlo0 : whi0;
            float w1 = lo_j[j] ? wlo1 : whi1;
            float w2 = lo_j[j] ? wlo2 : whi2;
            float w3 = lo_j[j] ? wlo3 : whi3;
            acc[j] += w0 * hv0[j] + w1 * hv1[j] + w2 * hv2[j] + w3 * hv3[j];
        }
    }
    for (; e < deg; ++e) {
        int s = cp[e];
        float wlo = wp[(size_t)e * 4 + t_lo];
        float whi = wp[(size_t)e * 4 + t_hi];
        ws_lo += wlo; ws_hi += whi;
        float4 h0 = bf4_to_f4(*(const s4v*)(htb + (size_t)s * 224 + ch0));
        float hv[4] = {h0.x, h0.y, h0.z, h0.w};
        #pragma unroll
        for (int j = 0; j < 4; ++j)
            acc[j] += (lo_j[j] ? wlo : whi) * hv[j];
    }
    float inv_lo = 1.f / (ws_lo + 1e-16f);
    float inv_hi = 1.f / (ws_hi + 1e-16f);

    // normalized logits; per-lane partial max for its lo/hi tasks
    float vout[4];
    float m_lo = -1e30f, m_hi = -1e30f;
    #pragma unroll
    for (int j = 0; j < 4; ++j) {
        float v = 0.f;
        if (valj[j]) {
            v = acc[j] * (lo_j[j] ? inv_lo : inv_hi) + bcat[ch0 + j];
            if (lo_j[j]) m_lo = fmaxf(m_lo, v); else m_hi = fmaxf(m_hi, v);
        }
        vout[j] = v;
    }
    // scatter partials into 4 task scalars (static selects), butterfly
    float m0 = -1e30f, m1 = -1e30f, m2 = -1e30f, m3 = -1e30f;
    m0 = (t_lo == 0) ? fmaxf(m0, m_lo) : m0;  m0 = (t_hi == 0) ? fmaxf(m0, m_hi) : m0;
    m1 = (t_lo == 1) ? fmaxf(m1, m_lo) : m1;  m1 = (t_hi == 1) ? fmaxf(m1, m_hi) : m1;
    m2 = (t_lo == 2) ? fmaxf(m2, m_lo) : m2;  m2 = (t_hi == 2) ? fmaxf(m2, m_hi) : m2;
    m3 = (t_lo == 3) ? fmaxf(m3, m_lo) : m3;  m3 = (t_hi == 3) ? fmaxf(m3, m_hi) : m3;
    #pragma unroll
    for (int off = 1; off < 64; off <<= 1) {
        m0 = fmaxf(m0, __shfl_xor(m0, off));
        m1 = fmaxf(m1, __shfl_xor(m1, off));
        m2 = fmaxf(m2, __shfl_xor(m2, off));
        m3 = fmaxf(m3, __shfl_xor(m3, off));
    }
    float mt_lo = sel4(t_lo, m0, m1, m2, m3);
    float mt_hi = sel4(t_hi, m0, m1, m2, m3);
    float s_lo = 0.f, s_hi = 0.f;
    #pragma unroll
    for (int j = 0; j < 4; ++j) {
        if (valj[j]) {
            if (lo_j[j]) s_lo += __expf(vout[j] - mt_lo);
            else         s_hi += __expf(vout[j] - mt_hi);
        }
    }
    float s0 = ((t_lo == 0) ? s_lo : 0.f) + ((t_hi == 0 && t_hi != t_lo) ? s_hi : 0.f);
    float s1 = ((t_lo == 1) ? s_lo : 0.f) + ((t_hi == 1 && t_hi != t_lo) ? s_hi : 0.f);
    float s2 = ((t_lo == 2) ? s_lo : 0.f) + ((t_hi == 2 && t_hi != t_lo) ? s_hi : 0.f);
    float s3 = ((t_lo == 3) ? s_lo : 0.f) + ((t_hi == 3 && t_hi != t_lo) ? s_hi : 0.f);
    #pragma unroll
    for (int off = 1; off < 64; off <<= 1) {
        s0 += __shfl_xor(s0, off);
        s1 += __shfl_xor(s1, off);
        s2 += __shfl_xor(s2, off);
        s3 += __shfl_xor(s3, off);
    }
    float l0 = m0 + __logf(s0), l1 = m1 + __logf(s1);
    float l2 = m2 + __logf(s2), l3 = m3 + __logf(s3);
    float lse_lo = sel4(t_lo, l0, l1, l2, l3);
    float lse_hi = sel4(t_hi, l0, l1, l2, l3);
    int co_lo = sel4i(t_lo, 0, 12, 42, 102), cl_lo = sel4i(t_lo, 12, 30, 60, 120);
    int co_hi = sel4i(t_hi, 0, 12, 42, 102), cl_hi = sel4i(t_hi, 12, 30, 60, 120);
    #pragma unroll
    for (int j = 0; j < 4; ++j) {
        if (!valj[j]) continue;
        int co = lo_j[j] ? co_lo : co_hi;
        int cl = lo_j[j] ? cl_lo : cl_hi;
        float lse = lo_j[j] ? lse_lo : lse_hi;
        out[(size_t)co * n + (size_t)wid * cl + (ch0 + j - co)] = vout[j] - lse;
    }
}

// ---------------- launcher ----------------

extern "C" void kernel_launch(void* const* d_in, const int* in_sizes, int n_in,
                              void* d_out, int out_size, void* d_ws, size_t ws_size,
                              hipStream_t stream) {
    const float* x   = (const float*)d_in[0];
    const int*   ei  = (const int*)d_in[1];
    const float* W1  = (const float*)d_in[2];
    const float* a1s = (const float*)d_in[3];
    const float* a1d = (const float*)d_in[4];
    const float* b1  = (const float*)d_in[5];
    const float* W2  = (const float*)d_in[6];
    const float* a2s = (const float*)d_in[7];
    const float* a2d = (const float*)d_in[8];
    const float* b2  = (const float*)d_in[9];
    const float* W_TL = (const float*)d_in[10]; const float* as_TL = (const float*)d_in[11];
    const float* ad_TL = (const float*)d_in[12]; const float* b_TL = (const float*)d_in[13];
    const float* W_YL = (const float*)d_in[14]; const float* as_YL = (const float*)d_in[15];
    const float* ad_YL = (const float*)d_in[16]; const float* b_YL = (const float*)d_in[17];
    const float* W_TS = (const float*)d_in[18]; const float* as_TS = (const float*)d_in[19];
    const float* ad_TS = (const float*)d_in[20]; const float* b_TS = (const float*)d_in[21];
    const float* W_TZ = (const float*)d_in[22]; const float* as_TZ = (const float*)d_in[23];
    const float* ad_TZ = (const float*)d_in[24]; const float* b_TZ = (const float*)d_in[25];

    const int N = in_sizes[0] / 128;
    const int E = in_sizes[1] / 2;
    const int* e_src = ei;
    const int* e_dst = ei + E;
    const int M = E + N;                   // CSR slots incl. self loops

    float* ws = (float*)d_ws;
    // Phase plan (B1/B2/B3 each N*256 floats = N*512 shorts):
    //  B1: Xh (N*128sh) -> Sh (N*256sh) -> Th (N*256sh)   [A operands]
    //  B2: h1b -> h2b (stride 256sh) -> htb (stride 224sh) [gather rows]
    //  B3: ew1 (M*8 f) -> ew2 -> ewt (M*4 f)
    float* B1   = ws;
    float* B2   = B1 + (size_t)N * 256;
    float* B3   = B2 + (size_t)N * 256;
    float* as1  = B3 + (size_t)N * 256;    // N*8
    float* ad1  = as1 + (size_t)N * 8;
    float* as2  = ad1 + (size_t)N * 8;
    float* ad2  = as2 + (size_t)N * 8;
    float* ast  = ad2 + (size_t)N * 8;     // N*4
    float* adt  = ast + (size_t)N * 4;
    float* Wcat = adt + (size_t)N * 4;     // 256*222
    float* bcat = Wcat + 256 * 222;        // 222 (+pad)
    float* ascat = bcat + 224;             // 222 (+pad)
    float* adcat = ascat + 224;            // 222 (+pad)
    int* deg      = (int*)(adcat + 224);   // N
    int* rowstart = deg + N;               // N+1
    int* cursor   = rowstart + (N + 1);    // N
    int* csr      = cursor + N;            // M (src per slot)
    int* csrd     = csr + M;               // M (dst per slot)
    uintptr_t wsp = (uintptr_t)(csrd + M);
    wsp = (wsp + 15) & ~(uintptr_t)15;
    short* W1h = (short*)wsp;              // 272*128 (256 feat + 16 alpha)
    short* W1l = W1h + 272 * 128;
    short* W2h = W1l + 272 * 128;          // 272*256
    short* W2l = W2h + 272 * 256;
    short* Wth = W2l + 272 * 256;          // 230*256 (222 feat + 8 alpha)
    short* Wtl = Wth + 230 * 256;
    // overlays
    short* Xh  = (short*)B1;                       // N*128
    short* Sh  = (short*)B1;                       // N*256
    short* Th  = (short*)B1;                       // N*256
    short* h1b = (short*)B2;                       // stride 256
    short* h2b = (short*)B2;                       // stride 256
    short* htb = (short*)B2;                       // stride 224
    float* ew1 = B3;                               // M*8
    float* ew2 = B3;                               // M*8
    float* ewt = B3;                               // M*4

    float* out = (float*)d_out;

    const int B = 256;
    // --- CSR build ---
    init_kernel<<<(N + B - 1) / B, B, 0, stream>>>(deg, cursor, N);
    count_kernel<<<(E + B - 1) / B, B, 0, stream>>>(e_dst, deg, E);
    scan_kernel<<<1, 1024, 0, stream>>>(deg, rowstart, N);
    scatter_kernel<<<(M + B - 1) / B, B, 0, stream>>>(e_src, e_dst, rowstart, cursor, csr, csrd, E, N);
    // --- pack + split + fold weights ---
    pack_w_kernel<<<(256 * 222 + B - 1) / B, B, 0, stream>>>(W_TL, W_YL, W_TS, W_TZ,
        b_TL, b_YL, b_TS, b_TZ, as_TL, as_YL, as_TS, as_TZ, ad_TL, ad_YL, ad_TS, ad_TZ,
        Wcat, bcat, ascat, adcat);
    split_bt_kernel<<<(256 * 128 + B - 1) / B, B, 0, stream>>>(W1, W1h, W1l, 128, 256, 7);
    split_bt_kernel<<<(256 * 256 + B - 1) / B, B, 0, stream>>>(W2, W2h, W2l, 256, 256, 8);
    split_bt_kernel<<<(222 * 256 + B - 1) / B, B, 0, stream>>>(Wcat, Wth, Wtl, 256, 222, 8);
    fold_alpha8_kernel<<<(128 * 16 + B - 1) / B, B, 0, stream>>>(W1, a1s, a1d, W1h, W1l, 128, 256);
    fold_alpha8_kernel<<<(256 * 16 + B - 1) / B, B, 0, stream>>>(W2, a2s, a2d, W2h, W2l, 256, 256);
    fold_alpha4_kernel<<<(256 * 8 + B - 1) / B, B, 0, stream>>>(Wcat, ascat, adcat, Wth, Wtl);
    // --- conv1: GEMM emits h1b bf16 + als1/ald1 directly ---
    tobf_kernel<<<((N * 128 / 4) + B - 1) / B, B, 0, stream>>>(x, Xh, N * 128 / 4);
    {
        dim3 g((272 + NB - 1) / NB, (N + MB - 1) / MB);
        gemm_mfma_kernel<<<g, 256, 0, stream>>>(Xh, W1h, W1l, h1b, 256,
                                                as1, ad1, 8, N, 128, 256, 272);
    }
    ew8_kernel<<<(M + B - 1) / B, B, 0, stream>>>(as1, ad1, csr, csrd, ew1, M);
    gat_gather_kernel<<<(N + 3) / 4, 256, 0, stream>>>(h1b, ew1, rowstart, csr, b1, Sh, N, 1);
    // --- conv2 ---
    {
        dim3 g((272 + NB - 1) / NB, (N + MB - 1) / MB);
        gemm_mfma_kernel<<<g, 256, 0, stream>>>(Sh, W2h, W2l, h2b, 256,
                                                as2, ad2, 8, N, 256, 256, 272);
    }
    ew8_kernel<<<(M + B - 1) / B, B, 0, stream>>>(as2, ad2, csr, csrd, ew2, M);
    gat_gather_kernel<<<(N + 3) / 4, 256, 0, stream>>>(h2b, ew2, rowstart, csr, b2, Th, N, 0);
    // --- task heads: GEMM emits htb bf16 + ast/adt ---
    {
        dim3 g((230 + NB - 1) / NB, (N + MB - 1) / MB);
        gemm_mfma_kernel<<<g, 256, 0, stream>>>(Th, Wth, Wtl, htb, 224,
                                                ast, adt, 4, N, 256, 222, 230);
    }
    ew4_kernel<<<(M + B - 1) / B, B, 0, stream>>>(ast, adt, csr, csrd, ewt, M);
    task_gather_ls_kernel<<<(N + 3) / 4, 256, 0, stream>>>(htb, ewt, rowstart, csr, bcat, out, N);
}

// Round 8
// 629.571 us; speedup vs baseline: 2.0945x; 1.0208x over previous
//
#include <hip/hip_runtime.h>
#include <math.h>

// ---------------------------------------------------------------------------
// MultiTaskGAT: 2x GATConv(8 heads x 32ch, concat) + 4 task heads (1 head)
// N=50000 nodes, E=800000 edges (+N self loops), F_IN=128, DH=256.
//
// R2: unnormalized softmax (exp hoisted), single-pass gathers.
// R3: gather loops unrolled x4 (latency/MLP).
// R4: GEMMs -> bf16 MFMA hi/lo split.
// R5: gathers read bf16 feature rows.
// R6: alphas folded into GEMM B-columns; gathers emit GEMM A-operand;
//     log_softmax fused into task gather.
// R7: fused-softmax epilogue de-LDS'd; A-operand single bf16 (2-term MFMA).
// R8: gather addressing scalarized (readfirstlane src -> SALU row math,
//     saddr gathers), CSR rows padded to x4 (aligned int4 index loads, no
//     tail loop; pad slots s=-1 -> weight 0), shuffle-based scan kernel.
// ---------------------------------------------------------------------------

#define NEG_SLOPE 0.2f

typedef short s8v __attribute__((ext_vector_type(8)));
typedef short s4v __attribute__((ext_vector_type(4)));
typedef float f4v __attribute__((ext_vector_type(4)));

__device__ __forceinline__ short f2bf(float x) {
    unsigned u = __float_as_uint(x);
    u += 0x7fffu + ((u >> 16) & 1u);
    return (short)(u >> 16);
}
__device__ __forceinline__ float bf2f(short b) {
    return __uint_as_float(((unsigned)(unsigned short)b) << 16);
}
__device__ __forceinline__ void split2(float x, short& h, short& l) {
    h = f2bf(x);
    l = f2bf(x - bf2f(h));
}
__device__ __forceinline__ float4 bf4_to_f4(s4v v) {
    return make_float4(bf2f(v[0]), bf2f(v[1]), bf2f(v[2]), bf2f(v[3]));
}
__device__ __forceinline__ int rfl_clamp(int v) {
    int s = __builtin_amdgcn_readfirstlane(v);
    return s < 0 ? 0 : s;      // pad slots are -1 -> read row 0 (weight 0)
}

// ---------------- CSR build ----------------

__global__ void init_kernel(int* __restrict__ deg, int* __restrict__ cursor, int n) {
    int i = blockIdx.x * blockDim.x + threadIdx.x;
    if (i < n) { deg[i] = 1; cursor[i] = 0; }   // deg starts at 1: self loop
}

__global__ void count_kernel(const int* __restrict__ dst, int* __restrict__ deg, int E) {
    int i = blockIdx.x * blockDim.x + threadIdx.x;
    if (i < E) atomicAdd(&deg[dst[i]], 1);
}

// scan of padded degrees ((deg+3)&~3) — shuffle-based, 3 barriers/iter
__global__ __launch_bounds__(1024) void scan_kernel(const int* __restrict__ deg,
                                                    int* __restrict__ rowstart, int n) {
    __shared__ int wsum[16];
    __shared__ int carry_sh;
    int lane = threadIdx.x & 63, wv = threadIdx.x >> 6;
    if (threadIdx.x == 0) { carry_sh = 0; rowstart[0] = 0; }
    __syncthreads();
    for (int base = 0; base < n; base += 8192) {
        int vals[8];
        int sum = 0;
        int i0 = base + threadIdx.x * 8;
        #pragma unroll
        for (int j = 0; j < 8; ++j) {
            int i = i0 + j;
            int v = (i < n) ? ((deg[i] + 3) & ~3) : 0;
            sum += v;
            vals[j] = sum;               // local inclusive
        }
        int incl = sum;
        #pragma unroll
        for (int off = 1; off < 64; off <<= 1) {
            int t = __shfl_up(incl, off);
            if (lane >= off) incl += t;
        }
        if (lane == 63) wsum[wv] = incl;
        __syncthreads();
        if (wv == 0) {
            int s = (lane < 16) ? wsum[lane] : 0;
            #pragma unroll
            for (int off = 1; off < 16; off <<= 1) {
                int t = __shfl_up(s, off);
                if (lane >= off) s += t;
            }
            if (lane < 16) wsum[lane] = s;
        }
        __syncthreads();
        int wexcl = (wv == 0) ? 0 : wsum[wv - 1];
        int excl = carry_sh + wexcl + (incl - sum);
        #pragma unroll
        for (int j = 0; j < 8; ++j) {
            int i = i0 + j;
            if (i < n) rowstart[i + 1] = excl + vals[j];
        }
        __syncthreads();
        if (threadIdx.x == 0) carry_sh += wsum[15];
        __syncthreads();
    }
}

__global__ void scatter_kernel(const int* __restrict__ src, const int* __restrict__ dst,
                               const int* __restrict__ rowstart, int* __restrict__ cursor,
                               int* __restrict__ csr, int* __restrict__ csrd, int E, int n) {
    int i = blockIdx.x * blockDim.x + threadIdx.x;
    if (i >= E + n) return;
    int s, d;
    if (i < E) { s = src[i]; d = dst[i]; }
    else       { s = d = i - E; }          // self loop
    int p = atomicAdd(&cursor[d], 1);
    int slot = rowstart[d] + p;
    csr[slot] = s;
    csrd[slot] = d;
}

// ---------------- bf16 conversions / splits ----------------

__global__ void tobf_kernel(const float* __restrict__ A, short* __restrict__ Ah, int n4) {
    int i = blockIdx.x * blockDim.x + threadIdx.x;
    if (i >= n4) return;
    float4 v = ((const float4*)A)[i];
    s4v hv = {f2bf(v.x), f2bf(v.y), f2bf(v.z), f2bf(v.w)};
    ((s4v*)Ah)[i] = hv;
}

// B[K][Nc] fp32 -> Bt[n][k] bf16 hi/lo (k-contiguous for MFMA B-fragments)
__global__ void split_bt_kernel(const float* __restrict__ B, short* __restrict__ Bh,
                                short* __restrict__ Bl, int K, int Nc, int kshift) {
    int idx = blockIdx.x * blockDim.x + threadIdx.x;
    if (idx >= Nc * K) return;
    int n = idx >> kshift;          // K is a power of two (128/256)
    int k = idx & (K - 1);
    float v = B[(size_t)k * Nc + n];
    short h, l; split2(v, h, l);
    Bh[idx] = h;
    Bl[idx] = l;
}

// fold alphas into extra B-columns: col Nfeat+j (j<8: a_s head j, j>=8: a_d)
__global__ void fold_alpha8_kernel(const float* __restrict__ W,
                                   const float* __restrict__ a_s, const float* __restrict__ a_d,
                                   short* __restrict__ Bth, short* __restrict__ Btl,
                                   int K, int Nfeat) {
    int idx = blockIdx.x * blockDim.x + threadIdx.x;
    if (idx >= K * 16) return;
    int j = idx / K, k = idx % K;
    int h = j & 7;
    const float* av = ((j < 8) ? a_s : a_d) + h * 32;
    const float* wp = W + (size_t)k * 256 + h * 32;
    float s = 0.f;
    #pragma unroll
    for (int c = 0; c < 32; ++c) s += wp[c] * av[c];
    short hi, lo; split2(s, hi, lo);
    size_t off = (size_t)(Nfeat + j) * K + k;
    Bth[off] = hi; Btl[off] = lo;
}

// task version: 4 tasks, segments over 222 channels, K=256
__global__ void fold_alpha4_kernel(const float* __restrict__ Wcat,
                                   const float* __restrict__ ascat, const float* __restrict__ adcat,
                                   short* __restrict__ Bth, short* __restrict__ Btl) {
    int idx = blockIdx.x * blockDim.x + threadIdx.x;
    if (idx >= 256 * 8) return;
    int j = idx >> 8, k = idx & 255;
    const int CO[4] = {0, 12, 42, 102};
    const int CL[4] = {12, 30, 60, 120};
    int t = j & 3;
    const float* av = ((j < 4) ? ascat : adcat) + CO[t];
    const float* wp = Wcat + (size_t)k * 222 + CO[t];
    float s = 0.f;
    for (int c = 0; c < CL[t]; ++c) s += wp[c] * av[c];
    short hi, lo; split2(s, hi, lo);
    size_t off = (size_t)(222 + j) * 256 + k;
    Bth[off] = hi; Btl[off] = lo;
}

// ---------------- bf16 MFMA GEMM + fused alpha output ----------------------

#define MB 128
#define NB 64
#define KS 32

__global__ __launch_bounds__(256) void gemm_mfma_kernel(
        const short* __restrict__ Ah_g,
        const short* __restrict__ Bth_g, const short* __restrict__ Btl_g,
        short* __restrict__ Cb, int cb_stride,
        float* __restrict__ als, float* __restrict__ ald, int nsplit,
        int M, int K, int Nfeat, int NcExt) {
    __shared__ __align__(16) short Ah[MB][40];
    __shared__ __align__(16) short Bh[NB][40];
    __shared__ __align__(16) short Bl[NB][40];

    int t = threadIdx.x;
    int lane = t & 63, w = t >> 6;
    int quad = lane >> 4, l16 = lane & 15;
    int row0 = blockIdx.y * MB, col0 = blockIdx.x * NB;

    f4v acc[2][4];
    #pragma unroll
    for (int mt = 0; mt < 2; ++mt)
        #pragma unroll
        for (int nt = 0; nt < 4; ++nt)
            acc[mt][nt] = (f4v){0.f, 0.f, 0.f, 0.f};

    for (int k0 = 0; k0 < K; k0 += KS) {
        __syncthreads();
        #pragma unroll
        for (int i = 0; i < 2; ++i) {
            int u = i * 256 + t;
            int r = u >> 2, kk = (u & 3) * 8;
            int gr = row0 + r;
            s8v vh = {0, 0, 0, 0, 0, 0, 0, 0};
            if (gr < M) vh = *(const s8v*)(Ah_g + (size_t)gr * K + k0 + kk);
            *(s8v*)&Ah[r][kk] = vh;
        }
        {
            int n = t >> 2, kk = (t & 3) * 8;
            int gc = col0 + n;
            s8v vh = {0, 0, 0, 0, 0, 0, 0, 0};
            s8v vl = {0, 0, 0, 0, 0, 0, 0, 0};
            if (gc < NcExt) {
                vh = *(const s8v*)(Bth_g + (size_t)gc * K + k0 + kk);
                vl = *(const s8v*)(Btl_g + (size_t)gc * K + k0 + kk);
            }
            *(s8v*)&Bh[n][kk] = vh;
            *(s8v*)&Bl[n][kk] = vl;
        }
        __syncthreads();

        int kb = quad * 8;
        s8v a_f[2], b_h[4], b_l[4];
        #pragma unroll
        for (int mt = 0; mt < 2; ++mt) {
            int r = w * 32 + mt * 16 + l16;
            a_f[mt] = *(const s8v*)&Ah[r][kb];
        }
        #pragma unroll
        for (int nt = 0; nt < 4; ++nt) {
            int c = nt * 16 + l16;
            b_h[nt] = *(const s8v*)&Bh[c][kb];
            b_l[nt] = *(const s8v*)&Bl[c][kb];
        }
        #pragma unroll
        for (int mt = 0; mt < 2; ++mt)
            #pragma unroll
            for (int nt = 0; nt < 4; ++nt) {
                acc[mt][nt] = __builtin_amdgcn_mfma_f32_16x16x32_bf16(
                    a_f[mt], b_h[nt], acc[mt][nt], 0, 0, 0);
                acc[mt][nt] = __builtin_amdgcn_mfma_f32_16x16x32_bf16(
                    a_f[mt], b_l[nt], acc[mt][nt], 0, 0, 0);
            }
    }

    // epilogue: C/D layout col=lane&15, row=quad*4+reg
    #pragma unroll
    for (int mt = 0; mt < 2; ++mt) {
        #pragma unroll
        for (int nt = 0; nt < 4; ++nt) {
            int gc = col0 + nt * 16 + l16;
            if (gc >= NcExt) continue;
            #pragma unroll
            for (int r = 0; r < 4; ++r) {
                int gr = row0 + w * 32 + mt * 16 + quad * 4 + r;
                if (gr >= M) continue;
                float v = acc[mt][nt][r];
                if (gc < Nfeat) {
                    Cb[(size_t)gr * cb_stride + gc] = f2bf(v);
                } else {
                    int j = gc - Nfeat;
                    if (j < nsplit)            als[(size_t)gr * nsplit + j] = v;
                    else if (j < 2 * nsplit)   ald[(size_t)gr * nsplit + (j - nsplit)] = v;
                }
            }
        }
    }
}

// ---------------- edge weights, 8 heads (unnormalized softmax) -------------
// pad slots (s<0) get zero weights.

__global__ void ew8_kernel(const float* __restrict__ als, const float* __restrict__ ald,
                           const int* __restrict__ csr, const int* __restrict__ csrd,
                           float* __restrict__ ew, int M4) {
    int i = blockIdx.x * blockDim.x + threadIdx.x;
    if (i >= M4) return;
    int s = csr[i], d = csrd[i];
    float4* op = (float4*)(ew + (size_t)i * 8);
    if (s < 0) {
        op[0] = make_float4(0.f, 0.f, 0.f, 0.f);
        op[1] = make_float4(0.f, 0.f, 0.f, 0.f);
        return;
    }
    const float4* ap = (const float4*)(als + (size_t)s * 8);
    const float4* dp = (const float4*)(ald + (size_t)d * 8);
    float4 a0 = ap[0], a1 = ap[1];
    float4 d0 = dp[0], d1 = dp[1];
    float v[8] = {a0.x + d0.x, a0.y + d0.y, a0.z + d0.z, a0.w + d0.w,
                  a1.x + d1.x, a1.y + d1.y, a1.z + d1.z, a1.w + d1.w};
    float w[8];
    #pragma unroll
    for (int h = 0; h < 8; ++h) {
        float x = v[h];
        x = (x > 0.f) ? x : NEG_SLOPE * x;
        w[h] = __expf(x);
    }
    op[0] = make_float4(w[0], w[1], w[2], w[3]);
    op[1] = make_float4(w[4], w[5], w[6], w[7]);
}

// ---------------- GAT gather (8 heads x 32 ch), one wave per dst -----------
// Padded rows (x4): aligned int4 index loads, scalarized src, no tail.

__global__ __launch_bounds__(256) void gat_gather_kernel(
        const short* __restrict__ hb, const float* __restrict__ ew,
        const int* __restrict__ rowstart, const int* __restrict__ csr,
        const float* __restrict__ bias, short* __restrict__ oh, int n, int elu) {
    int wid  = blockIdx.x * 4 + (threadIdx.x >> 6);
    int lane = threadIdx.x & 63;
    if (wid >= n) return;
    int row = rowstart[wid];
    int pdeg = rowstart[wid + 1] - row;
    int hp = lane >> 3;
    int ch = lane * 4;
    const int* cp = csr + row;
    const float* wp = ew + (size_t)row * 8 + hp;

    float4 acc = {0.f, 0.f, 0.f, 0.f};
    float wsum = 0.f;
    for (int e = 0; e < pdeg; e += 4) {
        int4 sv = *(const int4*)(cp + e);          // 16B-aligned (rows padded)
        int s0 = rfl_clamp(sv.x);
        int s1 = rfl_clamp(sv.y);
        int s2 = rfl_clamp(sv.z);
        int s3 = rfl_clamp(sv.w);
        float w0 = wp[(size_t)(e + 0) * 8];
        float w1 = wp[(size_t)(e + 1) * 8];
        float w2 = wp[(size_t)(e + 2) * 8];
        float w3 = wp[(size_t)(e + 3) * 8];
        float4 h0 = bf4_to_f4(*(const s4v*)(hb + (size_t)s0 * 256 + ch));
        float4 h1 = bf4_to_f4(*(const s4v*)(hb + (size_t)s1 * 256 + ch));
        float4 h2 = bf4_to_f4(*(const s4v*)(hb + (size_t)s2 * 256 + ch));
        float4 h3 = bf4_to_f4(*(const s4v*)(hb + (size_t)s3 * 256 + ch));
        acc.x += w0 * h0.x + w1 * h1.x + w2 * h2.x + w3 * h3.x;
        acc.y += w0 * h0.y + w1 * h1.y + w2 * h2.y + w3 * h3.y;
        acc.z += w0 * h0.z + w1 * h1.z + w2 * h2.z + w3 * h3.z;
        acc.w += w0 * h0.w + w1 * h1.w + w2 * h2.w + w3 * h3.w;
        wsum += (w0 + w1) + (w2 + w3);
    }
    float inv = 1.f / (wsum + 1e-16f);
    float4 b4 = *(const float4*)(bias + ch);
    float v[4] = {acc.x * inv + b4.x, acc.y * inv + b4.y,
                  acc.z * inv + b4.z, acc.w * inv + b4.w};
    if (elu) {
        #pragma unroll
        for (int j = 0; j < 4; ++j)
            v[j] = (v[j] > 0.f) ? v[j] : __expf(v[j]) - 1.f;
    }
    s4v hv = {f2bf(v[0]), f2bf(v[1]), f2bf(v[2]), f2bf(v[3])};
    *(s4v*)(oh + (size_t)wid * 256 + ch) = hv;
}

// ---------------- task-head packing (Wcat, bcat, ascat, adcat) -------------

__global__ void pack_w_kernel(const float* __restrict__ wTL, const float* __restrict__ wYL,
                              const float* __restrict__ wTS, const float* __restrict__ wTZ,
                              const float* __restrict__ bTL, const float* __restrict__ bYL,
                              const float* __restrict__ bTS, const float* __restrict__ bTZ,
                              const float* __restrict__ asTL, const float* __restrict__ asYL,
                              const float* __restrict__ asTS, const float* __restrict__ asTZ,
                              const float* __restrict__ adTL, const float* __restrict__ adYL,
                              const float* __restrict__ adTS, const float* __restrict__ adTZ,
                              float* __restrict__ Wcat, float* __restrict__ bcat,
                              float* __restrict__ ascat, float* __restrict__ adcat) {
    int idx = blockIdx.x * blockDim.x + threadIdx.x;
    if (idx < 256 * 222) {
        int r = idx / 222, c = idx % 222;
        float v;
        if (c < 12)       v = wTL[r * 12 + c];
        else if (c < 42)  v = wYL[r * 30 + (c - 12)];
        else if (c < 102) v = wTS[r * 60 + (c - 42)];
        else              v = wTZ[r * 120 + (c - 102)];
        Wcat[idx] = v;
    }
    if (idx < 222) {
        bcat[idx]  = (idx < 12) ? bTL[idx] : (idx < 42) ? bYL[idx - 12]
                   : (idx < 102) ? bTS[idx - 42] : bTZ[idx - 102];
        ascat[idx] = (idx < 12) ? asTL[idx] : (idx < 42) ? asYL[idx - 12]
                   : (idx < 102) ? asTS[idx - 42] : asTZ[idx - 102];
        adcat[idx] = (idx < 12) ? adTL[idx] : (idx < 42) ? adYL[idx - 12]
                   : (idx < 102) ? adTS[idx - 42] : adTZ[idx - 102];
    }
}

// ---------------- edge weights, 4 tasks ----------------

__global__ void ew4_kernel(const float* __restrict__ ast, const float* __restrict__ adt,
                           const int* __restrict__ csr, const int* __restrict__ csrd,
                           float* __restrict__ ew, int M4) {
    int i = blockIdx.x * blockDim.x + threadIdx.x;
    if (i >= M4) return;
    int s = csr[i], d = csrd[i];
    if (s < 0) {
        *(float4*)(ew + (size_t)i * 4) = make_float4(0.f, 0.f, 0.f, 0.f);
        return;
    }
    float4 a = *(const float4*)(ast + (size_t)s * 4);
    float4 b = *(const float4*)(adt + (size_t)d * 4);
    float v[4] = {a.x + b.x, a.y + b.y, a.z + b.z, a.w + b.w};
    float w[4];
    #pragma unroll
    for (int t = 0; t < 4; ++t) {
        float x = v[t];
        x = (x > 0.f) ? x : NEG_SLOPE * x;
        w[t] = __expf(x);
    }
    *(float4*)(ew + (size_t)i * 4) = make_float4(w[0], w[1], w[2], w[3]);
}

// ---------------- 4-task gather + fused log_softmax (register-only) --------

__device__ __forceinline__ float sel4(int t, float v0, float v1, float v2, float v3) {
    return (t == 0) ? v0 : (t == 1) ? v1 : (t == 2) ? v2 : v3;
}
__device__ __forceinline__ int sel4i(int t, int v0, int v1, int v2, int v3) {
    return (t == 0) ? v0 : (t == 1) ? v1 : (t == 2) ? v2 : v3;
}

__global__ __launch_bounds__(256) void task_gather_ls_kernel(
        const short* __restrict__ htb, const float* __restrict__ ew,
        const int* __restrict__ rowstart, const int* __restrict__ csr,
        const float* __restrict__ bcat, float* __restrict__ out, int n) {
    int wid  = blockIdx.x * 4 + (threadIdx.x >> 6);
    int lane = threadIdx.x & 63;
    if (wid >= n) return;
    int row = rowstart[wid];
    int pdeg = rowstart[wid + 1] - row;
    int ch0 = lane * 4;

    bool valj[4]; bool lo_j[4];
    int t_lo, t_hi;
    {
        int tj0 = (ch0 >= 102) ? 3 : (ch0 >= 42) ? 2 : (ch0 >= 12) ? 1 : 0;
        int ch3 = ch0 + 3;
        int tj3 = (ch3 >= 102) ? 3 : (ch3 >= 42) ? 2 : (ch3 >= 12) ? 1 : 0;
        t_lo = tj0; t_hi = tj3;
        #pragma unroll
        for (int j = 0; j < 4; ++j) {
            int ch = ch0 + j;
            valj[j] = (ch < 222);
            int tj = (ch >= 102) ? 3 : (ch >= 42) ? 2 : (ch >= 12) ? 1 : 0;
            lo_j[j] = (tj == t_lo);
        }
    }

    const int* cp = csr + row;
    const float* wp = ew + (size_t)row * 4;

    float acc[4] = {0.f, 0.f, 0.f, 0.f};
    float ws_lo = 0.f, ws_hi = 0.f;
    for (int e = 0; e < pdeg; e += 4) {
        int4 sv = *(const int4*)(cp + e);
        int s0 = rfl_clamp(sv.x);
        int s1 = rfl_clamp(sv.y);
        int s2 = rfl_clamp(sv.z);
        int s3 = rfl_clamp(sv.w);
        float wlo0 = wp[(size_t)(e + 0) * 4 + t_lo], whi0 = wp[(size_t)(e + 0) * 4 + t_hi];
        float wlo1 = wp[(size_t)(e + 1) * 4 + t_lo], whi1 = wp[(size_t)(e + 1) * 4 + t_hi];
        float wlo2 = wp[(size_t)(e + 2) * 4 + t_lo], whi2 = wp[(size_t)(e + 2) * 4 + t_hi];
        float wlo3 = wp[(size_t)(e + 3) * 4 + t_lo], whi3 = wp[(size_t)(e + 3) * 4 + t_hi];
        float4 h0 = bf4_to_f4(*(const s4v*)(htb + (size_t)s0 * 224 + ch0));
        float4 h1 = bf4_to_f4(*(const s4v*)(htb + (size_t)s1 * 224 + ch0));
        float4 h2 = bf4_to_f4(*(const s4v*)(htb + (size_t)s2 * 224 + ch0));
        float4 h3 = bf4_to_f4(*(const s4v*)(htb + (size_t)s3 * 224 + ch0));
        ws_lo += (wlo0 + wlo1) + (wlo2 + wlo3);
        ws_hi += (whi0 + whi1) + (whi2 + whi3);
        float hv0[4] = {h0.x, h0.y, h0.z, h0.w};
        float hv1[4] = {h1.x, h1.y, h1.z, h1.w};
        float hv2[4] = {h2.x, h2.y, h2.z, h2.w};
        float hv3[4] = {h3.x, h3.y, h3.z, h3.w};
        #pragma unroll
        for (int j = 0; j < 4; ++j) {
            float w0 = lo_j[j] ? wlo0 : whi0;
            float w1 = lo_j[j] ? wlo1 : whi1;
            float w2 = lo_j[j] ? wlo2 : whi2;
            float w3 = lo_j[j] ? wlo3 : whi3;
            acc[j] += w0 * hv0[j] + w1 * hv1[j] + w2 * hv2[j] + w3 * hv3[j];
        }
    }
    float inv_lo = 1.f / (ws_lo + 1e-16f);
    float inv_hi = 1.f / (ws_hi + 1e-16f);

    // normalized logits; per-lane partial max for its lo/hi tasks
    float vout[4];
    float m_lo = -1e30f, m_hi = -1e30f;
    #pragma unroll
    for (int j = 0; j < 4; ++j) {
        float v = 0.f;
        if (valj[j]) {
            v = acc[j] * (lo_j[j] ? inv_lo : inv_hi) + bcat[ch0 + j];
            if (lo_j[j]) m_lo = fmaxf(m_lo, v); else m_hi = fmaxf(m_hi, v);
        }
        vout[j] = v;
    }
    float m0 = -1e30f, m1 = -1e30f, m2 = -1e30f, m3 = -1e30f;
    m0 = (t_lo == 0) ? fmaxf(m0, m_lo) : m0;  m0 = (t_hi == 0) ? fmaxf(m0, m_hi) : m0;
    m1 = (t_lo == 1) ? fmaxf(m1, m_lo) : m1;  m1 = (t_hi == 1) ? fmaxf(m1, m_hi) : m1;
    m2 = (t_lo == 2) ? fmaxf(m2, m_lo) : m2;  m2 = (t_hi == 2) ? fmaxf(m2, m_hi) : m2;
    m3 = (t_lo == 3) ? fmaxf(m3, m_lo) : m3;  m3 = (t_hi == 3) ? fmaxf(m3, m_hi) : m3;
    #pragma unroll
    for (int off = 1; off < 64; off <<= 1) {
        m0 = fmaxf(m0, __shfl_xor(m0, off));
        m1 = fmaxf(m1, __shfl_xor(m1, off));
        m2 = fmaxf(m2, __shfl_xor(m2, off));
        m3 = fmaxf(m3, __shfl_xor(m3, off));
    }
    float mt_lo = sel4(t_lo, m0, m1, m2, m3);
    float mt_hi = sel4(t_hi, m0, m1, m2, m3);
    float s_lo = 0.f, s_hi = 0.f;
    #pragma unroll
    for (int j = 0; j < 4; ++j) {
        if (valj[j]) {
            if (lo_j[j]) s_lo += __expf(vout[j] - mt_lo);
            else         s_hi += __expf(vout[j] - mt_hi);
        }
    }
    float s0 = ((t_lo == 0) ? s_lo : 0.f) + ((t_hi == 0 && t_hi != t_lo) ? s_hi : 0.f);
    float s1 = ((t_lo == 1) ? s_lo : 0.f) + ((t_hi == 1 && t_hi != t_lo) ? s_hi : 0.f);
    float s2 = ((t_lo == 2) ? s_lo : 0.f) + ((t_hi == 2 && t_hi != t_lo) ? s_hi : 0.f);
    float s3 = ((t_lo == 3) ? s_lo : 0.f) + ((t_hi == 3 && t_hi != t_lo) ? s_hi : 0.f);
    #pragma unroll
    for (int off = 1; off < 64; off <<= 1) {
        s0 += __shfl_xor(s0, off);
        s1 += __shfl_xor(s1, off);
        s2 += __shfl_xor(s2, off);
        s3 += __shfl_xor(s3, off);
    }
    float l0 = m0 + __logf(s0), l1 = m1 + __logf(s1);
    float l2 = m2 + __logf(s2), l3 = m3 + __logf(s3);
    float lse_lo = sel4(t_lo, l0, l1, l2, l3);
    float lse_hi = sel4(t_hi, l0, l1, l2, l3);
    int co_lo = sel4i(t_lo, 0, 12, 42, 102), cl_lo = sel4i(t_lo, 12, 30, 60, 120);
    int co_hi = sel4i(t_hi, 0, 12, 42, 102), cl_hi = sel4i(t_hi, 12, 30, 60, 120);
    #pragma unroll
    for (int j = 0; j < 4; ++j) {
        if (!valj[j]) continue;
        int co = lo_j[j] ? co_lo : co_hi;
        int cl = lo_j[j] ? cl_lo : cl_hi;
        float lse = lo_j[j] ? lse_lo : lse_hi;
        out[(size_t)co * n + (size_t)wid * cl + (ch0 + j - co)] = vout[j] - lse;
    }
}

// ---------------- launcher ----------------

extern "C" void kernel_launch(void* const* d_in, const int* in_sizes, int n_in,
                              void* d_out, int out_size, void* d_ws, size_t ws_size,
                              hipStream_t stream) {
    const float* x   = (const float*)d_in[0];
    const int*   ei  = (const int*)d_in[1];
    const float* W1  = (const float*)d_in[2];
    const float* a1s = (const float*)d_in[3];
    const float* a1d = (const float*)d_in[4];
    const float* b1  = (const float*)d_in[5];
    const float* W2  = (const float*)d_in[6];
    const float* a2s = (const float*)d_in[7];
    const float* a2d = (const float*)d_in[8];
    const float* b2  = (const float*)d_in[9];
    const float* W_TL = (const float*)d_in[10]; const float* as_TL = (const float*)d_in[11];
    const float* ad_TL = (const float*)d_in[12]; const float* b_TL = (const float*)d_in[13];
    const float* W_YL = (const float*)d_in[14]; const float* as_YL = (const float*)d_in[15];
    const float* ad_YL = (const float*)d_in[16]; const float* b_YL = (const float*)d_in[17];
    const float* W_TS = (const float*)d_in[18]; const float* as_TS = (const float*)d_in[19];
    const float* ad_TS = (const float*)d_in[20]; const float* b_TS = (const float*)d_in[21];
    const float* W_TZ = (const float*)d_in[22]; const float* as_TZ = (const float*)d_in[23];
    const float* ad_TZ = (const float*)d_in[24]; const float* b_TZ = (const float*)d_in[25];

    const int N = in_sizes[0] / 128;
    const int E = in_sizes[1] / 2;
    const int* e_src = ei;
    const int* e_dst = ei + E;
    const int M4 = E + 4 * N;              // padded CSR slot bound (rows x4)

    float* ws = (float*)d_ws;
    float* B1   = ws;
    float* B2   = B1 + (size_t)N * 256;
    float* B3   = B2 + (size_t)N * 256;
    float* as1  = B3 + (size_t)N * 256;    // N*8
    float* ad1  = as1 + (size_t)N * 8;
    float* as2  = ad1 + (size_t)N * 8;
    float* ad2  = as2 + (size_t)N * 8;
    float* ast  = ad2 + (size_t)N * 8;     // N*4
    float* adt  = ast + (size_t)N * 4;
    float* Wcat = adt + (size_t)N * 4;     // 256*222
    float* bcat = Wcat + 256 * 222;        // 222 (+pad)
    float* ascat = bcat + 224;
    float* adcat = ascat + 224;
    int* deg      = (int*)(adcat + 224);   // N
    int* rowstart = deg + N;               // N+1 (cap N+4, keeps csr 16B-aligned)
    int* cursor   = rowstart + (N + 4);    // N
    int* csr      = cursor + N;            // M4 (16B-aligned)
    int* csrd     = csr + M4;              // M4
    uintptr_t wsp = (uintptr_t)(csrd + M4);
    wsp = (wsp + 15) & ~(uintptr_t)15;
    short* W1h = (short*)wsp;              // 272*128 (256 feat + 16 alpha)
    short* W1l = W1h + 272 * 128;
    short* W2h = W1l + 272 * 128;          // 272*256
    short* W2l = W2h + 272 * 256;
    short* Wth = W2l + 272 * 256;          // 230*256 (222 feat + 8 alpha)
    short* Wtl = Wth + 230 * 256;
    // overlays
    short* Xh  = (short*)B1;               // N*128
    short* Sh  = (short*)B1;               // N*256
    short* Th  = (short*)B1;               // N*256
    short* h1b = (short*)B2;               // stride 256
    short* h2b = (short*)B2;               // stride 256
    short* htb = (short*)B2;               // stride 224
    float* ew1 = B3;                       // M4*8
    float* ew2 = B3;                       // M4*8
    float* ewt = B3;                       // M4*4

    float* out = (float*)d_out;

    const int B = 256;
    // --- CSR build (padded rows) ---
    init_kernel<<<(N + B - 1) / B, B, 0, stream>>>(deg, cursor, N);
    count_kernel<<<(E + B - 1) / B, B, 0, stream>>>(e_dst, deg, E);
    scan_kernel<<<1, 1024, 0, stream>>>(deg, rowstart, N);
    hipMemsetAsync(csr, 0xFF, (size_t)2 * M4 * sizeof(int), stream);   // csr+csrd = -1
    scatter_kernel<<<(E + N + B - 1) / B, B, 0, stream>>>(e_src, e_dst, rowstart, cursor, csr, csrd, E, N);
    // --- pack + split + fold weights ---
    pack_w_kernel<<<(256 * 222 + B - 1) / B, B, 0, stream>>>(W_TL, W_YL, W_TS, W_TZ,
        b_TL, b_YL, b_TS, b_TZ, as_TL, as_YL, as_TS, as_TZ, ad_TL, ad_YL, ad_TS, ad_TZ,
        Wcat, bcat, ascat, adcat);
    split_bt_kernel<<<(256 * 128 + B - 1) / B, B, 0, stream>>>(W1, W1h, W1l, 128, 256, 7);
    split_bt_kernel<<<(256 * 256 + B - 1) / B, B, 0, stream>>>(W2, W2h, W2l, 256, 256, 8);
    split_bt_kernel<<<(222 * 256 + B - 1) / B, B, 0, stream>>>(Wcat, Wth, Wtl, 256, 222, 8);
    fold_alpha8_kernel<<<(128 * 16 + B - 1) / B, B, 0, stream>>>(W1, a1s, a1d, W1h, W1l, 128, 256);
    fold_alpha8_kernel<<<(256 * 16 + B - 1) / B, B, 0, stream>>>(W2, a2s, a2d, W2h, W2l, 256, 256);
    fold_alpha4_kernel<<<(256 * 8 + B - 1) / B, B, 0, stream>>>(Wcat, ascat, adcat, Wth, Wtl);
    // --- conv1: GEMM emits h1b bf16 + als1/ald1 directly ---
    tobf_kernel<<<((N * 128 / 4) + B - 1) / B, B, 0, stream>>>(x, Xh, N * 128 / 4);
    {
        dim3 g((272 + NB - 1) / NB, (N + MB - 1) / MB);
        gemm_mfma_kernel<<<g, 256, 0, stream>>>(Xh, W1h, W1l, h1b, 256,
                                                as1, ad1, 8, N, 128, 256, 272);
    }
    ew8_kernel<<<(M4 + B - 1) / B, B, 0, stream>>>(as1, ad1, csr, csrd, ew1, M4);
    gat_gather_kernel<<<(N + 3) / 4, 256, 0, stream>>>(h1b, ew1, rowstart, csr, b1, Sh, N, 1);
    // --- conv2 ---
    {
        dim3 g((272 + NB - 1) / NB, (N + MB - 1) / MB);
        gemm_mfma_kernel<<<g, 256, 0, stream>>>(Sh, W2h, W2l, h2b, 256,
                                                as2, ad2, 8, N, 256, 256, 272);
    }
    ew8_kernel<<<(M4 + B - 1) / B, B, 0, stream>>>(as2, ad2, csr, csrd, ew2, M4);
    gat_gather_kernel<<<(N + 3) / 4, 256, 0, stream>>>(h2b, ew2, rowstart, csr, b2, Th, N, 0);
    // --- task heads: GEMM emits htb bf16 + ast/adt ---
    {
        dim3 g((230 + NB - 1) / NB, (N + MB - 1) / MB);
        gemm_mfma_kernel<<<g, 256, 0, stream>>>(Th, Wth, Wtl, htb, 224,
                                                ast, adt, 4, N, 256, 222, 230);
    }
    ew4_kernel<<<(M4 + B - 1) / B, B, 0, stream>>>(ast, adt, csr, csrd, ewt, M4);
    task_gather_ls_kernel<<<(N + 3) / 4, 256, 0, stream>>>(htb, ewt, rowstart, csr, bcat, out, N);
}